// Round 8
// baseline (1448.473 us; speedup 1.0000x reference)
//
#include <hip/hip_runtime.h>
#include <hip/hip_bf16.h>

// ---------------------------------------------------------------------------
// Hetero-GCN (3 node types, 9 relations), 2 GraphConv layers + classifier.
// Round 6:
//  - GEMM moved to matrix cores: 3-pass split-bf16 (A_hi*W_hi + A_hi*W_lo +
//    A_lo*W_hi), mfma_f32_16x16x32_bf16, fp32 accumulate. No LDS: A planes
//    row-major bf16 -> fragment = one 16B global load (L2-resident); W
//    pre-converted to chunk-major [4][128][32] bf16 planes by k_wprep.
//  - k_agg2 emits bf16 hi/lo planes directly (same write bytes as fp32).
//  - k_fill: NT store reverted (round-5: +63us, WRITE_SIZE up — NT defeats
//    L2 line-merging on random scatter).
// ---------------------------------------------------------------------------

#define NN 50000
#define EE 400000
#define NRG 2            // node ranges for histogram
#define RGN (NN / NRG)   // 25000 nodes per range
#define HCH 8            // edge chunks
#define HEG (EE / HCH)   // 50000 edges per chunk

typedef __attribute__((ext_vector_type(8))) short bf16x8;
typedef __attribute__((ext_vector_type(4))) float f32x4;
#define MFMA16(a, b, c) __builtin_amdgcn_mfma_f32_16x16x32_bf16(a, b, c, 0, 0, 0)

// ---------------- degree histogram (chunked, LDS, no global atomics) --------
__global__ __launch_bounds__(256) void k_hist(const int* __restrict__ edges,
                                              unsigned* __restrict__ hist) {
    __shared__ unsigned bins[RGN / 2];  // 12500 u32 = 50 KB
    int bid = blockIdx.x;
    int task = bid >> 4;           // r*2 + side
    int rem = bid & 15;
    int rg = rem >> 3;
    int c = rem & 7;
    int r = task >> 1, side = task & 1;
    int tid = threadIdx.x;
    for (int i = tid; i < RGN / 2; i += 256) bins[i] = 0;
    __syncthreads();
    const int* ea = edges + (size_t)r * 2 * EE + (size_t)side * EE + (size_t)c * HEG;
    int base = rg * RGN;
    for (int e = tid; e < HEG; e += 256) {
        int idx = __builtin_nontemporal_load(&ea[e]) - base;
        if ((unsigned)idx < (unsigned)RGN)
            atomicAdd(&bins[idx >> 1], (idx & 1) ? 65536u : 1u);
    }
    __syncthreads();
    unsigned* ho = hist + ((size_t)(task * NRG + rg) * HCH + c) * (RGN / 2);
    for (int i = tid; i < RGN / 2; i += 256) ho[i] = bins[i];
}

// ---------------- reduce histograms -> ns, nd, deg_d ------------------------
__global__ void k_sums(const unsigned* __restrict__ hist, float* __restrict__ ns,
                       float* __restrict__ nd, int* __restrict__ deg_d) {
    int i = blockIdx.x * blockDim.x + threadIdx.x;
    if (i >= 9 * (NN / 2)) return;
    int r = i / (NN / 2);
    int ps = i - r * (NN / 2);
    int rg = ps / (RGN / 2);
    int slot = ps - rg * (RGN / 2);
    const unsigned* hs = hist + ((size_t)((r * 2 + 0) * NRG + rg) * HCH) * (RGN / 2) + slot;
    const unsigned* hd = hist + ((size_t)((r * 2 + 1) * NRG + rg) * HCH) * (RGN / 2) + slot;
    unsigned slo = 0, shi = 0, dlo = 0, dhi = 0;
#pragma unroll
    for (int c = 0; c < HCH; ++c) {
        unsigned a = hs[(size_t)c * (RGN / 2)];
        unsigned b = hd[(size_t)c * (RGN / 2)];
        slo += a & 0xffffu; shi += a >> 16;
        dlo += b & 0xffffu; dhi += b >> 16;
    }
    int n0 = 2 * ps;
    ns[r * NN + n0]     = slo ? rsqrtf((float)slo) : 0.f;
    ns[r * NN + n0 + 1] = shi ? rsqrtf((float)shi) : 0.f;
    nd[r * NN + n0]     = dlo ? rsqrtf((float)dlo) : 0.f;
    nd[r * NN + n0 + 1] = dhi ? rsqrtf((float)dhi) : 0.f;
    deg_d[r * NN + n0]     = (int)dlo;
    deg_d[r * NN + n0 + 1] = (int)dhi;
}

// ---------------- exclusive scan of in-degrees -> CSR offsets ---------------
__global__ __launch_bounds__(256) void k_offsets(const int* __restrict__ deg_d,
                                                 int* __restrict__ off,
                                                 int* __restrict__ cur) {
    __shared__ int wsum[4];
    __shared__ int s_carry;
    int r = blockIdx.x;
    const int* c = deg_d + r * NN;
    int* o = off + r * (NN + 1);
    int* cu = cur + r * NN;
    int tid = threadIdx.x, lane = tid & 63, w = tid >> 6;
    if (tid == 0) s_carry = 0;
    __syncthreads();
    for (int base = 0; base < NN; base += 256) {
        int i = base + tid;
        int v = (i < NN) ? c[i] : 0;
        int x = v;
#pragma unroll
        for (int s = 1; s < 64; s <<= 1) {
            int y = __shfl_up(x, (unsigned)s);
            if (lane >= s) x += y;
        }
        if (lane == 63) wsum[w] = x;
        __syncthreads();
        int wbase = 0;
#pragma unroll
        for (int j = 0; j < 3; ++j) wbase += (j < w) ? wsum[j] : 0;
        int excl = s_carry + wbase + x - v;
        if (i < NN) { o[i] = excl; cu[i] = excl; }
        __syncthreads();
        if (tid == 255) s_carry += wbase + x;
    }
    __syncthreads();
    if (tid == 0) o[NN] = s_carry;
}

// ---------------- CSR fill (global atomics; plain store) --------------------
__global__ __launch_bounds__(256) void k_fill(const int* __restrict__ edges,
                                              int* __restrict__ cur,
                                              int* __restrict__ esrc) {
    int i = blockIdx.x * blockDim.x + threadIdx.x;
    if (i >= 9 * EE) return;
    int r = i / EE;
    int e = i - r * EE;
    int src = __builtin_nontemporal_load(&edges[(size_t)r * 2 * EE + e]);
    int dst = __builtin_nontemporal_load(&edges[(size_t)r * 2 * EE + EE + e]);
    int pos = atomicAdd(&cur[r * NN + dst], 1);
    esrc[(size_t)r * EE + pos] = src;
}

// ---------------- W prep: fp32 [K][N] -> chunk-major bf16 hi/lo planes ------
// out layout per (layer*9+r): [4 kchunks][128 n][32 k]
__global__ void k_wprep(const float* __restrict__ W1, const float* __restrict__ W2,
                        unsigned short* __restrict__ whi,
                        unsigned short* __restrict__ wlo) {
    int id = blockIdx.x * blockDim.x + threadIdx.x;
    const int total = 2 * 9 * 128 * 128;
    if (id >= total) return;
    int n = id & 127;
    int k = (id >> 7) & 127;
    int rl = id >> 14;  // layer*9 + r
    const float* W = (rl < 9) ? W1 : W2;
    int r = (rl < 9) ? rl : rl - 9;
    float f = W[((size_t)r * 128 + k) * 128 + n];
    unsigned u = __float_as_uint(f);
    unsigned hb = (u + 0x7fffu + ((u >> 16) & 1u)) & 0xffff0000u;
    float lo = f - __uint_as_float(hb);
    unsigned ul = __float_as_uint(lo);
    unsigned short l16 = (unsigned short)((ul + 0x7fffu + ((ul >> 16) & 1u)) >> 16);
    size_t oidx = (((size_t)rl * 4 + (k >> 5)) * 128 + n) * 32 + (k & 31);
    whi[oidx] = (unsigned short)(hb >> 16);
    wlo[oidx] = l16;
}

// ---------------- aggregation (CSR gather, one wave per dst row) ------------
// Emits bf16 hi/lo planes of the aggregated row.
struct AggT {
    const float* xin;
    const int* off;
    const int* esrc;
    const float* ns;
    const float* nd;
    unsigned short* Ah;
    unsigned short* Al;
};

template <int RELU>
__global__ __launch_bounds__(256) void k_agg2(AggT ta, AggT tb) {
    AggT t = (blockIdx.y == 0) ? ta : tb;
    int wave = (blockIdx.x * blockDim.x + threadIdx.x) >> 6;
    int lane = threadIdx.x & 63;
    if (wave >= NN) return;
    int e0 = t.off[wave], e1 = t.off[wave + 1];
    const float* xin = t.xin;
    const int* esrc = t.esrc;
    const float* ns = t.ns;
    float a0 = 0.f, a1 = 0.f, b0 = 0.f, b1 = 0.f;
    float c0 = 0.f, c1 = 0.f, d0 = 0.f, d1 = 0.f;
    int e = e0;
    for (; e + 4 <= e1; e += 4) {
        int s0 = esrc[e], s1 = esrc[e + 1], s2 = esrc[e + 2], s3 = esrc[e + 3];
        float w0 = ns[s0], w1 = ns[s1], w2 = ns[s2], w3 = ns[s3];
        float2 v0 = *reinterpret_cast<const float2*>(xin + (size_t)s0 * 128 + lane * 2);
        float2 v1 = *reinterpret_cast<const float2*>(xin + (size_t)s1 * 128 + lane * 2);
        float2 v2 = *reinterpret_cast<const float2*>(xin + (size_t)s2 * 128 + lane * 2);
        float2 v3 = *reinterpret_cast<const float2*>(xin + (size_t)s3 * 128 + lane * 2);
        if (RELU) {
            v0.x = fmaxf(v0.x, 0.f); v0.y = fmaxf(v0.y, 0.f);
            v1.x = fmaxf(v1.x, 0.f); v1.y = fmaxf(v1.y, 0.f);
            v2.x = fmaxf(v2.x, 0.f); v2.y = fmaxf(v2.y, 0.f);
            v3.x = fmaxf(v3.x, 0.f); v3.y = fmaxf(v3.y, 0.f);
        }
        a0 = fmaf(w0, v0.x, a0); a1 = fmaf(w0, v0.y, a1);
        b0 = fmaf(w1, v1.x, b0); b1 = fmaf(w1, v1.y, b1);
        c0 = fmaf(w2, v2.x, c0); c1 = fmaf(w2, v2.y, c1);
        d0 = fmaf(w3, v3.x, d0); d1 = fmaf(w3, v3.y, d1);
    }
    for (; e < e1; ++e) {
        int s = esrc[e];
        float w = ns[s];
        float2 v = *reinterpret_cast<const float2*>(xin + (size_t)s * 128 + lane * 2);
        if (RELU) { v.x = fmaxf(v.x, 0.f); v.y = fmaxf(v.y, 0.f); }
        a0 = fmaf(w, v.x, a0); a1 = fmaf(w, v.y, a1);
    }
    float nr = t.nd[wave];
    float r0 = ((a0 + b0) + (c0 + d0)) * nr;
    float r1 = ((a1 + b1) + (c1 + d1)) * nr;
    // split-bf16: hi = rn(v), lo = rn(v - hi)
    unsigned u0 = __float_as_uint(r0);
    unsigned h0b = (u0 + 0x7fffu + ((u0 >> 16) & 1u)) & 0xffff0000u;
    unsigned ul0 = __float_as_uint(r0 - __uint_as_float(h0b));
    unsigned u1 = __float_as_uint(r1);
    unsigned h1b = (u1 + 0x7fffu + ((u1 >> 16) & 1u)) & 0xffff0000u;
    unsigned ul1 = __float_as_uint(r1 - __uint_as_float(h1b));
    ushort2 hv, lv;
    hv.x = (unsigned short)(h0b >> 16);
    hv.y = (unsigned short)(h1b >> 16);
    lv.x = (unsigned short)((ul0 + 0x7fffu + ((ul0 >> 16) & 1u)) >> 16);
    lv.y = (unsigned short)((ul1 + 0x7fffu + ((ul1 >> 16) & 1u)) >> 16);
    *reinterpret_cast<ushort2*>(t.Ah + (size_t)wave * 128 + lane * 2) = hv;
    *reinterpret_cast<ushort2*>(t.Al + (size_t)wave * 128 + lane * 2) = lv;
}

// ---------------- MFMA GEMM: H (=|+=) sum_s A_s @ W_s + bias ----------------
// A planes: [NS][NN][128] bf16 (hi,lo). W planes: chunk-major [4][128][32].
// Block 256 thr = 4 waves; block tile 64 rows x 128 cols; wave = 32-col slice,
// 4 row-tiles x 2 col-tiles of 16x16. 3-pass split product per k-chunk.
template <int NS, int STORE>
__global__ __launch_bounds__(256) void k_gemm_mfma(
    const unsigned short* __restrict__ Ah, const unsigned short* __restrict__ Al,
    const unsigned short* __restrict__ wha, const unsigned short* __restrict__ wla,
    const unsigned short* __restrict__ whb, const unsigned short* __restrict__ wlb,
    const float* __restrict__ ba, const float* __restrict__ bb,
    float* __restrict__ H) {
    int tid = threadIdx.x;
    int w = tid >> 6, lane = tid & 63;
    int row0 = blockIdx.x * 64;
    int colbase = w * 32;
    int r16 = lane & 15;
    int koff = (lane >> 4) * 8;   // k element offset within 32-chunk

    f32x4 acc[4][2];
#pragma unroll
    for (int rt = 0; rt < 4; ++rt)
#pragma unroll
        for (int nt = 0; nt < 2; ++nt)
            acc[rt][nt] = f32x4{0.f, 0.f, 0.f, 0.f};

#pragma unroll
    for (int s = 0; s < NS; ++s) {
        const unsigned short* A_h = Ah + (size_t)s * NN * 128;
        const unsigned short* A_l = Al + (size_t)s * NN * 128;
        const unsigned short* w_h = (s == 0) ? wha : whb;
        const unsigned short* w_l = (s == 0) ? wla : wlb;
#pragma unroll
        for (int c = 0; c < 4; ++c) {
            int kbase = c * 32 + koff;
            bf16x8 ah[4], al[4], bh[2], bl[2];
#pragma unroll
            for (int rt = 0; rt < 4; ++rt) {
                int rr = rt * 16 + r16;
                // OOB rows: clamp to row 0 (results discarded by epilogue guard)
                int rc = (row0 + rr < NN) ? rr : 0;
                const unsigned short* ap = A_h + ((size_t)(row0 + rc)) * 128 + kbase;
                ah[rt] = *reinterpret_cast<const bf16x8*>(ap);
                al[rt] = *reinterpret_cast<const bf16x8*>(
                    A_l + ((size_t)(row0 + rc)) * 128 + kbase);
            }
#pragma unroll
            for (int nt = 0; nt < 2; ++nt) {
                int col = colbase + nt * 16 + r16;
                size_t widx = ((size_t)c * 128 + col) * 32 + koff;
                bh[nt] = *reinterpret_cast<const bf16x8*>(w_h + widx);
                bl[nt] = *reinterpret_cast<const bf16x8*>(w_l + widx);
            }
#pragma unroll
            for (int rt = 0; rt < 4; ++rt)
#pragma unroll
                for (int nt = 0; nt < 2; ++nt) {
                    acc[rt][nt] = MFMA16(ah[rt], bh[nt], acc[rt][nt]);
                    acc[rt][nt] = MFMA16(ah[rt], bl[nt], acc[rt][nt]);
                    acc[rt][nt] = MFMA16(al[rt], bh[nt], acc[rt][nt]);
                }
        }
    }

    // epilogue: D row = (lane>>4)*4 + j, col = lane&15 (per 16x16 tile)
    int orow = (lane >> 4) * 4;
#pragma unroll
    for (int nt = 0; nt < 2; ++nt) {
        int col = colbase + nt * 16 + r16;
        float bias = ba[col];
        if (NS == 2) bias += bb[col];
#pragma unroll
        for (int rt = 0; rt < 4; ++rt) {
#pragma unroll
            for (int j = 0; j < 4; ++j) {
                int grow = row0 + rt * 16 + orow + j;
                if (grow < NN) {
                    float* hp = H + (size_t)grow * 128 + col;
                    float v = acc[rt][nt][j] + bias;
                    if (!STORE) v += *hp;
                    *hp = v;
                }
            }
        }
    }
}

// ---------------- classifier: out = relu(H) @ Wc + bc -----------------------
__global__ __launch_bounds__(256) void k_classifier(const float* __restrict__ H,
                                                    const float* __restrict__ Wc,
                                                    const float* __restrict__ bc,
                                                    float* __restrict__ out) {
    __shared__ float sW[128 * 16];
    __shared__ float sb[16];
    int tid = threadIdx.x;
#pragma unroll
    for (int i = tid; i < 2048; i += 256) sW[i] = Wc[i];
    if (tid < 16) sb[tid] = bc[tid];
    __syncthreads();
    int node = blockIdx.x * 64 + (tid >> 2);
    if (node >= 3 * NN) return;
    int cg = (tid & 3) << 2;
    const float* h = H + (size_t)node * 128;
    float acc0 = 0.f, acc1 = 0.f, acc2 = 0.f, acc3 = 0.f;
#pragma unroll 4
    for (int k0 = 0; k0 < 128; k0 += 4) {
        float4 a4 = *reinterpret_cast<const float4*>(h + k0);
        float a;
        a = fmaxf(a4.x, 0.f);
        { float4 wv = *reinterpret_cast<const float4*>(&sW[(k0 + 0) * 16 + cg]);
          acc0 = fmaf(a, wv.x, acc0); acc1 = fmaf(a, wv.y, acc1);
          acc2 = fmaf(a, wv.z, acc2); acc3 = fmaf(a, wv.w, acc3); }
        a = fmaxf(a4.y, 0.f);
        { float4 wv = *reinterpret_cast<const float4*>(&sW[(k0 + 1) * 16 + cg]);
          acc0 = fmaf(a, wv.x, acc0); acc1 = fmaf(a, wv.y, acc1);
          acc2 = fmaf(a, wv.z, acc2); acc3 = fmaf(a, wv.w, acc3); }
        a = fmaxf(a4.z, 0.f);
        { float4 wv = *reinterpret_cast<const float4*>(&sW[(k0 + 2) * 16 + cg]);
          acc0 = fmaf(a, wv.x, acc0); acc1 = fmaf(a, wv.y, acc1);
          acc2 = fmaf(a, wv.z, acc2); acc3 = fmaf(a, wv.w, acc3); }
        a = fmaxf(a4.w, 0.f);
        { float4 wv = *reinterpret_cast<const float4*>(&sW[(k0 + 3) * 16 + cg]);
          acc0 = fmaf(a, wv.x, acc0); acc1 = fmaf(a, wv.y, acc1);
          acc2 = fmaf(a, wv.z, acc2); acc3 = fmaf(a, wv.w, acc3); }
    }
    float4 o = make_float4(acc0 + sb[cg], acc1 + sb[cg + 1],
                           acc2 + sb[cg + 2], acc3 + sb[cg + 3]);
    *reinterpret_cast<float4*>(out + (size_t)node * 16 + cg) = o;
}

// ---------------------------------------------------------------------------
extern "C" void kernel_launch(void* const* d_in, const int* in_sizes, int n_in,
                              void* d_out, int out_size, void* d_ws, size_t ws_size,
                              hipStream_t stream) {
    const float* x0 = (const float*)d_in[0];
    const float* x1 = (const float*)d_in[1];
    const float* x2 = (const float*)d_in[2];
    const float* W1 = (const float*)d_in[3];
    const float* b1 = (const float*)d_in[4];
    const float* W2 = (const float*)d_in[5];
    const float* b2 = (const float*)d_in[6];
    const float* Wc = (const float*)d_in[7];
    const float* bc = (const float*)d_in[8];
    const int* edges = (const int*)d_in[9];
    const float* x[3] = {x0, x1, x2};

    const int REL_S[9] = {0, 1, 1, 0, 2, 2, 0, 2, 1};

    // ---- workspace carve-up with overlays (~226 MB peak) ----
    char* p = (char*)d_ws;
    auto alloc = [&](size_t bytes) -> void* {
        void* r = (void*)p;
        p += (bytes + 255) & ~(size_t)255;
        return r;
    };
    float* h2 = (float*)alloc((size_t)3 * NN * 128 * sizeof(float));  // 76.8 MB
    unsigned* hist = (unsigned*)h2;    // alias: hist dead after k_sums
    float* h1 = (float*)alloc((size_t)3 * NN * 128 * sizeof(float));  // 76.8 MB
    int* cur = (int*)h1;               // alias: cur dead after k_fill
    int* deg_d = (int*)(h1 + 9 * NN);  // alias: deg_d dead after k_offsets
    unsigned short* Ah = (unsigned short*)alloc((size_t)2 * NN * 128 * 2);  // 25.6 MB
    unsigned short* Al = (unsigned short*)alloc((size_t)2 * NN * 128 * 2);  // 25.6 MB
    int* off = (int*)alloc((size_t)9 * (NN + 1) * sizeof(int));
    float* ns = (float*)alloc((size_t)9 * NN * sizeof(float));
    float* nd = (float*)alloc((size_t)9 * NN * sizeof(float));
    int* esrc = (int*)alloc((size_t)9 * EE * sizeof(int));            // 14.4 MB
    unsigned short* whi = (unsigned short*)alloc((size_t)2 * 9 * 128 * 128 * 2);
    unsigned short* wlo = (unsigned short*)alloc((size_t)2 * 9 * 128 * 128 * 2);
    unsigned short* Ah1 = Ah + (size_t)NN * 128;
    unsigned short* Al1 = Al + (size_t)NN * 128;

    // ---- CSR build + W prep (reused by both layers) ----
    k_hist<<<288, 256, 0, stream>>>(edges, hist);
    k_sums<<<(9 * (NN / 2) + 255) / 256, 256, 0, stream>>>(hist, ns, nd, deg_d);
    k_offsets<<<9, 256, 0, stream>>>(deg_d, off, cur);
    k_fill<<<(9 * EE + 255) / 256, 256, 0, stream>>>(edges, cur, esrc);
    k_wprep<<<(2 * 9 * 128 * 128 + 255) / 256, 256, 0, stream>>>(W1, W2, whi, wlo);

    const dim3 agg2_grid(12500, 2);
    const dim3 agg1_grid(12500, 1);
    const int gemm_blocks = (NN + 63) / 64;   // 782

    auto mk = [&](int r, const float* xin, unsigned short* ah, unsigned short* al) -> AggT {
        return AggT{xin, off + r * (NN + 1), esrc + (size_t)r * EE,
                    ns + r * NN, nd + r * NN, ah, al};
    };
    auto wp = [&](int layer, int r) { return (size_t)(layer * 9 + r) * 16384; };

    // ======== layer 1 (inputs x[], no relu) ========
    {
        const float* b = b1; float* h = h1; const int L = 0;
        k_agg2<0><<<agg2_grid, 256, 0, stream>>>(mk(2, x[REL_S[2]], Ah, Al),
                                                 mk(3, x[REL_S[3]], Ah1, Al1));
        k_gemm_mfma<2, 1><<<gemm_blocks, 256, 0, stream>>>(
            Ah, Al, whi + wp(L, 2), wlo + wp(L, 2), whi + wp(L, 3), wlo + wp(L, 3),
            b + 2 * 128, b + 3 * 128, h + (size_t)0 * NN * 128);
        k_agg2<0><<<agg2_grid, 256, 0, stream>>>(mk(5, x[REL_S[5]], Ah, Al),
                                                 mk(6, x[REL_S[6]], Ah1, Al1));
        k_gemm_mfma<2, 0><<<gemm_blocks, 256, 0, stream>>>(
            Ah, Al, whi + wp(L, 5), wlo + wp(L, 5), whi + wp(L, 6), wlo + wp(L, 6),
            b + 5 * 128, b + 6 * 128, h + (size_t)0 * NN * 128);
        k_agg2<0><<<agg2_grid, 256, 0, stream>>>(mk(4, x[REL_S[4]], Ah, Al),
                                                 mk(8, x[REL_S[8]], Ah1, Al1));
        k_gemm_mfma<2, 1><<<gemm_blocks, 256, 0, stream>>>(
            Ah, Al, whi + wp(L, 4), wlo + wp(L, 4), whi + wp(L, 8), wlo + wp(L, 8),
            b + 4 * 128, b + 8 * 128, h + (size_t)1 * NN * 128);
        k_agg2<0><<<agg2_grid, 256, 0, stream>>>(mk(0, x[REL_S[0]], Ah, Al),
                                                 mk(1, x[REL_S[1]], Ah1, Al1));
        k_gemm_mfma<2, 1><<<gemm_blocks, 256, 0, stream>>>(
            Ah, Al, whi + wp(L, 0), wlo + wp(L, 0), whi + wp(L, 1), wlo + wp(L, 1),
            b + 0 * 128, b + 1 * 128, h + (size_t)2 * NN * 128);
        k_agg2<0><<<agg1_grid, 256, 0, stream>>>(mk(7, x[REL_S[7]], Ah, Al),
                                                 mk(7, x[REL_S[7]], Ah, Al));
        k_gemm_mfma<1, 0><<<gemm_blocks, 256, 0, stream>>>(
            Ah, Al, whi + wp(L, 7), wlo + wp(L, 7), whi + wp(L, 7), wlo + wp(L, 7),
            b + 7 * 128, b + 7 * 128, h + (size_t)2 * NN * 128);
    }

    // ======== layer 2 (inputs relu(h1), folded into gather) ========
    {
        const float* b = b2; float* h = h2; const int L = 1;
        auto hin = [&](int r) { return h1 + (size_t)REL_S[r] * NN * 128; };
        k_agg2<1><<<agg2_grid, 256, 0, stream>>>(mk(2, hin(2), Ah, Al),
                                                 mk(3, hin(3), Ah1, Al1));
        k_gemm_mfma<2, 1><<<gemm_blocks, 256, 0, stream>>>(
            Ah, Al, whi + wp(L, 2), wlo + wp(L, 2), whi + wp(L, 3), wlo + wp(L, 3),
            b + 2 * 128, b + 3 * 128, h + (size_t)0 * NN * 128);
        k_agg2<1><<<agg2_grid, 256, 0, stream>>>(mk(5, hin(5), Ah, Al),
                                                 mk(6, hin(6), Ah1, Al1));
        k_gemm_mfma<2, 0><<<gemm_blocks, 256, 0, stream>>>(
            Ah, Al, whi + wp(L, 5), wlo + wp(L, 5), whi + wp(L, 6), wlo + wp(L, 6),
            b + 5 * 128, b + 6 * 128, h + (size_t)0 * NN * 128);
        k_agg2<1><<<agg2_grid, 256, 0, stream>>>(mk(4, hin(4), Ah, Al),
                                                 mk(8, hin(8), Ah1, Al1));
        k_gemm_mfma<2, 1><<<gemm_blocks, 256, 0, stream>>>(
            Ah, Al, whi + wp(L, 4), wlo + wp(L, 4), whi + wp(L, 8), wlo + wp(L, 8),
            b + 4 * 128, b + 8 * 128, h + (size_t)1 * NN * 128);
        k_agg2<1><<<agg2_grid, 256, 0, stream>>>(mk(0, hin(0), Ah, Al),
                                                 mk(1, hin(1), Ah1, Al1));
        k_gemm_mfma<2, 1><<<gemm_blocks, 256, 0, stream>>>(
            Ah, Al, whi + wp(L, 0), wlo + wp(L, 0), whi + wp(L, 1), wlo + wp(L, 1),
            b + 0 * 128, b + 1 * 128, h + (size_t)2 * NN * 128);
        k_agg2<1><<<agg1_grid, 256, 0, stream>>>(mk(7, hin(7), Ah, Al),
                                                 mk(7, hin(7), Ah, Al));
        k_gemm_mfma<1, 0><<<gemm_blocks, 256, 0, stream>>>(
            Ah, Al, whi + wp(L, 7), wlo + wp(L, 7), whi + wp(L, 7), wlo + wp(L, 7),
            b + 7 * 128, b + 7 * 128, h + (size_t)2 * NN * 128);
    }

    // ---- classifier: out = relu(h2) @ Wc + bc ----
    k_classifier<<<(3 * NN + 63) / 64, 256, 0, stream>>>(h2, Wc, bc, (float*)d_out);
}

// Round 9
// 1436.513 us; speedup vs baseline: 1.0083x; 1.0083x over previous
//
#include <hip/hip_runtime.h>
#include <hip/hip_bf16.h>

// ---------------------------------------------------------------------------
// Hetero-GCN (3 node types, 9 relations), 2 GraphConv layers + classifier.
// Round 6:
//  - GEMM moved to matrix cores: 3-pass split-bf16 (A_hi*W_hi + A_hi*W_lo +
//    A_lo*W_hi), mfma_f32_16x16x32_bf16, fp32 accumulate. No LDS: A planes
//    row-major bf16 -> fragment = one 16B global load (L2-resident); W
//    pre-converted to chunk-major [4][128][32] bf16 planes by k_wprep.
//  - k_agg2 emits bf16 hi/lo planes directly (same write bytes as fp32).
//  - k_fill: NT store reverted (round-5: +63us, WRITE_SIZE up — NT defeats
//    L2 line-merging on random scatter).
// ---------------------------------------------------------------------------

#define NN 50000
#define EE 400000
#define NRG 2            // node ranges for histogram
#define RGN (NN / NRG)   // 25000 nodes per range
#define HCH 8            // edge chunks
#define HEG (EE / HCH)   // 50000 edges per chunk

typedef __attribute__((ext_vector_type(8))) short bf16x8;
typedef __attribute__((ext_vector_type(4))) float f32x4;
#define MFMA16(a, b, c) __builtin_amdgcn_mfma_f32_16x16x32_bf16(a, b, c, 0, 0, 0)

// ---------------- degree histogram (chunked, LDS, no global atomics) --------
__global__ __launch_bounds__(256) void k_hist(const int* __restrict__ edges,
                                              unsigned* __restrict__ hist) {
    __shared__ unsigned bins[RGN / 2];  // 12500 u32 = 50 KB
    int bid = blockIdx.x;
    int task = bid >> 4;           // r*2 + side
    int rem = bid & 15;
    int rg = rem >> 3;
    int c = rem & 7;
    int r = task >> 1, side = task & 1;
    int tid = threadIdx.x;
    for (int i = tid; i < RGN / 2; i += 256) bins[i] = 0;
    __syncthreads();
    const int* ea = edges + (size_t)r * 2 * EE + (size_t)side * EE + (size_t)c * HEG;
    int base = rg * RGN;
    for (int e = tid; e < HEG; e += 256) {
        int idx = __builtin_nontemporal_load(&ea[e]) - base;
        if ((unsigned)idx < (unsigned)RGN)
            atomicAdd(&bins[idx >> 1], (idx & 1) ? 65536u : 1u);
    }
    __syncthreads();
    unsigned* ho = hist + ((size_t)(task * NRG + rg) * HCH + c) * (RGN / 2);
    for (int i = tid; i < RGN / 2; i += 256) ho[i] = bins[i];
}

// ---------------- reduce histograms -> ns, nd, deg_d ------------------------
__global__ void k_sums(const unsigned* __restrict__ hist, float* __restrict__ ns,
                       float* __restrict__ nd, int* __restrict__ deg_d) {
    int i = blockIdx.x * blockDim.x + threadIdx.x;
    if (i >= 9 * (NN / 2)) return;
    int r = i / (NN / 2);
    int ps = i - r * (NN / 2);
    int rg = ps / (RGN / 2);
    int slot = ps - rg * (RGN / 2);
    const unsigned* hs = hist + ((size_t)((r * 2 + 0) * NRG + rg) * HCH) * (RGN / 2) + slot;
    const unsigned* hd = hist + ((size_t)((r * 2 + 1) * NRG + rg) * HCH) * (RGN / 2) + slot;
    unsigned slo = 0, shi = 0, dlo = 0, dhi = 0;
#pragma unroll
    for (int c = 0; c < HCH; ++c) {
        unsigned a = hs[(size_t)c * (RGN / 2)];
        unsigned b = hd[(size_t)c * (RGN / 2)];
        slo += a & 0xffffu; shi += a >> 16;
        dlo += b & 0xffffu; dhi += b >> 16;
    }
    int n0 = 2 * ps;
    ns[r * NN + n0]     = slo ? rsqrtf((float)slo) : 0.f;
    ns[r * NN + n0 + 1] = shi ? rsqrtf((float)shi) : 0.f;
    nd[r * NN + n0]     = dlo ? rsqrtf((float)dlo) : 0.f;
    nd[r * NN + n0 + 1] = dhi ? rsqrtf((float)dhi) : 0.f;
    deg_d[r * NN + n0]     = (int)dlo;
    deg_d[r * NN + n0 + 1] = (int)dhi;
}

// ---------------- exclusive scan of in-degrees -> CSR offsets ---------------
__global__ __launch_bounds__(256) void k_offsets(const int* __restrict__ deg_d,
                                                 int* __restrict__ off,
                                                 int* __restrict__ cur) {
    __shared__ int wsum[4];
    __shared__ int s_carry;
    int r = blockIdx.x;
    const int* c = deg_d + r * NN;
    int* o = off + r * (NN + 1);
    int* cu = cur + r * NN;
    int tid = threadIdx.x, lane = tid & 63, w = tid >> 6;
    if (tid == 0) s_carry = 0;
    __syncthreads();
    for (int base = 0; base < NN; base += 256) {
        int i = base + tid;
        int v = (i < NN) ? c[i] : 0;
        int x = v;
#pragma unroll
        for (int s = 1; s < 64; s <<= 1) {
            int y = __shfl_up(x, (unsigned)s);
            if (lane >= s) x += y;
        }
        if (lane == 63) wsum[w] = x;
        __syncthreads();
        int wbase = 0;
#pragma unroll
        for (int j = 0; j < 3; ++j) wbase += (j < w) ? wsum[j] : 0;
        int excl = s_carry + wbase + x - v;
        if (i < NN) { o[i] = excl; cu[i] = excl; }
        __syncthreads();
        if (tid == 255) s_carry += wbase + x;
    }
    __syncthreads();
    if (tid == 0) o[NN] = s_carry;
}

// ---------------- CSR fill (global atomics; plain store) --------------------
__global__ __launch_bounds__(256) void k_fill(const int* __restrict__ edges,
                                              int* __restrict__ cur,
                                              int* __restrict__ esrc) {
    int i = blockIdx.x * blockDim.x + threadIdx.x;
    if (i >= 9 * EE) return;
    int r = i / EE;
    int e = i - r * EE;
    int src = __builtin_nontemporal_load(&edges[(size_t)r * 2 * EE + e]);
    int dst = __builtin_nontemporal_load(&edges[(size_t)r * 2 * EE + EE + e]);
    int pos = atomicAdd(&cur[r * NN + dst], 1);
    esrc[(size_t)r * EE + pos] = src;
}

// ---------------- W prep: fp32 [K][N] -> chunk-major bf16 hi/lo planes ------
// out layout per (layer*9+r): [4 kchunks][128 n][32 k]
__global__ void k_wprep(const float* __restrict__ W1, const float* __restrict__ W2,
                        unsigned short* __restrict__ whi,
                        unsigned short* __restrict__ wlo) {
    int id = blockIdx.x * blockDim.x + threadIdx.x;
    const int total = 2 * 9 * 128 * 128;
    if (id >= total) return;
    int n = id & 127;
    int k = (id >> 7) & 127;
    int rl = id >> 14;  // layer*9 + r
    const float* W = (rl < 9) ? W1 : W2;
    int r = (rl < 9) ? rl : rl - 9;
    float f = W[((size_t)r * 128 + k) * 128 + n];
    unsigned u = __float_as_uint(f);
    unsigned hb = (u + 0x7fffu + ((u >> 16) & 1u)) & 0xffff0000u;
    float lo = f - __uint_as_float(hb);
    unsigned ul = __float_as_uint(lo);
    unsigned short l16 = (unsigned short)((ul + 0x7fffu + ((ul >> 16) & 1u)) >> 16);
    size_t oidx = (((size_t)rl * 4 + (k >> 5)) * 128 + n) * 32 + (k & 31);
    whi[oidx] = (unsigned short)(hb >> 16);
    wlo[oidx] = l16;
}

// ---------------- aggregation (CSR gather, one wave per dst row) ------------
// Emits bf16 hi/lo planes of the aggregated row.
struct AggT {
    const float* xin;
    const int* off;
    const int* esrc;
    const float* ns;
    const float* nd;
    unsigned short* Ah;
    unsigned short* Al;
};

template <int RELU>
__global__ __launch_bounds__(256) void k_agg2(AggT ta, AggT tb) {
    AggT t = (blockIdx.y == 0) ? ta : tb;
    int wave = (blockIdx.x * blockDim.x + threadIdx.x) >> 6;
    int lane = threadIdx.x & 63;
    if (wave >= NN) return;
    int e0 = t.off[wave], e1 = t.off[wave + 1];
    const float* xin = t.xin;
    const int* esrc = t.esrc;
    const float* ns = t.ns;
    float a0 = 0.f, a1 = 0.f, b0 = 0.f, b1 = 0.f;
    float c0 = 0.f, c1 = 0.f, d0 = 0.f, d1 = 0.f;
    int e = e0;
    for (; e + 4 <= e1; e += 4) {
        int s0 = esrc[e], s1 = esrc[e + 1], s2 = esrc[e + 2], s3 = esrc[e + 3];
        float w0 = ns[s0], w1 = ns[s1], w2 = ns[s2], w3 = ns[s3];
        float2 v0 = *reinterpret_cast<const float2*>(xin + (size_t)s0 * 128 + lane * 2);
        float2 v1 = *reinterpret_cast<const float2*>(xin + (size_t)s1 * 128 + lane * 2);
        float2 v2 = *reinterpret_cast<const float2*>(xin + (size_t)s2 * 128 + lane * 2);
        float2 v3 = *reinterpret_cast<const float2*>(xin + (size_t)s3 * 128 + lane * 2);
        if (RELU) {
            v0.x = fmaxf(v0.x, 0.f); v0.y = fmaxf(v0.y, 0.f);
            v1.x = fmaxf(v1.x, 0.f); v1.y = fmaxf(v1.y, 0.f);
            v2.x = fmaxf(v2.x, 0.f); v2.y = fmaxf(v2.y, 0.f);
            v3.x = fmaxf(v3.x, 0.f); v3.y = fmaxf(v3.y, 0.f);
        }
        a0 = fmaf(w0, v0.x, a0); a1 = fmaf(w0, v0.y, a1);
        b0 = fmaf(w1, v1.x, b0); b1 = fmaf(w1, v1.y, b1);
        c0 = fmaf(w2, v2.x, c0); c1 = fmaf(w2, v2.y, c1);
        d0 = fmaf(w3, v3.x, d0); d1 = fmaf(w3, v3.y, d1);
    }
    for (; e < e1; ++e) {
        int s = esrc[e];
        float w = ns[s];
        float2 v = *reinterpret_cast<const float2*>(xin + (size_t)s * 128 + lane * 2);
        if (RELU) { v.x = fmaxf(v.x, 0.f); v.y = fmaxf(v.y, 0.f); }
        a0 = fmaf(w, v.x, a0); a1 = fmaf(w, v.y, a1);
    }
    float nr = t.nd[wave];
    float r0 = ((a0 + b0) + (c0 + d0)) * nr;
    float r1 = ((a1 + b1) + (c1 + d1)) * nr;
    // split-bf16: hi = rn(v), lo = rn(v - hi)
    unsigned u0 = __float_as_uint(r0);
    unsigned h0b = (u0 + 0x7fffu + ((u0 >> 16) & 1u)) & 0xffff0000u;
    unsigned ul0 = __float_as_uint(r0 - __uint_as_float(h0b));
    unsigned u1 = __float_as_uint(r1);
    unsigned h1b = (u1 + 0x7fffu + ((u1 >> 16) & 1u)) & 0xffff0000u;
    unsigned ul1 = __float_as_uint(r1 - __uint_as_float(h1b));
    ushort2 hv, lv;
    hv.x = (unsigned short)(h0b >> 16);
    hv.y = (unsigned short)(h1b >> 16);
    lv.x = (unsigned short)((ul0 + 0x7fffu + ((ul0 >> 16) & 1u)) >> 16);
    lv.y = (unsigned short)((ul1 + 0x7fffu + ((ul1 >> 16) & 1u)) >> 16);
    *reinterpret_cast<ushort2*>(t.Ah + (size_t)wave * 128 + lane * 2) = hv;
    *reinterpret_cast<ushort2*>(t.Al + (size_t)wave * 128 + lane * 2) = lv;
}

// ---------------- MFMA GEMM: H (=|+=) sum_s A_s @ W_s + bias ----------------
// A planes: [NS][NN][128] bf16 (hi,lo). W planes: chunk-major [4][128][32].
// Block 256 thr = 4 waves; block tile 64 rows x 128 cols; wave = 32-col slice,
// 4 row-tiles x 2 col-tiles of 16x16. 3-pass split product per k-chunk.
template <int NS, int STORE>
__global__ __launch_bounds__(256) void k_gemm_mfma(
    const unsigned short* __restrict__ Ah, const unsigned short* __restrict__ Al,
    const unsigned short* __restrict__ wha, const unsigned short* __restrict__ wla,
    const unsigned short* __restrict__ whb, const unsigned short* __restrict__ wlb,
    const float* __restrict__ ba, const float* __restrict__ bb,
    float* __restrict__ H) {
    int tid = threadIdx.x;
    int w = tid >> 6, lane = tid & 63;
    int row0 = blockIdx.x * 64;
    int colbase = w * 32;
    int r16 = lane & 15;
    int koff = (lane >> 4) * 8;   // k element offset within 32-chunk

    f32x4 acc[4][2];
#pragma unroll
    for (int rt = 0; rt < 4; ++rt)
#pragma unroll
        for (int nt = 0; nt < 2; ++nt)
            acc[rt][nt] = f32x4{0.f, 0.f, 0.f, 0.f};

#pragma unroll
    for (int s = 0; s < NS; ++s) {
        const unsigned short* A_h = Ah + (size_t)s * NN * 128;
        const unsigned short* A_l = Al + (size_t)s * NN * 128;
        const unsigned short* w_h = (s == 0) ? wha : whb;
        const unsigned short* w_l = (s == 0) ? wla : wlb;
#pragma unroll
        for (int c = 0; c < 4; ++c) {
            int kbase = c * 32 + koff;
            bf16x8 ah[4], al[4], bh[2], bl[2];
#pragma unroll
            for (int rt = 0; rt < 4; ++rt) {
                int rr = rt * 16 + r16;
                // OOB rows: clamp to row 0 (results discarded by epilogue guard)
                int rc = (row0 + rr < NN) ? rr : 0;
                const unsigned short* ap = A_h + ((size_t)(row0 + rc)) * 128 + kbase;
                ah[rt] = *reinterpret_cast<const bf16x8*>(ap);
                al[rt] = *reinterpret_cast<const bf16x8*>(
                    A_l + ((size_t)(row0 + rc)) * 128 + kbase);
            }
#pragma unroll
            for (int nt = 0; nt < 2; ++nt) {
                int col = colbase + nt * 16 + r16;
                size_t widx = ((size_t)c * 128 + col) * 32 + koff;
                bh[nt] = *reinterpret_cast<const bf16x8*>(w_h + widx);
                bl[nt] = *reinterpret_cast<const bf16x8*>(w_l + widx);
            }
#pragma unroll
            for (int rt = 0; rt < 4; ++rt)
#pragma unroll
                for (int nt = 0; nt < 2; ++nt) {
                    acc[rt][nt] = MFMA16(ah[rt], bh[nt], acc[rt][nt]);
                    acc[rt][nt] = MFMA16(ah[rt], bl[nt], acc[rt][nt]);
                    acc[rt][nt] = MFMA16(al[rt], bh[nt], acc[rt][nt]);
                }
        }
    }

    // epilogue: D row = (lane>>4)*4 + j, col = lane&15 (per 16x16 tile)
    int orow = (lane >> 4) * 4;
#pragma unroll
    for (int nt = 0; nt < 2; ++nt) {
        int col = colbase + nt * 16 + r16;
        float bias = ba[col];
        if (NS == 2) bias += bb[col];
#pragma unroll
        for (int rt = 0; rt < 4; ++rt) {
#pragma unroll
            for (int j = 0; j < 4; ++j) {
                int grow = row0 + rt * 16 + orow + j;
                if (grow < NN) {
                    float* hp = H + (size_t)grow * 128 + col;
                    float v = acc[rt][nt][j] + bias;
                    if (!STORE) v += *hp;
                    *hp = v;
                }
            }
        }
    }
}

// ---------------- classifier: out = relu(H) @ Wc + bc -----------------------
__global__ __launch_bounds__(256) void k_classifier(const float* __restrict__ H,
                                                    const float* __restrict__ Wc,
                                                    const float* __restrict__ bc,
                                                    float* __restrict__ out) {
    __shared__ float sW[128 * 16];
    __shared__ float sb[16];
    int tid = threadIdx.x;
#pragma unroll
    for (int i = tid; i < 2048; i += 256) sW[i] = Wc[i];
    if (tid < 16) sb[tid] = bc[tid];
    __syncthreads();
    int node = blockIdx.x * 64 + (tid >> 2);
    if (node >= 3 * NN) return;
    int cg = (tid & 3) << 2;
    const float* h = H + (size_t)node * 128;
    float acc0 = 0.f, acc1 = 0.f, acc2 = 0.f, acc3 = 0.f;
#pragma unroll 4
    for (int k0 = 0; k0 < 128; k0 += 4) {
        float4 a4 = *reinterpret_cast<const float4*>(h + k0);
        float a;
        a = fmaxf(a4.x, 0.f);
        { float4 wv = *reinterpret_cast<const float4*>(&sW[(k0 + 0) * 16 + cg]);
          acc0 = fmaf(a, wv.x, acc0); acc1 = fmaf(a, wv.y, acc1);
          acc2 = fmaf(a, wv.z, acc2); acc3 = fmaf(a, wv.w, acc3); }
        a = fmaxf(a4.y, 0.f);
        { float4 wv = *reinterpret_cast<const float4*>(&sW[(k0 + 1) * 16 + cg]);
          acc0 = fmaf(a, wv.x, acc0); acc1 = fmaf(a, wv.y, acc1);
          acc2 = fmaf(a, wv.z, acc2); acc3 = fmaf(a, wv.w, acc3); }
        a = fmaxf(a4.z, 0.f);
        { float4 wv = *reinterpret_cast<const float4*>(&sW[(k0 + 2) * 16 + cg]);
          acc0 = fmaf(a, wv.x, acc0); acc1 = fmaf(a, wv.y, acc1);
          acc2 = fmaf(a, wv.z, acc2); acc3 = fmaf(a, wv.w, acc3); }
        a = fmaxf(a4.w, 0.f);
        { float4 wv = *reinterpret_cast<const float4*>(&sW[(k0 + 3) * 16 + cg]);
          acc0 = fmaf(a, wv.x, acc0); acc1 = fmaf(a, wv.y, acc1);
          acc2 = fmaf(a, wv.z, acc2); acc3 = fmaf(a, wv.w, acc3); }
    }
    float4 o = make_float4(acc0 + sb[cg], acc1 + sb[cg + 1],
                           acc2 + sb[cg + 2], acc3 + sb[cg + 3]);
    *reinterpret_cast<float4*>(out + (size_t)node * 16 + cg) = o;
}

// ---------------------------------------------------------------------------
extern "C" void kernel_launch(void* const* d_in, const int* in_sizes, int n_in,
                              void* d_out, int out_size, void* d_ws, size_t ws_size,
                              hipStream_t stream) {
    const float* x0 = (const float*)d_in[0];
    const float* x1 = (const float*)d_in[1];
    const float* x2 = (const float*)d_in[2];
    const float* W1 = (const float*)d_in[3];
    const float* b1 = (const float*)d_in[4];
    const float* W2 = (const float*)d_in[5];
    const float* b2 = (const float*)d_in[6];
    const float* Wc = (const float*)d_in[7];
    const float* bc = (const float*)d_in[8];
    const int* edges = (const int*)d_in[9];
    const float* x[3] = {x0, x1, x2};

    const int REL_S[9] = {0, 1, 1, 0, 2, 2, 0, 2, 1};

    // ---- workspace carve-up with overlays (~226 MB peak) ----
    char* p = (char*)d_ws;
    auto alloc = [&](size_t bytes) -> void* {
        void* r = (void*)p;
        p += (bytes + 255) & ~(size_t)255;
        return r;
    };
    float* h2 = (float*)alloc((size_t)3 * NN * 128 * sizeof(float));  // 76.8 MB
    unsigned* hist = (unsigned*)h2;    // alias: hist dead after k_sums
    float* h1 = (float*)alloc((size_t)3 * NN * 128 * sizeof(float));  // 76.8 MB
    int* cur = (int*)h1;               // alias: cur dead after k_fill
    int* deg_d = (int*)(h1 + 9 * NN);  // alias: deg_d dead after k_offsets
    unsigned short* Ah = (unsigned short*)alloc((size_t)2 * NN * 128 * 2);  // 25.6 MB
    unsigned short* Al = (unsigned short*)alloc((size_t)2 * NN * 128 * 2);  // 25.6 MB
    int* off = (int*)alloc((size_t)9 * (NN + 1) * sizeof(int));
    float* ns = (float*)alloc((size_t)9 * NN * sizeof(float));
    float* nd = (float*)alloc((size_t)9 * NN * sizeof(float));
    int* esrc = (int*)alloc((size_t)9 * EE * sizeof(int));            // 14.4 MB
    unsigned short* whi = (unsigned short*)alloc((size_t)2 * 9 * 128 * 128 * 2);
    unsigned short* wlo = (unsigned short*)alloc((size_t)2 * 9 * 128 * 128 * 2);
    unsigned short* Ah1 = Ah + (size_t)NN * 128;
    unsigned short* Al1 = Al + (size_t)NN * 128;

    // ---- CSR build + W prep (reused by both layers) ----
    k_hist<<<288, 256, 0, stream>>>(edges, hist);
    k_sums<<<(9 * (NN / 2) + 255) / 256, 256, 0, stream>>>(hist, ns, nd, deg_d);
    k_offsets<<<9, 256, 0, stream>>>(deg_d, off, cur);
    k_fill<<<(9 * EE + 255) / 256, 256, 0, stream>>>(edges, cur, esrc);
    k_wprep<<<(2 * 9 * 128 * 128 + 255) / 256, 256, 0, stream>>>(W1, W2, whi, wlo);

    const dim3 agg2_grid(12500, 2);
    const dim3 agg1_grid(12500, 1);
    const int gemm_blocks = (NN + 63) / 64;   // 782

    auto mk = [&](int r, const float* xin, unsigned short* ah, unsigned short* al) -> AggT {
        return AggT{xin, off + r * (NN + 1), esrc + (size_t)r * EE,
                    ns + r * NN, nd + r * NN, ah, al};
    };
    auto wp = [&](int layer, int r) { return (size_t)(layer * 9 + r) * 16384; };

    // ======== layer 1 (inputs x[], no relu) ========
    {
        const float* b = b1; float* h = h1; const int L = 0;
        k_agg2<0><<<agg2_grid, 256, 0, stream>>>(mk(2, x[REL_S[2]], Ah, Al),
                                                 mk(3, x[REL_S[3]], Ah1, Al1));
        k_gemm_mfma<2, 1><<<gemm_blocks, 256, 0, stream>>>(
            Ah, Al, whi + wp(L, 2), wlo + wp(L, 2), whi + wp(L, 3), wlo + wp(L, 3),
            b + 2 * 128, b + 3 * 128, h + (size_t)0 * NN * 128);
        k_agg2<0><<<agg2_grid, 256, 0, stream>>>(mk(5, x[REL_S[5]], Ah, Al),
                                                 mk(6, x[REL_S[6]], Ah1, Al1));
        k_gemm_mfma<2, 0><<<gemm_blocks, 256, 0, stream>>>(
            Ah, Al, whi + wp(L, 5), wlo + wp(L, 5), whi + wp(L, 6), wlo + wp(L, 6),
            b + 5 * 128, b + 6 * 128, h + (size_t)0 * NN * 128);
        k_agg2<0><<<agg2_grid, 256, 0, stream>>>(mk(4, x[REL_S[4]], Ah, Al),
                                                 mk(8, x[REL_S[8]], Ah1, Al1));
        k_gemm_mfma<2, 1><<<gemm_blocks, 256, 0, stream>>>(
            Ah, Al, whi + wp(L, 4), wlo + wp(L, 4), whi + wp(L, 8), wlo + wp(L, 8),
            b + 4 * 128, b + 8 * 128, h + (size_t)1 * NN * 128);
        k_agg2<0><<<agg2_grid, 256, 0, stream>>>(mk(0, x[REL_S[0]], Ah, Al),
                                                 mk(1, x[REL_S[1]], Ah1, Al1));
        k_gemm_mfma<2, 1><<<gemm_blocks, 256, 0, stream>>>(
            Ah, Al, whi + wp(L, 0), wlo + wp(L, 0), whi + wp(L, 1), wlo + wp(L, 1),
            b + 0 * 128, b + 1 * 128, h + (size_t)2 * NN * 128);
        k_agg2<0><<<agg1_grid, 256, 0, stream>>>(mk(7, x[REL_S[7]], Ah, Al),
                                                 mk(7, x[REL_S[7]], Ah, Al));
        k_gemm_mfma<1, 0><<<gemm_blocks, 256, 0, stream>>>(
            Ah, Al, whi + wp(L, 7), wlo + wp(L, 7), whi + wp(L, 7), wlo + wp(L, 7),
            b + 7 * 128, b + 7 * 128, h + (size_t)2 * NN * 128);
    }

    // ======== layer 2 (inputs relu(h1), folded into gather) ========
    {
        const float* b = b2; float* h = h2; const int L = 1;
        auto hin = [&](int r) { return h1 + (size_t)REL_S[r] * NN * 128; };
        k_agg2<1><<<agg2_grid, 256, 0, stream>>>(mk(2, hin(2), Ah, Al),
                                                 mk(3, hin(3), Ah1, Al1));
        k_gemm_mfma<2, 1><<<gemm_blocks, 256, 0, stream>>>(
            Ah, Al, whi + wp(L, 2), wlo + wp(L, 2), whi + wp(L, 3), wlo + wp(L, 3),
            b + 2 * 128, b + 3 * 128, h + (size_t)0 * NN * 128);
        k_agg2<1><<<agg2_grid, 256, 0, stream>>>(mk(5, hin(5), Ah, Al),
                                                 mk(6, hin(6), Ah1, Al1));
        k_gemm_mfma<2, 0><<<gemm_blocks, 256, 0, stream>>>(
            Ah, Al, whi + wp(L, 5), wlo + wp(L, 5), whi + wp(L, 6), wlo + wp(L, 6),
            b + 5 * 128, b + 6 * 128, h + (size_t)0 * NN * 128);
        k_agg2<1><<<agg2_grid, 256, 0, stream>>>(mk(4, hin(4), Ah, Al),
                                                 mk(8, hin(8), Ah1, Al1));
        k_gemm_mfma<2, 1><<<gemm_blocks, 256, 0, stream>>>(
            Ah, Al, whi + wp(L, 4), wlo + wp(L, 4), whi + wp(L, 8), wlo + wp(L, 8),
            b + 4 * 128, b + 8 * 128, h + (size_t)1 * NN * 128);
        k_agg2<1><<<agg2_grid, 256, 0, stream>>>(mk(0, hin(0), Ah, Al),
                                                 mk(1, hin(1), Ah1, Al1));
        k_gemm_mfma<2, 1><<<gemm_blocks, 256, 0, stream>>>(
            Ah, Al, whi + wp(L, 0), wlo + wp(L, 0), whi + wp(L, 1), wlo + wp(L, 1),
            b + 0 * 128, b + 1 * 128, h + (size_t)2 * NN * 128);
        k_agg2<1><<<agg1_grid, 256, 0, stream>>>(mk(7, hin(7), Ah, Al),
                                                 mk(7, hin(7), Ah, Al));
        k_gemm_mfma<1, 0><<<gemm_blocks, 256, 0, stream>>>(
            Ah, Al, whi + wp(L, 7), wlo + wp(L, 7), whi + wp(L, 7), wlo + wp(L, 7),
            b + 7 * 128, b + 7 * 128, h + (size_t)2 * NN * 128);
    }

    // ---- classifier: out = relu(h2) @ Wc + bc ----
    k_classifier<<<(3 * NN + 63) / 64, 256, 0, stream>>>(h2, Wc, bc, (float*)d_out);
}

// Round 10
// 1274.183 us; speedup vs baseline: 1.1368x; 1.1274x over previous
//
#include <hip/hip_runtime.h>
#include <hip/hip_bf16.h>
#include <hip/hip_fp16.h>

// ---------------------------------------------------------------------------
// Hetero-GCN (3 node types, 9 relations), 2 GraphConv layers + classifier.
// Round 10:
//  - fp16 gather planes: x converted once (k_xprep); layer-1 GEMM epilogue
//    writes h1 as fp16. Gather volume halves (3.7 -> 1.85 GB). A/W stay
//    split-bf16, accumulation fp32.
//  - k_fill XCD-partitioned: relation r handled by blocks with bid%8==r
//    (rel 8 striped). Each esrc region written from one XCD -> scatter lines
//    merge in its private L2 (write amp 204 MB -> ~45 MB predicted).
//  - relation pairs reordered to share src planes where possible.
//  - k_agg2: 8-deep unroll.
// ---------------------------------------------------------------------------

#define NN 50000
#define EE 400000
#define NRG 2            // node ranges for histogram
#define RGN (NN / NRG)   // 25000 nodes per range
#define HCH 8            // edge chunks
#define HEG (EE / HCH)   // 50000 edges per chunk
#define FSL 192          // fill: slices per XCD slot
#define FR8 168          // fill: slices [FR8,FSL) handle relation 8

typedef __attribute__((ext_vector_type(8))) short bf16x8;
typedef __attribute__((ext_vector_type(4))) float f32x4;
#define MFMA16(a, b, c) __builtin_amdgcn_mfma_f32_16x16x32_bf16(a, b, c, 0, 0, 0)

// ---------------- degree histogram (chunked, LDS, no global atomics) --------
__global__ __launch_bounds__(256) void k_hist(const int* __restrict__ edges,
                                              unsigned* __restrict__ hist) {
    __shared__ unsigned bins[RGN / 2];  // 12500 u32 = 50 KB
    int bid = blockIdx.x;
    int task = bid >> 4;           // r*2 + side
    int rem = bid & 15;
    int rg = rem >> 3;
    int c = rem & 7;
    int r = task >> 1, side = task & 1;
    int tid = threadIdx.x;
    for (int i = tid; i < RGN / 2; i += 256) bins[i] = 0;
    __syncthreads();
    const int* ea = edges + (size_t)r * 2 * EE + (size_t)side * EE + (size_t)c * HEG;
    int base = rg * RGN;
    for (int e = tid; e < HEG; e += 256) {
        int idx = __builtin_nontemporal_load(&ea[e]) - base;
        if ((unsigned)idx < (unsigned)RGN)
            atomicAdd(&bins[idx >> 1], (idx & 1) ? 65536u : 1u);
    }
    __syncthreads();
    unsigned* ho = hist + ((size_t)(task * NRG + rg) * HCH + c) * (RGN / 2);
    for (int i = tid; i < RGN / 2; i += 256) ho[i] = bins[i];
}

// ---------------- reduce histograms -> ns, nd, deg_d ------------------------
__global__ void k_sums(const unsigned* __restrict__ hist, float* __restrict__ ns,
                       float* __restrict__ nd, int* __restrict__ deg_d) {
    int i = blockIdx.x * blockDim.x + threadIdx.x;
    if (i >= 9 * (NN / 2)) return;
    int r = i / (NN / 2);
    int ps = i - r * (NN / 2);
    int rg = ps / (RGN / 2);
    int slot = ps - rg * (RGN / 2);
    const unsigned* hs = hist + ((size_t)((r * 2 + 0) * NRG + rg) * HCH) * (RGN / 2) + slot;
    const unsigned* hd = hist + ((size_t)((r * 2 + 1) * NRG + rg) * HCH) * (RGN / 2) + slot;
    unsigned slo = 0, shi = 0, dlo = 0, dhi = 0;
#pragma unroll
    for (int c = 0; c < HCH; ++c) {
        unsigned a = hs[(size_t)c * (RGN / 2)];
        unsigned b = hd[(size_t)c * (RGN / 2)];
        slo += a & 0xffffu; shi += a >> 16;
        dlo += b & 0xffffu; dhi += b >> 16;
    }
    int n0 = 2 * ps;
    ns[r * NN + n0]     = slo ? rsqrtf((float)slo) : 0.f;
    ns[r * NN + n0 + 1] = shi ? rsqrtf((float)shi) : 0.f;
    nd[r * NN + n0]     = dlo ? rsqrtf((float)dlo) : 0.f;
    nd[r * NN + n0 + 1] = dhi ? rsqrtf((float)dhi) : 0.f;
    deg_d[r * NN + n0]     = (int)dlo;
    deg_d[r * NN + n0 + 1] = (int)dhi;
}

// ---------------- exclusive scan of in-degrees -> CSR offsets ---------------
__global__ __launch_bounds__(256) void k_offsets(const int* __restrict__ deg_d,
                                                 int* __restrict__ off,
                                                 int* __restrict__ cur) {
    __shared__ int wsum[4];
    __shared__ int s_carry;
    int r = blockIdx.x;
    const int* c = deg_d + r * NN;
    int* o = off + r * (NN + 1);
    int* cu = cur + r * NN;
    int tid = threadIdx.x, lane = tid & 63, w = tid >> 6;
    if (tid == 0) s_carry = 0;
    __syncthreads();
    for (int base = 0; base < NN; base += 256) {
        int i = base + tid;
        int v = (i < NN) ? c[i] : 0;
        int x = v;
#pragma unroll
        for (int s = 1; s < 64; s <<= 1) {
            int y = __shfl_up(x, (unsigned)s);
            if (lane >= s) x += y;
        }
        if (lane == 63) wsum[w] = x;
        __syncthreads();
        int wbase = 0;
#pragma unroll
        for (int j = 0; j < 3; ++j) wbase += (j < w) ? wsum[j] : 0;
        int excl = s_carry + wbase + x - v;
        if (i < NN) { o[i] = excl; cu[i] = excl; }
        __syncthreads();
        if (tid == 255) s_carry += wbase + x;
    }
    __syncthreads();
    if (tid == 0) o[NN] = s_carry;
}

// ---------------- CSR fill (XCD-partitioned scatter) -------------------------
// blockIdx%8 selects the XCD (round-robin dispatch heuristic). Relation r<8 is
// handled only by blocks on XCD r -> its esrc scatter lines merge in that
// XCD's private L2. Relation 8 is striped across all XCDs.
__global__ __launch_bounds__(256) void k_fill(const int* __restrict__ edges,
                                              int* __restrict__ cur,
                                              int* __restrict__ esrc) {
    int bid = blockIdx.x;          // 8 * FSL blocks
    int s = bid & 7;
    int t = bid >> 3;
    int r, chunk, nchunk;
    if (t < FR8) { r = s; chunk = t; nchunk = FR8; }
    else { r = 8; chunk = s + 8 * (t - FR8); nchunk = 8 * (FSL - FR8); }
    int per = (EE + nchunk - 1) / nchunk;
    int e0 = chunk * per;
    int e1 = min(EE, e0 + per);
    const int* es = edges + (size_t)r * 2 * EE;
    const int* ed = es + EE;
    int* cu = cur + r * NN;
    int* eo = esrc + (size_t)r * EE;
    for (int e = e0 + (int)threadIdx.x; e < e1; e += 256) {
        int src = __builtin_nontemporal_load(&es[e]);
        int dst = __builtin_nontemporal_load(&ed[e]);
        int pos = atomicAdd(&cu[dst], 1);
        eo[pos] = src;
    }
}

// ---------------- x -> fp16 conversion ---------------------------------------
__global__ void k_xprep(const float* __restrict__ x0, const float* __restrict__ x1,
                        const float* __restrict__ x2, __half* __restrict__ xh) {
    int i = blockIdx.x * blockDim.x + threadIdx.x;  // float4 index over 3*NN*32
    const int per = NN * 32;
    if (i >= 3 * per) return;
    int tsel = i / per;
    int o = i - tsel * per;
    const float* xp = (tsel == 0) ? x0 : ((tsel == 1) ? x1 : x2);
    float4 v = *reinterpret_cast<const float4*>(xp + (size_t)o * 4);
    __half* dst = xh + (size_t)tsel * NN * 128 + (size_t)o * 4;
    *reinterpret_cast<__half2*>(dst) = __floats2half2_rn(v.x, v.y);
    *reinterpret_cast<__half2*>(dst + 2) = __floats2half2_rn(v.z, v.w);
}

// ---------------- W prep: fp32 [K][N] -> chunk-major bf16 hi/lo planes ------
__global__ void k_wprep(const float* __restrict__ W1, const float* __restrict__ W2,
                        unsigned short* __restrict__ whi,
                        unsigned short* __restrict__ wlo) {
    int id = blockIdx.x * blockDim.x + threadIdx.x;
    const int total = 2 * 9 * 128 * 128;
    if (id >= total) return;
    int n = id & 127;
    int k = (id >> 7) & 127;
    int rl = id >> 14;  // layer*9 + r
    const float* W = (rl < 9) ? W1 : W2;
    int r = (rl < 9) ? rl : rl - 9;
    float f = W[((size_t)r * 128 + k) * 128 + n];
    unsigned u = __float_as_uint(f);
    unsigned hb = (u + 0x7fffu + ((u >> 16) & 1u)) & 0xffff0000u;
    float lo = f - __uint_as_float(hb);
    unsigned ul = __float_as_uint(lo);
    unsigned short l16 = (unsigned short)((ul + 0x7fffu + ((ul >> 16) & 1u)) >> 16);
    size_t oidx = (((size_t)rl * 4 + (k >> 5)) * 128 + n) * 32 + (k & 31);
    whi[oidx] = (unsigned short)(hb >> 16);
    wlo[oidx] = l16;
}

// ---------------- aggregation (CSR gather of fp16 rows) ----------------------
// One wave per dst row; 8-deep unrolled edge loop; emits bf16 hi/lo planes.
struct AggT {
    const __half* xin;
    const int* off;
    const int* esrc;
    const float* ns;
    const float* nd;
    unsigned short* Ah;
    unsigned short* Al;
};

template <int RELU>
__global__ __launch_bounds__(256) void k_agg2(AggT ta, AggT tb) {
    AggT t = (blockIdx.y == 0) ? ta : tb;
    int wave = (blockIdx.x * blockDim.x + threadIdx.x) >> 6;
    int lane = threadIdx.x & 63;
    if (wave >= NN) return;
    int e0 = t.off[wave], e1 = t.off[wave + 1];
    const __half* xin = t.xin;
    const int* esrc = t.esrc;
    const float* ns = t.ns;
    float a0 = 0.f, a1 = 0.f, b0 = 0.f, b1 = 0.f;
    float c0 = 0.f, c1 = 0.f, d0 = 0.f, d1 = 0.f;
    int e = e0;
    for (; e + 8 <= e1; e += 8) {
        int s0 = esrc[e], s1 = esrc[e + 1], s2 = esrc[e + 2], s3 = esrc[e + 3];
        int s4 = esrc[e + 4], s5 = esrc[e + 5], s6 = esrc[e + 6], s7 = esrc[e + 7];
        float w0 = ns[s0], w1 = ns[s1], w2 = ns[s2], w3 = ns[s3];
        float w4 = ns[s4], w5 = ns[s5], w6 = ns[s6], w7 = ns[s7];
        float2 v0 = __half22float2(*reinterpret_cast<const __half2*>(xin + (size_t)s0 * 128 + lane * 2));
        float2 v1 = __half22float2(*reinterpret_cast<const __half2*>(xin + (size_t)s1 * 128 + lane * 2));
        float2 v2 = __half22float2(*reinterpret_cast<const __half2*>(xin + (size_t)s2 * 128 + lane * 2));
        float2 v3 = __half22float2(*reinterpret_cast<const __half2*>(xin + (size_t)s3 * 128 + lane * 2));
        float2 v4 = __half22float2(*reinterpret_cast<const __half2*>(xin + (size_t)s4 * 128 + lane * 2));
        float2 v5 = __half22float2(*reinterpret_cast<const __half2*>(xin + (size_t)s5 * 128 + lane * 2));
        float2 v6 = __half22float2(*reinterpret_cast<const __half2*>(xin + (size_t)s6 * 128 + lane * 2));
        float2 v7 = __half22float2(*reinterpret_cast<const __half2*>(xin + (size_t)s7 * 128 + lane * 2));
        if (RELU) {
            v0.x = fmaxf(v0.x, 0.f); v0.y = fmaxf(v0.y, 0.f);
            v1.x = fmaxf(v1.x, 0.f); v1.y = fmaxf(v1.y, 0.f);
            v2.x = fmaxf(v2.x, 0.f); v2.y = fmaxf(v2.y, 0.f);
            v3.x = fmaxf(v3.x, 0.f); v3.y = fmaxf(v3.y, 0.f);
            v4.x = fmaxf(v4.x, 0.f); v4.y = fmaxf(v4.y, 0.f);
            v5.x = fmaxf(v5.x, 0.f); v5.y = fmaxf(v5.y, 0.f);
            v6.x = fmaxf(v6.x, 0.f); v6.y = fmaxf(v6.y, 0.f);
            v7.x = fmaxf(v7.x, 0.f); v7.y = fmaxf(v7.y, 0.f);
        }
        a0 = fmaf(w0, v0.x, a0); a1 = fmaf(w0, v0.y, a1);
        b0 = fmaf(w1, v1.x, b0); b1 = fmaf(w1, v1.y, b1);
        c0 = fmaf(w2, v2.x, c0); c1 = fmaf(w2, v2.y, c1);
        d0 = fmaf(w3, v3.x, d0); d1 = fmaf(w3, v3.y, d1);
        a0 = fmaf(w4, v4.x, a0); a1 = fmaf(w4, v4.y, a1);
        b0 = fmaf(w5, v5.x, b0); b1 = fmaf(w5, v5.y, b1);
        c0 = fmaf(w6, v6.x, c0); c1 = fmaf(w6, v6.y, c1);
        d0 = fmaf(w7, v7.x, d0); d1 = fmaf(w7, v7.y, d1);
    }
    if (e + 4 <= e1) {
        int s0 = esrc[e], s1 = esrc[e + 1], s2 = esrc[e + 2], s3 = esrc[e + 3];
        float w0 = ns[s0], w1 = ns[s1], w2 = ns[s2], w3 = ns[s3];
        float2 v0 = __half22float2(*reinterpret_cast<const __half2*>(xin + (size_t)s0 * 128 + lane * 2));
        float2 v1 = __half22float2(*reinterpret_cast<const __half2*>(xin + (size_t)s1 * 128 + lane * 2));
        float2 v2 = __half22float2(*reinterpret_cast<const __half2*>(xin + (size_t)s2 * 128 + lane * 2));
        float2 v3 = __half22float2(*reinterpret_cast<const __half2*>(xin + (size_t)s3 * 128 + lane * 2));
        if (RELU) {
            v0.x = fmaxf(v0.x, 0.f); v0.y = fmaxf(v0.y, 0.f);
            v1.x = fmaxf(v1.x, 0.f); v1.y = fmaxf(v1.y, 0.f);
            v2.x = fmaxf(v2.x, 0.f); v2.y = fmaxf(v2.y, 0.f);
            v3.x = fmaxf(v3.x, 0.f); v3.y = fmaxf(v3.y, 0.f);
        }
        a0 = fmaf(w0, v0.x, a0); a1 = fmaf(w0, v0.y, a1);
        b0 = fmaf(w1, v1.x, b0); b1 = fmaf(w1, v1.y, b1);
        c0 = fmaf(w2, v2.x, c0); c1 = fmaf(w2, v2.y, c1);
        d0 = fmaf(w3, v3.x, d0); d1 = fmaf(w3, v3.y, d1);
        e += 4;
    }
    for (; e < e1; ++e) {
        int s = esrc[e];
        float w = ns[s];
        float2 v = __half22float2(*reinterpret_cast<const __half2*>(xin + (size_t)s * 128 + lane * 2));
        if (RELU) { v.x = fmaxf(v.x, 0.f); v.y = fmaxf(v.y, 0.f); }
        a0 = fmaf(w, v.x, a0); a1 = fmaf(w, v.y, a1);
    }
    float nr = t.nd[wave];
    float r0 = ((a0 + b0) + (c0 + d0)) * nr;
    float r1 = ((a1 + b1) + (c1 + d1)) * nr;
    // split-bf16: hi = rn(v), lo = rn(v - hi)
    unsigned u0 = __float_as_uint(r0);
    unsigned h0b = (u0 + 0x7fffu + ((u0 >> 16) & 1u)) & 0xffff0000u;
    unsigned ul0 = __float_as_uint(r0 - __uint_as_float(h0b));
    unsigned u1 = __float_as_uint(r1);
    unsigned h1b = (u1 + 0x7fffu + ((u1 >> 16) & 1u)) & 0xffff0000u;
    unsigned ul1 = __float_as_uint(r1 - __uint_as_float(h1b));
    ushort2 hv, lv;
    hv.x = (unsigned short)(h0b >> 16);
    hv.y = (unsigned short)(h1b >> 16);
    lv.x = (unsigned short)((ul0 + 0x7fffu + ((ul0 >> 16) & 1u)) >> 16);
    lv.y = (unsigned short)((ul1 + 0x7fffu + ((ul1 >> 16) & 1u)) >> 16);
    *reinterpret_cast<ushort2*>(t.Ah + (size_t)wave * 128 + lane * 2) = hv;
    *reinterpret_cast<ushort2*>(t.Al + (size_t)wave * 128 + lane * 2) = lv;
}

// ---------------- MFMA GEMM: H (=|+=) sum_s A_s @ W_s + bias ----------------
__device__ __forceinline__ float ld_val(const float* p) { return *p; }
__device__ __forceinline__ float ld_val(const __half* p) { return __half2float(*p); }
__device__ __forceinline__ void st_val(float* p, float v) { *p = v; }
__device__ __forceinline__ void st_val(__half* p, float v) { *p = __float2half_rn(v); }

template <int NS, int STORE, typename TH>
__global__ __launch_bounds__(256) void k_gemm_mfma(
    const unsigned short* __restrict__ Ah, const unsigned short* __restrict__ Al,
    const unsigned short* __restrict__ wha, const unsigned short* __restrict__ wla,
    const unsigned short* __restrict__ whb, const unsigned short* __restrict__ wlb,
    const float* __restrict__ ba, const float* __restrict__ bb,
    TH* __restrict__ H) {
    int tid = threadIdx.x;
    int w = tid >> 6, lane = tid & 63;
    int row0 = blockIdx.x * 64;
    int colbase = w * 32;
    int r16 = lane & 15;
    int koff = (lane >> 4) * 8;

    f32x4 acc[4][2];
#pragma unroll
    for (int rt = 0; rt < 4; ++rt)
#pragma unroll
        for (int nt = 0; nt < 2; ++nt)
            acc[rt][nt] = f32x4{0.f, 0.f, 0.f, 0.f};

#pragma unroll
    for (int s = 0; s < NS; ++s) {
        const unsigned short* A_h = Ah + (size_t)s * NN * 128;
        const unsigned short* A_l = Al + (size_t)s * NN * 128;
        const unsigned short* w_h = (s == 0) ? wha : whb;
        const unsigned short* w_l = (s == 0) ? wla : wlb;
#pragma unroll
        for (int c = 0; c < 4; ++c) {
            int kbase = c * 32 + koff;
            bf16x8 ah[4], al[4], bh[2], bl[2];
#pragma unroll
            for (int rt = 0; rt < 4; ++rt) {
                int rr = rt * 16 + r16;
                int rc = (row0 + rr < NN) ? rr : 0;
                ah[rt] = *reinterpret_cast<const bf16x8*>(
                    A_h + ((size_t)(row0 + rc)) * 128 + kbase);
                al[rt] = *reinterpret_cast<const bf16x8*>(
                    A_l + ((size_t)(row0 + rc)) * 128 + kbase);
            }
#pragma unroll
            for (int nt = 0; nt < 2; ++nt) {
                int col = colbase + nt * 16 + r16;
                size_t widx = ((size_t)c * 128 + col) * 32 + koff;
                bh[nt] = *reinterpret_cast<const bf16x8*>(w_h + widx);
                bl[nt] = *reinterpret_cast<const bf16x8*>(w_l + widx);
            }
#pragma unroll
            for (int rt = 0; rt < 4; ++rt)
#pragma unroll
                for (int nt = 0; nt < 2; ++nt) {
                    acc[rt][nt] = MFMA16(ah[rt], bh[nt], acc[rt][nt]);
                    acc[rt][nt] = MFMA16(ah[rt], bl[nt], acc[rt][nt]);
                    acc[rt][nt] = MFMA16(al[rt], bh[nt], acc[rt][nt]);
                }
        }
    }

    int orow = (lane >> 4) * 4;
#pragma unroll
    for (int nt = 0; nt < 2; ++nt) {
        int col = colbase + nt * 16 + r16;
        float bias = ba[col];
        if (NS == 2) bias += bb[col];
#pragma unroll
        for (int rt = 0; rt < 4; ++rt) {
#pragma unroll
            for (int j = 0; j < 4; ++j) {
                int grow = row0 + rt * 16 + orow + j;
                if (grow < NN) {
                    TH* hp = H + (size_t)grow * 128 + col;
                    float v = acc[rt][nt][j] + bias;
                    if (!STORE) v += ld_val(hp);
                    st_val(hp, v);
                }
            }
        }
    }
}

// ---------------- classifier: out = relu(H) @ Wc + bc -----------------------
__global__ __launch_bounds__(256) void k_classifier(const float* __restrict__ H,
                                                    const float* __restrict__ Wc,
                                                    const float* __restrict__ bc,
                                                    float* __restrict__ out) {
    __shared__ float sW[128 * 16];
    __shared__ float sb[16];
    int tid = threadIdx.x;
#pragma unroll
    for (int i = tid; i < 2048; i += 256) sW[i] = Wc[i];
    if (tid < 16) sb[tid] = bc[tid];
    __syncthreads();
    int node = blockIdx.x * 64 + (tid >> 2);
    if (node >= 3 * NN) return;
    int cg = (tid & 3) << 2;
    const float* h = H + (size_t)node * 128;
    float acc0 = 0.f, acc1 = 0.f, acc2 = 0.f, acc3 = 0.f;
#pragma unroll 4
    for (int k0 = 0; k0 < 128; k0 += 4) {
        float4 a4 = *reinterpret_cast<const float4*>(h + k0);
        float a;
        a = fmaxf(a4.x, 0.f);
        { float4 wv = *reinterpret_cast<const float4*>(&sW[(k0 + 0) * 16 + cg]);
          acc0 = fmaf(a, wv.x, acc0); acc1 = fmaf(a, wv.y, acc1);
          acc2 = fmaf(a, wv.z, acc2); acc3 = fmaf(a, wv.w, acc3); }
        a = fmaxf(a4.y, 0.f);
        { float4 wv = *reinterpret_cast<const float4*>(&sW[(k0 + 1) * 16 + cg]);
          acc0 = fmaf(a, wv.x, acc0); acc1 = fmaf(a, wv.y, acc1);
          acc2 = fmaf(a, wv.z, acc2); acc3 = fmaf(a, wv.w, acc3); }
        a = fmaxf(a4.z, 0.f);
        { float4 wv = *reinterpret_cast<const float4*>(&sW[(k0 + 2) * 16 + cg]);
          acc0 = fmaf(a, wv.x, acc0); acc1 = fmaf(a, wv.y, acc1);
          acc2 = fmaf(a, wv.z, acc2); acc3 = fmaf(a, wv.w, acc3); }
        a = fmaxf(a4.w, 0.f);
        { float4 wv = *reinterpret_cast<const float4*>(&sW[(k0 + 3) * 16 + cg]);
          acc0 = fmaf(a, wv.x, acc0); acc1 = fmaf(a, wv.y, acc1);
          acc2 = fmaf(a, wv.z, acc2); acc3 = fmaf(a, wv.w, acc3); }
    }
    float4 o = make_float4(acc0 + sb[cg], acc1 + sb[cg + 1],
                           acc2 + sb[cg + 2], acc3 + sb[cg + 3]);
    *reinterpret_cast<float4*>(out + (size_t)node * 16 + cg) = o;
}

// ---------------------------------------------------------------------------
extern "C" void kernel_launch(void* const* d_in, const int* in_sizes, int n_in,
                              void* d_out, int out_size, void* d_ws, size_t ws_size,
                              hipStream_t stream) {
    const float* x0 = (const float*)d_in[0];
    const float* x1 = (const float*)d_in[1];
    const float* x2 = (const float*)d_in[2];
    const float* W1 = (const float*)d_in[3];
    const float* b1 = (const float*)d_in[4];
    const float* W2 = (const float*)d_in[5];
    const float* b2 = (const float*)d_in[6];
    const float* Wc = (const float*)d_in[7];
    const float* bc = (const float*)d_in[8];
    const int* edges = (const int*)d_in[9];

    const int REL_S[9] = {0, 1, 1, 0, 2, 2, 0, 2, 1};

    // ---- workspace carve-up with overlays (~227 MB peak) ----
    char* p = (char*)d_ws;
    auto alloc = [&](size_t bytes) -> void* {
        void* r = (void*)p;
        p += (bytes + 255) & ~(size_t)255;
        return r;
    };
    float* h2 = (float*)alloc((size_t)3 * NN * 128 * sizeof(float));  // 76.8 MB
    // aliases inside h2 (all dead before first h2 write at layer-2 GEMM):
    unsigned* hist = (unsigned*)h2;                    // 14.4 MB, dead after k_sums
    int* cur = (int*)h2 + 4 * 1024 * 1024;             // 1.8 MB, dead after k_fill
    int* deg_d = cur + 9 * NN;                         // 1.8 MB, dead after k_offsets
    __half* xh  = (__half*)alloc((size_t)3 * NN * 128 * sizeof(__half));  // 38.4 MB
    __half* h1h = (__half*)alloc((size_t)3 * NN * 128 * sizeof(__half));  // 38.4 MB
    unsigned short* Ah = (unsigned short*)alloc((size_t)2 * NN * 128 * 2);  // 25.6 MB
    unsigned short* Al = (unsigned short*)alloc((size_t)2 * NN * 128 * 2);  // 25.6 MB
    int* off = (int*)alloc((size_t)9 * (NN + 1) * sizeof(int));
    float* ns = (float*)alloc((size_t)9 * NN * sizeof(float));
    float* nd = (float*)alloc((size_t)9 * NN * sizeof(float));
    int* esrc = (int*)alloc((size_t)9 * EE * sizeof(int));            // 14.4 MB
    unsigned short* whi = (unsigned short*)alloc((size_t)2 * 9 * 128 * 128 * 2);
    unsigned short* wlo = (unsigned short*)alloc((size_t)2 * 9 * 128 * 128 * 2);
    unsigned short* Ah1 = Ah + (size_t)NN * 128;
    unsigned short* Al1 = Al + (size_t)NN * 128;
    const __half* xph[3] = {xh, xh + (size_t)NN * 128, xh + (size_t)2 * NN * 128};

    // ---- CSR build + input/weight prep (reused by both layers) ----
    k_hist<<<288, 256, 0, stream>>>(edges, hist);
    k_xprep<<<(3 * NN * 32 + 255) / 256, 256, 0, stream>>>(x0, x1, x2, xh);
    k_sums<<<(9 * (NN / 2) + 255) / 256, 256, 0, stream>>>(hist, ns, nd, deg_d);
    k_offsets<<<9, 256, 0, stream>>>(deg_d, off, cur);
    k_fill<<<8 * FSL, 256, 0, stream>>>(edges, cur, esrc);
    k_wprep<<<(2 * 9 * 128 * 128 + 255) / 256, 256, 0, stream>>>(W1, W2, whi, wlo);

    const dim3 agg2_grid(12500, 2);
    const dim3 agg1_grid(12500, 1);
    const int gemm_blocks = (NN + 63) / 64;   // 782

    auto mk = [&](int r, const __half* xin, unsigned short* ah, unsigned short* al) -> AggT {
        return AggT{xin, off + r * (NN + 1), esrc + (size_t)r * EE,
                    ns + r * NN, nd + r * NN, ah, al};
    };
    auto wp = [&](int layer, int r) { return (size_t)(layer * 9 + r) * 16384; };

    // pairs reordered so (3,6) share src plane x0.
    // ======== layer 1 (inputs xh fp16, no relu) -> h1h fp16 ========
    {
        const float* b = b1; const int L = 0;
        k_agg2<0><<<agg2_grid, 256, 0, stream>>>(mk(3, xph[REL_S[3]], Ah, Al),
                                                 mk(6, xph[REL_S[6]], Ah1, Al1));
        k_gemm_mfma<2, 1, __half><<<gemm_blocks, 256, 0, stream>>>(
            Ah, Al, whi + wp(L, 3), wlo + wp(L, 3), whi + wp(L, 6), wlo + wp(L, 6),
            b + 3 * 128, b + 6 * 128, h1h + (size_t)0 * NN * 128);
        k_agg2<0><<<agg2_grid, 256, 0, stream>>>(mk(2, xph[REL_S[2]], Ah, Al),
                                                 mk(5, xph[REL_S[5]], Ah1, Al1));
        k_gemm_mfma<2, 0, __half><<<gemm_blocks, 256, 0, stream>>>(
            Ah, Al, whi + wp(L, 2), wlo + wp(L, 2), whi + wp(L, 5), wlo + wp(L, 5),
            b + 2 * 128, b + 5 * 128, h1h + (size_t)0 * NN * 128);
        k_agg2<0><<<agg2_grid, 256, 0, stream>>>(mk(4, xph[REL_S[4]], Ah, Al),
                                                 mk(8, xph[REL_S[8]], Ah1, Al1));
        k_gemm_mfma<2, 1, __half><<<gemm_blocks, 256, 0, stream>>>(
            Ah, Al, whi + wp(L, 4), wlo + wp(L, 4), whi + wp(L, 8), wlo + wp(L, 8),
            b + 4 * 128, b + 8 * 128, h1h + (size_t)1 * NN * 128);
        k_agg2<0><<<agg2_grid, 256, 0, stream>>>(mk(0, xph[REL_S[0]], Ah, Al),
                                                 mk(1, xph[REL_S[1]], Ah1, Al1));
        k_gemm_mfma<2, 1, __half><<<gemm_blocks, 256, 0, stream>>>(
            Ah, Al, whi + wp(L, 0), wlo + wp(L, 0), whi + wp(L, 1), wlo + wp(L, 1),
            b + 0 * 128, b + 1 * 128, h1h + (size_t)2 * NN * 128);
        k_agg2<0><<<agg1_grid, 256, 0, stream>>>(mk(7, xph[REL_S[7]], Ah, Al),
                                                 mk(7, xph[REL_S[7]], Ah, Al));
        k_gemm_mfma<1, 0, __half><<<gemm_blocks, 256, 0, stream>>>(
            Ah, Al, whi + wp(L, 7), wlo + wp(L, 7), whi + wp(L, 7), wlo + wp(L, 7),
            b + 7 * 128, b + 7 * 128, h1h + (size_t)2 * NN * 128);
    }

    // ======== layer 2 (inputs relu(h1h) fp16, folded into gather) -> h2 fp32 ==
    {
        const float* b = b2; const int L = 1;
        auto hin = [&](int r) { return (const __half*)(h1h + (size_t)REL_S[r] * NN * 128); };
        k_agg2<1><<<agg2_grid, 256, 0, stream>>>(mk(3, hin(3), Ah, Al),
                                                 mk(6, hin(6), Ah1, Al1));
        k_gemm_mfma<2, 1, float><<<gemm_blocks, 256, 0, stream>>>(
            Ah, Al, whi + wp(L, 3), wlo + wp(L, 3), whi + wp(L, 6), wlo + wp(L, 6),
            b + 3 * 128, b + 6 * 128, h2 + (size_t)0 * NN * 128);
        k_agg2<1><<<agg2_grid, 256, 0, stream>>>(mk(2, hin(2), Ah, Al),
                                                 mk(5, hin(5), Ah1, Al1));
        k_gemm_mfma<2, 0, float><<<gemm_blocks, 256, 0, stream>>>(
            Ah, Al, whi + wp(L, 2), wlo + wp(L, 2), whi + wp(L, 5), wlo + wp(L, 5),
            b + 2 * 128, b + 5 * 128, h2 + (size_t)0 * NN * 128);
        k_agg2<1><<<agg2_grid, 256, 0, stream>>>(mk(4, hin(4), Ah, Al),
                                                 mk(8, hin(8), Ah1, Al1));
        k_gemm_mfma<2, 1, float><<<gemm_blocks, 256, 0, stream>>>(
            Ah, Al, whi + wp(L, 4), wlo + wp(L, 4), whi + wp(L, 8), wlo + wp(L, 8),
            b + 4 * 128, b + 8 * 128, h2 + (size_t)1 * NN * 128);
        k_agg2<1><<<agg2_grid, 256, 0, stream>>>(mk(0, hin(0), Ah, Al),
                                                 mk(1, hin(1), Ah1, Al1));
        k_gemm_mfma<2, 1, float><<<gemm_blocks, 256, 0, stream>>>(
            Ah, Al, whi + wp(L, 0), wlo + wp(L, 0), whi + wp(L, 1), wlo + wp(L, 1),
            b + 0 * 128, b + 1 * 128, h2 + (size_t)2 * NN * 128);
        k_agg2<1><<<agg1_grid, 256, 0, stream>>>(mk(7, hin(7), Ah, Al),
                                                 mk(7, hin(7), Ah, Al));
        k_gemm_mfma<1, 0, float><<<gemm_blocks, 256, 0, stream>>>(
            Ah, Al, whi + wp(L, 7), wlo + wp(L, 7), whi + wp(L, 7), wlo + wp(L, 7),
            b + 7 * 128, b + 7 * 128, h2 + (size_t)2 * NN * 128);
    }

    // ---- classifier: out = relu(h2) @ Wc + bc ----
    k_classifier<<<(3 * NN + 63) / 64, 256, 0, stream>>>(h2, Wc, bc, (float*)d_out);
}

// Round 11
// 1148.020 us; speedup vs baseline: 1.2617x; 1.1099x over previous
//
#include <hip/hip_runtime.h>
#include <hip/hip_bf16.h>
#include <hip/hip_fp16.h>

// ---------------------------------------------------------------------------
// Hetero-GCN (3 node types, 9 relations), 2 GraphConv layers + classifier.
// Round 11:
//  - CSR fill rewritten as 2-pass bucketed scatter (kills the 204MB line-
//    granular write amplification of the single-pass random scatter):
//    pass1 k_bucket: LDS-staged bucket sort per 8192-edge chunk, contiguous
//    run flushes; pass2 k_scatter: per-bucket LDS scatter + coalesced out.
//    Round-10 lesson: blockIdx%8 XCD affinity is unreliable; instead make
//    each line's writers a single block.
//  - agg (fp16 gather, split-bf16 A planes), MFMA GEMM, classifier unchanged.
// ---------------------------------------------------------------------------

#define NN 50000
#define EE 400000
#define NRG 2            // node ranges for histogram
#define RGN (NN / NRG)   // 25000 nodes per range
#define HCH 8            // edge chunks
#define HEG (EE / HCH)   // 50000 edges per chunk
#define NBK 98           // dst buckets (dst>>9)
#define BKW 512          // dsts per bucket
#define CH1 8192         // pass-1 edges per chunk
#define NCH ((EE + CH1 - 1) / CH1)   // 49
#define SCAP 6656        // pass-2 LDS segment capacity (mean 4096, sd 64)

typedef __attribute__((ext_vector_type(8))) short bf16x8;
typedef __attribute__((ext_vector_type(4))) float f32x4;
#define MFMA16(a, b, c) __builtin_amdgcn_mfma_f32_16x16x32_bf16(a, b, c, 0, 0, 0)

// ---------------- degree histogram (chunked, LDS, no global atomics) --------
__global__ __launch_bounds__(256) void k_hist(const int* __restrict__ edges,
                                              unsigned* __restrict__ hist) {
    __shared__ unsigned bins[RGN / 2];  // 12500 u32 = 50 KB
    int bid = blockIdx.x;
    int task = bid >> 4;           // r*2 + side
    int rem = bid & 15;
    int rg = rem >> 3;
    int c = rem & 7;
    int r = task >> 1, side = task & 1;
    int tid = threadIdx.x;
    for (int i = tid; i < RGN / 2; i += 256) bins[i] = 0;
    __syncthreads();
    const int* ea = edges + (size_t)r * 2 * EE + (size_t)side * EE + (size_t)c * HEG;
    int base = rg * RGN;
    for (int e = tid; e < HEG; e += 256) {
        int idx = __builtin_nontemporal_load(&ea[e]) - base;
        if ((unsigned)idx < (unsigned)RGN)
            atomicAdd(&bins[idx >> 1], (idx & 1) ? 65536u : 1u);
    }
    __syncthreads();
    unsigned* ho = hist + ((size_t)(task * NRG + rg) * HCH + c) * (RGN / 2);
    for (int i = tid; i < RGN / 2; i += 256) ho[i] = bins[i];
}

// ---------------- reduce histograms -> ns, nd, deg_d ------------------------
__global__ void k_sums(const unsigned* __restrict__ hist, float* __restrict__ ns,
                       float* __restrict__ nd, int* __restrict__ deg_d) {
    int i = blockIdx.x * blockDim.x + threadIdx.x;
    if (i >= 9 * (NN / 2)) return;
    int r = i / (NN / 2);
    int ps = i - r * (NN / 2);
    int rg = ps / (RGN / 2);
    int slot = ps - rg * (RGN / 2);
    const unsigned* hs = hist + ((size_t)((r * 2 + 0) * NRG + rg) * HCH) * (RGN / 2) + slot;
    const unsigned* hd = hist + ((size_t)((r * 2 + 1) * NRG + rg) * HCH) * (RGN / 2) + slot;
    unsigned slo = 0, shi = 0, dlo = 0, dhi = 0;
#pragma unroll
    for (int c = 0; c < HCH; ++c) {
        unsigned a = hs[(size_t)c * (RGN / 2)];
        unsigned b = hd[(size_t)c * (RGN / 2)];
        slo += a & 0xffffu; shi += a >> 16;
        dlo += b & 0xffffu; dhi += b >> 16;
    }
    int n0 = 2 * ps;
    ns[r * NN + n0]     = slo ? rsqrtf((float)slo) : 0.f;
    ns[r * NN + n0 + 1] = shi ? rsqrtf((float)shi) : 0.f;
    nd[r * NN + n0]     = dlo ? rsqrtf((float)dlo) : 0.f;
    nd[r * NN + n0 + 1] = dhi ? rsqrtf((float)dhi) : 0.f;
    deg_d[r * NN + n0]     = (int)dlo;
    deg_d[r * NN + n0 + 1] = (int)dhi;
}

// ---------------- exclusive scan of in-degrees -> CSR offsets ---------------
// also seeds per-bucket global cursors gcur[r][b] = off[r][b*BKW]
__global__ __launch_bounds__(256) void k_offsets(const int* __restrict__ deg_d,
                                                 int* __restrict__ off,
                                                 int* __restrict__ gcur) {
    __shared__ int wsum[4];
    __shared__ int s_carry;
    int r = blockIdx.x;
    const int* c = deg_d + r * NN;
    int* o = off + r * (NN + 1);
    int tid = threadIdx.x, lane = tid & 63, w = tid >> 6;
    if (tid == 0) s_carry = 0;
    __syncthreads();
    for (int base = 0; base < NN; base += 256) {
        int i = base + tid;
        int v = (i < NN) ? c[i] : 0;
        int x = v;
#pragma unroll
        for (int s = 1; s < 64; s <<= 1) {
            int y = __shfl_up(x, (unsigned)s);
            if (lane >= s) x += y;
        }
        if (lane == 63) wsum[w] = x;
        __syncthreads();
        int wbase = 0;
#pragma unroll
        for (int j = 0; j < 3; ++j) wbase += (j < w) ? wsum[j] : 0;
        int excl = s_carry + wbase + x - v;
        if (i < NN) o[i] = excl;
        __syncthreads();
        if (tid == 255) s_carry += wbase + x;
    }
    __syncthreads();
    if (tid == 0) o[NN] = s_carry;
    // seed bucket cursors (global writes by this block are visible after the
    // barrier: __syncthreads implies vmcnt(0) drain before s_barrier)
    for (int b = tid; b < NBK; b += 256) {
        int d = b * BKW; if (d > NN) d = NN;
        gcur[r * NBK + b] = o[d];
    }
}

// ---------------- pass 1: bucket edges by dst>>9, packed u32 ----------------
// grid: 9 rel x NCH chunks. Writes bucket-sorted (dst<<16|src) runs into
// bpairs at per-bucket cursors (contiguous runs -> line-merged writes).
__global__ __launch_bounds__(256) void k_bucket(const int* __restrict__ edges,
                                                int* __restrict__ gcur,
                                                unsigned* __restrict__ bpairs) {
    __shared__ int hist[NBK];
    __shared__ int sc[128];
    __shared__ int lofs[NBK + 1];
    __shared__ int lcur[NBK];
    __shared__ int gbase[NBK];
    __shared__ unsigned stage[CH1];
    int bid = blockIdx.x;
    int r = bid / NCH, c = bid - r * NCH;
    int tid = threadIdx.x;
    int e0 = c * CH1;
    int e1 = min(EE, e0 + CH1);
    int n = e1 - e0;
    const int* es = edges + (size_t)r * 2 * EE;
    const int* ed = es + EE;

    for (int i = tid; i < NBK; i += 256) hist[i] = 0;
    __syncthreads();
    for (int e = e0 + tid; e < e1; e += 256)
        atomicAdd(&hist[ed[e] >> 9], 1);
    __syncthreads();
    // inclusive Hillis-Steele scan over 128 (padded)
    if (tid < 128) sc[tid] = (tid < NBK) ? hist[tid] : 0;
    __syncthreads();
#pragma unroll
    for (int s = 1; s < 128; s <<= 1) {
        int t = 0;
        if (tid < 128 && tid >= s) t = sc[tid - s];
        __syncthreads();
        if (tid < 128 && tid >= s) sc[tid] += t;
        __syncthreads();
    }
    if (tid < NBK) {
        int ex = sc[tid] - hist[tid];
        lofs[tid] = ex;
        lcur[tid] = ex;
        gbase[tid] = atomicAdd(&gcur[r * NBK + tid], hist[tid]);
    }
    if (tid == 0) lofs[NBK] = n;
    __syncthreads();
    // stage bucket-sorted
    for (int e = e0 + tid; e < e1; e += 256) {
        int dst = ed[e];
        int src = es[e];
        int p = atomicAdd(&lcur[dst >> 9], 1);
        stage[p] = ((unsigned)dst << 16) | (unsigned)src;
    }
    __syncthreads();
    // flush contiguous runs
    unsigned* bp = bpairs + (size_t)r * EE;
    for (int i = tid; i < n; i += 256) {
        int lo = 0, hi = NBK;
        while (hi - lo > 1) {
            int m = (lo + hi) >> 1;
            if (lofs[m] <= i) lo = m; else hi = m;
        }
        bp[gbase[lo] + (i - lofs[lo])] = stage[i];
    }
}

// ---------------- pass 2: per-bucket LDS scatter -> coalesced esrc ----------
// grid: 9 rel x NBK buckets; each block owns one contiguous CSR segment.
__global__ __launch_bounds__(256) void k_scatter(const unsigned* __restrict__ bpairs,
                                                 const int* __restrict__ off,
                                                 int* __restrict__ esrc) {
    __shared__ int lcur[BKW];
    __shared__ int lout[SCAP];
    int bid = blockIdx.x;
    int r = bid / NBK, b = bid - r * NBK;
    int tid = threadIdx.x;
    int d0 = b * BKW;
    int d1 = min(NN, d0 + BKW);
    const int* o = off + r * (NN + 1);
    int s0 = o[d0], s1 = o[d1];
    int n = s1 - s0;
    for (int i = tid; i < d1 - d0; i += 256) lcur[i] = o[d0 + i] - s0;
    __syncthreads();
    const unsigned* bp = bpairs + (size_t)r * EE + s0;
    int* out = esrc + (size_t)r * EE + s0;
    if (n <= SCAP) {
        for (int i = tid; i < n; i += 256) {
            unsigned pr = bp[i];
            int dst = (int)(pr >> 16), src = (int)(pr & 0xffffu);
            int p = atomicAdd(&lcur[dst - d0], 1);
            lout[p] = src;
        }
        __syncthreads();
        for (int i = tid; i < n; i += 256) out[i] = lout[i];
    } else {  // safety fallback (statistically unreachable)
        for (int i = tid; i < n; i += 256) {
            unsigned pr = bp[i];
            int dst = (int)(pr >> 16), src = (int)(pr & 0xffffu);
            int p = atomicAdd(&lcur[dst - d0], 1);
            out[p] = src;
        }
    }
}

// ---------------- x -> fp16 conversion ---------------------------------------
__global__ void k_xprep(const float* __restrict__ x0, const float* __restrict__ x1,
                        const float* __restrict__ x2, __half* __restrict__ xh) {
    int i = blockIdx.x * blockDim.x + threadIdx.x;  // float4 index over 3*NN*32
    const int per = NN * 32;
    if (i >= 3 * per) return;
    int tsel = i / per;
    int o = i - tsel * per;
    const float* xp = (tsel == 0) ? x0 : ((tsel == 1) ? x1 : x2);
    float4 v = *reinterpret_cast<const float4*>(xp + (size_t)o * 4);
    __half* dst = xh + (size_t)tsel * NN * 128 + (size_t)o * 4;
    *reinterpret_cast<__half2*>(dst) = __floats2half2_rn(v.x, v.y);
    *reinterpret_cast<__half2*>(dst + 2) = __floats2half2_rn(v.z, v.w);
}

// ---------------- W prep: fp32 [K][N] -> chunk-major bf16 hi/lo planes ------
__global__ void k_wprep(const float* __restrict__ W1, const float* __restrict__ W2,
                        unsigned short* __restrict__ whi,
                        unsigned short* __restrict__ wlo) {
    int id = blockIdx.x * blockDim.x + threadIdx.x;
    const int total = 2 * 9 * 128 * 128;
    if (id >= total) return;
    int n = id & 127;
    int k = (id >> 7) & 127;
    int rl = id >> 14;  // layer*9 + r
    const float* W = (rl < 9) ? W1 : W2;
    int r = (rl < 9) ? rl : rl - 9;
    float f = W[((size_t)r * 128 + k) * 128 + n];
    unsigned u = __float_as_uint(f);
    unsigned hb = (u + 0x7fffu + ((u >> 16) & 1u)) & 0xffff0000u;
    float lo = f - __uint_as_float(hb);
    unsigned ul = __float_as_uint(lo);
    unsigned short l16 = (unsigned short)((ul + 0x7fffu + ((ul >> 16) & 1u)) >> 16);
    size_t oidx = (((size_t)rl * 4 + (k >> 5)) * 128 + n) * 32 + (k & 31);
    whi[oidx] = (unsigned short)(hb >> 16);
    wlo[oidx] = l16;
}

// ---------------- aggregation (CSR gather of fp16 rows) ----------------------
struct AggT {
    const __half* xin;
    const int* off;
    const int* esrc;
    const float* ns;
    const float* nd;
    unsigned short* Ah;
    unsigned short* Al;
};

template <int RELU>
__global__ __launch_bounds__(256) void k_agg2(AggT ta, AggT tb) {
    AggT t = (blockIdx.y == 0) ? ta : tb;
    int wave = (blockIdx.x * blockDim.x + threadIdx.x) >> 6;
    int lane = threadIdx.x & 63;
    if (wave >= NN) return;
    int e0 = t.off[wave], e1 = t.off[wave + 1];
    const __half* xin = t.xin;
    const int* esrc = t.esrc;
    const float* ns = t.ns;
    float a0 = 0.f, a1 = 0.f, b0 = 0.f, b1 = 0.f;
    float c0 = 0.f, c1 = 0.f, d0 = 0.f, d1 = 0.f;
    int e = e0;
    for (; e + 8 <= e1; e += 8) {
        int s0 = esrc[e], s1 = esrc[e + 1], s2 = esrc[e + 2], s3 = esrc[e + 3];
        int s4 = esrc[e + 4], s5 = esrc[e + 5], s6 = esrc[e + 6], s7 = esrc[e + 7];
        float w0 = ns[s0], w1 = ns[s1], w2 = ns[s2], w3 = ns[s3];
        float w4 = ns[s4], w5 = ns[s5], w6 = ns[s6], w7 = ns[s7];
        float2 v0 = __half22float2(*reinterpret_cast<const __half2*>(xin + (size_t)s0 * 128 + lane * 2));
        float2 v1 = __half22float2(*reinterpret_cast<const __half2*>(xin + (size_t)s1 * 128 + lane * 2));
        float2 v2 = __half22float2(*reinterpret_cast<const __half2*>(xin + (size_t)s2 * 128 + lane * 2));
        float2 v3 = __half22float2(*reinterpret_cast<const __half2*>(xin + (size_t)s3 * 128 + lane * 2));
        float2 v4 = __half22float2(*reinterpret_cast<const __half2*>(xin + (size_t)s4 * 128 + lane * 2));
        float2 v5 = __half22float2(*reinterpret_cast<const __half2*>(xin + (size_t)s5 * 128 + lane * 2));
        float2 v6 = __half22float2(*reinterpret_cast<const __half2*>(xin + (size_t)s6 * 128 + lane * 2));
        float2 v7 = __half22float2(*reinterpret_cast<const __half2*>(xin + (size_t)s7 * 128 + lane * 2));
        if (RELU) {
            v0.x = fmaxf(v0.x, 0.f); v0.y = fmaxf(v0.y, 0.f);
            v1.x = fmaxf(v1.x, 0.f); v1.y = fmaxf(v1.y, 0.f);
            v2.x = fmaxf(v2.x, 0.f); v2.y = fmaxf(v2.y, 0.f);
            v3.x = fmaxf(v3.x, 0.f); v3.y = fmaxf(v3.y, 0.f);
            v4.x = fmaxf(v4.x, 0.f); v4.y = fmaxf(v4.y, 0.f);
            v5.x = fmaxf(v5.x, 0.f); v5.y = fmaxf(v5.y, 0.f);
            v6.x = fmaxf(v6.x, 0.f); v6.y = fmaxf(v6.y, 0.f);
            v7.x = fmaxf(v7.x, 0.f); v7.y = fmaxf(v7.y, 0.f);
        }
        a0 = fmaf(w0, v0.x, a0); a1 = fmaf(w0, v0.y, a1);
        b0 = fmaf(w1, v1.x, b0); b1 = fmaf(w1, v1.y, b1);
        c0 = fmaf(w2, v2.x, c0); c1 = fmaf(w2, v2.y, c1);
        d0 = fmaf(w3, v3.x, d0); d1 = fmaf(w3, v3.y, d1);
        a0 = fmaf(w4, v4.x, a0); a1 = fmaf(w4, v4.y, a1);
        b0 = fmaf(w5, v5.x, b0); b1 = fmaf(w5, v5.y, b1);
        c0 = fmaf(w6, v6.x, c0); c1 = fmaf(w6, v6.y, c1);
        d0 = fmaf(w7, v7.x, d0); d1 = fmaf(w7, v7.y, d1);
    }
    if (e + 4 <= e1) {
        int s0 = esrc[e], s1 = esrc[e + 1], s2 = esrc[e + 2], s3 = esrc[e + 3];
        float w0 = ns[s0], w1 = ns[s1], w2 = ns[s2], w3 = ns[s3];
        float2 v0 = __half22float2(*reinterpret_cast<const __half2*>(xin + (size_t)s0 * 128 + lane * 2));
        float2 v1 = __half22float2(*reinterpret_cast<const __half2*>(xin + (size_t)s1 * 128 + lane * 2));
        float2 v2 = __half22float2(*reinterpret_cast<const __half2*>(xin + (size_t)s2 * 128 + lane * 2));
        float2 v3 = __half22float2(*reinterpret_cast<const __half2*>(xin + (size_t)s3 * 128 + lane * 2));
        if (RELU) {
            v0.x = fmaxf(v0.x, 0.f); v0.y = fmaxf(v0.y, 0.f);
            v1.x = fmaxf(v1.x, 0.f); v1.y = fmaxf(v1.y, 0.f);
            v2.x = fmaxf(v2.x, 0.f); v2.y = fmaxf(v2.y, 0.f);
            v3.x = fmaxf(v3.x, 0.f); v3.y = fmaxf(v3.y, 0.f);
        }
        a0 = fmaf(w0, v0.x, a0); a1 = fmaf(w0, v0.y, a1);
        b0 = fmaf(w1, v1.x, b0); b1 = fmaf(w1, v1.y, b1);
        c0 = fmaf(w2, v2.x, c0); c1 = fmaf(w2, v2.y, c1);
        d0 = fmaf(w3, v3.x, d0); d1 = fmaf(w3, v3.y, d1);
        e += 4;
    }
    for (; e < e1; ++e) {
        int s = esrc[e];
        float w = ns[s];
        float2 v = __half22float2(*reinterpret_cast<const __half2*>(xin + (size_t)s * 128 + lane * 2));
        if (RELU) { v.x = fmaxf(v.x, 0.f); v.y = fmaxf(v.y, 0.f); }
        a0 = fmaf(w, v.x, a0); a1 = fmaf(w, v.y, a1);
    }
    float nr = t.nd[wave];
    float r0 = ((a0 + b0) + (c0 + d0)) * nr;
    float r1 = ((a1 + b1) + (c1 + d1)) * nr;
    unsigned u0 = __float_as_uint(r0);
    unsigned h0b = (u0 + 0x7fffu + ((u0 >> 16) & 1u)) & 0xffff0000u;
    unsigned ul0 = __float_as_uint(r0 - __uint_as_float(h0b));
    unsigned u1 = __float_as_uint(r1);
    unsigned h1b = (u1 + 0x7fffu + ((u1 >> 16) & 1u)) & 0xffff0000u;
    unsigned ul1 = __float_as_uint(r1 - __uint_as_float(h1b));
    ushort2 hv, lv;
    hv.x = (unsigned short)(h0b >> 16);
    hv.y = (unsigned short)(h1b >> 16);
    lv.x = (unsigned short)((ul0 + 0x7fffu + ((ul0 >> 16) & 1u)) >> 16);
    lv.y = (unsigned short)((ul1 + 0x7fffu + ((ul1 >> 16) & 1u)) >> 16);
    *reinterpret_cast<ushort2*>(t.Ah + (size_t)wave * 128 + lane * 2) = hv;
    *reinterpret_cast<ushort2*>(t.Al + (size_t)wave * 128 + lane * 2) = lv;
}

// ---------------- MFMA GEMM: H (=|+=) sum_s A_s @ W_s + bias ----------------
__device__ __forceinline__ float ld_val(const float* p) { return *p; }
__device__ __forceinline__ float ld_val(const __half* p) { return __half2float(*p); }
__device__ __forceinline__ void st_val(float* p, float v) { *p = v; }
__device__ __forceinline__ void st_val(__half* p, float v) { *p = __float2half_rn(v); }

template <int NS, int STORE, typename TH>
__global__ __launch_bounds__(256) void k_gemm_mfma(
    const unsigned short* __restrict__ Ah, const unsigned short* __restrict__ Al,
    const unsigned short* __restrict__ wha, const unsigned short* __restrict__ wla,
    const unsigned short* __restrict__ whb, const unsigned short* __restrict__ wlb,
    const float* __restrict__ ba, const float* __restrict__ bb,
    TH* __restrict__ H) {
    int tid = threadIdx.x;
    int w = tid >> 6, lane = tid & 63;
    int row0 = blockIdx.x * 64;
    int colbase = w * 32;
    int r16 = lane & 15;
    int koff = (lane >> 4) * 8;

    f32x4 acc[4][2];
#pragma unroll
    for (int rt = 0; rt < 4; ++rt)
#pragma unroll
        for (int nt = 0; nt < 2; ++nt)
            acc[rt][nt] = f32x4{0.f, 0.f, 0.f, 0.f};

#pragma unroll
    for (int s = 0; s < NS; ++s) {
        const unsigned short* A_h = Ah + (size_t)s * NN * 128;
        const unsigned short* A_l = Al + (size_t)s * NN * 128;
        const unsigned short* w_h = (s == 0) ? wha : whb;
        const unsigned short* w_l = (s == 0) ? wla : wlb;
#pragma unroll
        for (int c = 0; c < 4; ++c) {
            int kbase = c * 32 + koff;
            bf16x8 ah[4], al[4], bh[2], bl[2];
#pragma unroll
            for (int rt = 0; rt < 4; ++rt) {
                int rr = rt * 16 + r16;
                int rc = (row0 + rr < NN) ? rr : 0;
                ah[rt] = *reinterpret_cast<const bf16x8*>(
                    A_h + ((size_t)(row0 + rc)) * 128 + kbase);
                al[rt] = *reinterpret_cast<const bf16x8*>(
                    A_l + ((size_t)(row0 + rc)) * 128 + kbase);
            }
#pragma unroll
            for (int nt = 0; nt < 2; ++nt) {
                int col = colbase + nt * 16 + r16;
                size_t widx = ((size_t)c * 128 + col) * 32 + koff;
                bh[nt] = *reinterpret_cast<const bf16x8*>(w_h + widx);
                bl[nt] = *reinterpret_cast<const bf16x8*>(w_l + widx);
            }
#pragma unroll
            for (int rt = 0; rt < 4; ++rt)
#pragma unroll
                for (int nt = 0; nt < 2; ++nt) {
                    acc[rt][nt] = MFMA16(ah[rt], bh[nt], acc[rt][nt]);
                    acc[rt][nt] = MFMA16(ah[rt], bl[nt], acc[rt][nt]);
                    acc[rt][nt] = MFMA16(al[rt], bh[nt], acc[rt][nt]);
                }
        }
    }

    int orow = (lane >> 4) * 4;
#pragma unroll
    for (int nt = 0; nt < 2; ++nt) {
        int col = colbase + nt * 16 + r16;
        float bias = ba[col];
        if (NS == 2) bias += bb[col];
#pragma unroll
        for (int rt = 0; rt < 4; ++rt) {
#pragma unroll
            for (int j = 0; j < 4; ++j) {
                int grow = row0 + rt * 16 + orow + j;
                if (grow < NN) {
                    TH* hp = H + (size_t)grow * 128 + col;
                    float v = acc[rt][nt][j] + bias;
                    if (!STORE) v += ld_val(hp);
                    st_val(hp, v);
                }
            }
        }
    }
}

// ---------------- classifier: out = relu(H) @ Wc + bc -----------------------
__global__ __launch_bounds__(256) void k_classifier(const float* __restrict__ H,
                                                    const float* __restrict__ Wc,
                                                    const float* __restrict__ bc,
                                                    float* __restrict__ out) {
    __shared__ float sW[128 * 16];
    __shared__ float sb[16];
    int tid = threadIdx.x;
#pragma unroll
    for (int i = tid; i < 2048; i += 256) sW[i] = Wc[i];
    if (tid < 16) sb[tid] = bc[tid];
    __syncthreads();
    int node = blockIdx.x * 64 + (tid >> 2);
    if (node >= 3 * NN) return;
    int cg = (tid & 3) << 2;
    const float* h = H + (size_t)node * 128;
    float acc0 = 0.f, acc1 = 0.f, acc2 = 0.f, acc3 = 0.f;
#pragma unroll 4
    for (int k0 = 0; k0 < 128; k0 += 4) {
        float4 a4 = *reinterpret_cast<const float4*>(h + k0);
        float a;
        a = fmaxf(a4.x, 0.f);
        { float4 wv = *reinterpret_cast<const float4*>(&sW[(k0 + 0) * 16 + cg]);
          acc0 = fmaf(a, wv.x, acc0); acc1 = fmaf(a, wv.y, acc1);
          acc2 = fmaf(a, wv.z, acc2); acc3 = fmaf(a, wv.w, acc3); }
        a = fmaxf(a4.y, 0.f);
        { float4 wv = *reinterpret_cast<const float4*>(&sW[(k0 + 1) * 16 + cg]);
          acc0 = fmaf(a, wv.x, acc0); acc1 = fmaf(a, wv.y, acc1);
          acc2 = fmaf(a, wv.z, acc2); acc3 = fmaf(a, wv.w, acc3); }
        a = fmaxf(a4.z, 0.f);
        { float4 wv = *reinterpret_cast<const float4*>(&sW[(k0 + 2) * 16 + cg]);
          acc0 = fmaf(a, wv.x, acc0); acc1 = fmaf(a, wv.y, acc1);
          acc2 = fmaf(a, wv.z, acc2); acc3 = fmaf(a, wv.w, acc3); }
        a = fmaxf(a4.w, 0.f);
        { float4 wv = *reinterpret_cast<const float4*>(&sW[(k0 + 3) * 16 + cg]);
          acc0 = fmaf(a, wv.x, acc0); acc1 = fmaf(a, wv.y, acc1);
          acc2 = fmaf(a, wv.z, acc2); acc3 = fmaf(a, wv.w, acc3); }
    }
    float4 o = make_float4(acc0 + sb[cg], acc1 + sb[cg + 1],
                           acc2 + sb[cg + 2], acc3 + sb[cg + 3]);
    *reinterpret_cast<float4*>(out + (size_t)node * 16 + cg) = o;
}

// ---------------------------------------------------------------------------
extern "C" void kernel_launch(void* const* d_in, const int* in_sizes, int n_in,
                              void* d_out, int out_size, void* d_ws, size_t ws_size,
                              hipStream_t stream) {
    const float* x0 = (const float*)d_in[0];
    const float* x1 = (const float*)d_in[1];
    const float* x2 = (const float*)d_in[2];
    const float* W1 = (const float*)d_in[3];
    const float* b1 = (const float*)d_in[4];
    const float* W2 = (const float*)d_in[5];
    const float* b2 = (const float*)d_in[6];
    const float* Wc = (const float*)d_in[7];
    const float* bc = (const float*)d_in[8];
    const int* edges = (const int*)d_in[9];

    const int REL_S[9] = {0, 1, 1, 0, 2, 2, 0, 2, 1};

    // ---- workspace carve-up with overlays (~227 MB peak) ----
    char* p = (char*)d_ws;
    auto alloc = [&](size_t bytes) -> void* {
        void* r = (void*)p;
        p += (bytes + 255) & ~(size_t)255;
        return r;
    };
    float* h2 = (float*)alloc((size_t)3 * NN * 128 * sizeof(float));  // 76.8 MB
    // aliases inside h2 (all dead before first h2 write at layer-2 GEMM):
    unsigned* hist = (unsigned*)h2;                          // 14.4 MB, dead after k_sums
    int* deg_d = (int*)((char*)h2 + 16 * 1024 * 1024);       // 1.8 MB, dead after k_offsets
    unsigned* bpairs = (unsigned*)((char*)h2 + 20 * 1024 * 1024); // 14.4 MB, dead after k_scatter
    __half* xh  = (__half*)alloc((size_t)3 * NN * 128 * sizeof(__half));  // 38.4 MB
    __half* h1h = (__half*)alloc((size_t)3 * NN * 128 * sizeof(__half));  // 38.4 MB
    unsigned short* Ah = (unsigned short*)alloc((size_t)2 * NN * 128 * 2);  // 25.6 MB
    unsigned short* Al = (unsigned short*)alloc((size_t)2 * NN * 128 * 2);  // 25.6 MB
    int* off = (int*)alloc((size_t)9 * (NN + 1) * sizeof(int));
    float* ns = (float*)alloc((size_t)9 * NN * sizeof(float));
    float* nd = (float*)alloc((size_t)9 * NN * sizeof(float));
    int* esrc = (int*)alloc((size_t)9 * EE * sizeof(int));            // 14.4 MB
    unsigned short* whi = (unsigned short*)alloc((size_t)2 * 9 * 128 * 128 * 2);
    unsigned short* wlo = (unsigned short*)alloc((size_t)2 * 9 * 128 * 128 * 2);
    int* gcur = (int*)alloc((size_t)9 * NBK * sizeof(int));
    unsigned short* Ah1 = Ah + (size_t)NN * 128;
    unsigned short* Al1 = Al + (size_t)NN * 128;
    const __half* xph[3] = {xh, xh + (size_t)NN * 128, xh + (size_t)2 * NN * 128};

    // ---- CSR build (2-pass bucketed) + input/weight prep ----
    k_hist<<<288, 256, 0, stream>>>(edges, hist);
    k_xprep<<<(3 * NN * 32 + 255) / 256, 256, 0, stream>>>(x0, x1, x2, xh);
    k_sums<<<(9 * (NN / 2) + 255) / 256, 256, 0, stream>>>(hist, ns, nd, deg_d);
    k_offsets<<<9, 256, 0, stream>>>(deg_d, off, gcur);
    k_bucket<<<9 * NCH, 256, 0, stream>>>(edges, gcur, bpairs);
    k_scatter<<<9 * NBK, 256, 0, stream>>>(bpairs, off, esrc);
    k_wprep<<<(2 * 9 * 128 * 128 + 255) / 256, 256, 0, stream>>>(W1, W2, whi, wlo);

    const dim3 agg2_grid(12500, 2);
    const dim3 agg1_grid(12500, 1);
    const int gemm_blocks = (NN + 63) / 64;   // 782

    auto mk = [&](int r, const __half* xin, unsigned short* ah, unsigned short* al) -> AggT {
        return AggT{xin, off + r * (NN + 1), esrc + (size_t)r * EE,
                    ns + r * NN, nd + r * NN, ah, al};
    };
    auto wp = [&](int layer, int r) { return (size_t)(layer * 9 + r) * 16384; };

    // ======== layer 1 (inputs xh fp16, no relu) -> h1h fp16 ========
    {
        const float* b = b1; const int L = 0;
        k_agg2<0><<<agg2_grid, 256, 0, stream>>>(mk(3, xph[REL_S[3]], Ah, Al),
                                                 mk(6, xph[REL_S[6]], Ah1, Al1));
        k_gemm_mfma<2, 1, __half><<<gemm_blocks, 256, 0, stream>>>(
            Ah, Al, whi + wp(L, 3), wlo + wp(L, 3), whi + wp(L, 6), wlo + wp(L, 6),
            b + 3 * 128, b + 6 * 128, h1h + (size_t)0 * NN * 128);
        k_agg2<0><<<agg2_grid, 256, 0, stream>>>(mk(2, xph[REL_S[2]], Ah, Al),
                                                 mk(5, xph[REL_S[5]], Ah1, Al1));
        k_gemm_mfma<2, 0, __half><<<gemm_blocks, 256, 0, stream>>>(
            Ah, Al, whi + wp(L, 2), wlo + wp(L, 2), whi + wp(L, 5), wlo + wp(L, 5),
            b + 2 * 128, b + 5 * 128, h1h + (size_t)0 * NN * 128);
        k_agg2<0><<<agg2_grid, 256, 0, stream>>>(mk(4, xph[REL_S[4]], Ah, Al),
                                                 mk(8, xph[REL_S[8]], Ah1, Al1));
        k_gemm_mfma<2, 1, __half><<<gemm_blocks, 256, 0, stream>>>(
            Ah, Al, whi + wp(L, 4), wlo + wp(L, 4), whi + wp(L, 8), wlo + wp(L, 8),
            b + 4 * 128, b + 8 * 128, h1h + (size_t)1 * NN * 128);
        k_agg2<0><<<agg2_grid, 256, 0, stream>>>(mk(0, xph[REL_S[0]], Ah, Al),
                                                 mk(1, xph[REL_S[1]], Ah1, Al1));
        k_gemm_mfma<2, 1, __half><<<gemm_blocks, 256, 0, stream>>>(
            Ah, Al, whi + wp(L, 0), wlo + wp(L, 0), whi + wp(L, 1), wlo + wp(L, 1),
            b + 0 * 128, b + 1 * 128, h1h + (size_t)2 * NN * 128);
        k_agg2<0><<<agg1_grid, 256, 0, stream>>>(mk(7, xph[REL_S[7]], Ah, Al),
                                                 mk(7, xph[REL_S[7]], Ah, Al));
        k_gemm_mfma<1, 0, __half><<<gemm_blocks, 256, 0, stream>>>(
            Ah, Al, whi + wp(L, 7), wlo + wp(L, 7), whi + wp(L, 7), wlo + wp(L, 7),
            b + 7 * 128, b + 7 * 128, h1h + (size_t)2 * NN * 128);
    }

    // ======== layer 2 (inputs relu(h1h) fp16, folded into gather) -> h2 fp32 ==
    {
        const float* b = b2; const int L = 1;
        auto hin = [&](int r) { return (const __half*)(h1h + (size_t)REL_S[r] * NN * 128); };
        k_agg2<1><<<agg2_grid, 256, 0, stream>>>(mk(3, hin(3), Ah, Al),
                                                 mk(6, hin(6), Ah1, Al1));
        k_gemm_mfma<2, 1, float><<<gemm_blocks, 256, 0, stream>>>(
            Ah, Al, whi + wp(L, 3), wlo + wp(L, 3), whi + wp(L, 6), wlo + wp(L, 6),
            b + 3 * 128, b + 6 * 128, h2 + (size_t)0 * NN * 128);
        k_agg2<1><<<agg2_grid, 256, 0, stream>>>(mk(2, hin(2), Ah, Al),
                                                 mk(5, hin(5), Ah1, Al1));
        k_gemm_mfma<2, 0, float><<<gemm_blocks, 256, 0, stream>>>(
            Ah, Al, whi + wp(L, 2), wlo + wp(L, 2), whi + wp(L, 5), wlo + wp(L, 5),
            b + 2 * 128, b + 5 * 128, h2 + (size_t)0 * NN * 128);
        k_agg2<1><<<agg2_grid, 256, 0, stream>>>(mk(4, hin(4), Ah, Al),
                                                 mk(8, hin(8), Ah1, Al1));
        k_gemm_mfma<2, 1, float><<<gemm_blocks, 256, 0, stream>>>(
            Ah, Al, whi + wp(L, 4), wlo + wp(L, 4), whi + wp(L, 8), wlo + wp(L, 8),
            b + 4 * 128, b + 8 * 128, h2 + (size_t)1 * NN * 128);
        k_agg2<1><<<agg2_grid, 256, 0, stream>>>(mk(0, hin(0), Ah, Al),
                                                 mk(1, hin(1), Ah1, Al1));
        k_gemm_mfma<2, 1, float><<<gemm_blocks, 256, 0, stream>>>(
            Ah, Al, whi + wp(L, 0), wlo + wp(L, 0), whi + wp(L, 1), wlo + wp(L, 1),
            b + 0 * 128, b + 1 * 128, h2 + (size_t)2 * NN * 128);
        k_agg2<1><<<agg1_grid, 256, 0, stream>>>(mk(7, hin(7), Ah, Al),
                                                 mk(7, hin(7), Ah, Al));
        k_gemm_mfma<1, 0, float><<<gemm_blocks, 256, 0, stream>>>(
            Ah, Al, whi + wp(L, 7), wlo + wp(L, 7), whi + wp(L, 7), wlo + wp(L, 7),
            b + 7 * 128, b + 7 * 128, h2 + (size_t)2 * NN * 128);
    }

    // ---- classifier: out = relu(h2) @ Wc + bc ----
    k_classifier<<<(3 * NN + 63) / 64, 256, 0, stream>>>(h2, Wc, bc, (float*)d_out);
}

// Round 12
// 1036.831 us; speedup vs baseline: 1.3970x; 1.1072x over previous
//
#include <hip/hip_runtime.h>
#include <hip/hip_bf16.h>
#include <hip/hip_fp16.h>

// ---------------------------------------------------------------------------
// Hetero-GCN (3 node types, 9 relations), 2 GraphConv layers + classifier.
// Round 12:
//  - k_offsets (9-block serial scan, 124us @ 0.4% occupancy) replaced by a
//    3-stage parallel scan: k_tsum (225 blk tile sums) -> k_tscan (tiny) ->
//    k_scan2 (225 blk local scan + off/gcur writes). Round-2/11 lesson again:
//    serial-structure kernels starve the machine; scans must be hierarchical.
//  - everything else unchanged (2-pass bucketed fill, fp16 gather planes,
//    split-bf16 MFMA GEMM).
// ---------------------------------------------------------------------------

#define NN 50000
#define EE 400000
#define NRG 2            // node ranges for histogram
#define RGN (NN / NRG)   // 25000 nodes per range
#define HCH 8            // edge chunks
#define HEG (EE / HCH)   // 50000 edges per chunk
#define NBK 98           // dst buckets (dst>>9)
#define BKW 512          // dsts per bucket
#define CH1 8192         // pass-1 edges per chunk
#define NCH ((EE + CH1 - 1) / CH1)   // 49
#define SCAP 6656        // pass-2 LDS segment capacity (mean 4096, sd 64)
#define TS 2048          // scan tile (nodes per block)
#define NT 25            // ceil(NN/TS)

typedef __attribute__((ext_vector_type(8))) short bf16x8;
typedef __attribute__((ext_vector_type(4))) float f32x4;
#define MFMA16(a, b, c) __builtin_amdgcn_mfma_f32_16x16x32_bf16(a, b, c, 0, 0, 0)

// ---------------- degree histogram (chunked, LDS, no global atomics) --------
__global__ __launch_bounds__(256) void k_hist(const int* __restrict__ edges,
                                              unsigned* __restrict__ hist) {
    __shared__ unsigned bins[RGN / 2];  // 12500 u32 = 50 KB
    int bid = blockIdx.x;
    int task = bid >> 4;           // r*2 + side
    int rem = bid & 15;
    int rg = rem >> 3;
    int c = rem & 7;
    int r = task >> 1, side = task & 1;
    int tid = threadIdx.x;
    for (int i = tid; i < RGN / 2; i += 256) bins[i] = 0;
    __syncthreads();
    const int* ea = edges + (size_t)r * 2 * EE + (size_t)side * EE + (size_t)c * HEG;
    int base = rg * RGN;
    for (int e = tid; e < HEG; e += 256) {
        int idx = __builtin_nontemporal_load(&ea[e]) - base;
        if ((unsigned)idx < (unsigned)RGN)
            atomicAdd(&bins[idx >> 1], (idx & 1) ? 65536u : 1u);
    }
    __syncthreads();
    unsigned* ho = hist + ((size_t)(task * NRG + rg) * HCH + c) * (RGN / 2);
    for (int i = tid; i < RGN / 2; i += 256) ho[i] = bins[i];
}

// ---------------- reduce histograms -> ns, nd, deg_d ------------------------
__global__ void k_sums(const unsigned* __restrict__ hist, float* __restrict__ ns,
                       float* __restrict__ nd, int* __restrict__ deg_d) {
    int i = blockIdx.x * blockDim.x + threadIdx.x;
    if (i >= 9 * (NN / 2)) return;
    int r = i / (NN / 2);
    int ps = i - r * (NN / 2);
    int rg = ps / (RGN / 2);
    int slot = ps - rg * (RGN / 2);
    const unsigned* hs = hist + ((size_t)((r * 2 + 0) * NRG + rg) * HCH) * (RGN / 2) + slot;
    const unsigned* hd = hist + ((size_t)((r * 2 + 1) * NRG + rg) * HCH) * (RGN / 2) + slot;
    unsigned slo = 0, shi = 0, dlo = 0, dhi = 0;
#pragma unroll
    for (int c = 0; c < HCH; ++c) {
        unsigned a = hs[(size_t)c * (RGN / 2)];
        unsigned b = hd[(size_t)c * (RGN / 2)];
        slo += a & 0xffffu; shi += a >> 16;
        dlo += b & 0xffffu; dhi += b >> 16;
    }
    int n0 = 2 * ps;
    ns[r * NN + n0]     = slo ? rsqrtf((float)slo) : 0.f;
    ns[r * NN + n0 + 1] = shi ? rsqrtf((float)shi) : 0.f;
    nd[r * NN + n0]     = dlo ? rsqrtf((float)dlo) : 0.f;
    nd[r * NN + n0 + 1] = dhi ? rsqrtf((float)dhi) : 0.f;
    deg_d[r * NN + n0]     = (int)dlo;
    deg_d[r * NN + n0 + 1] = (int)dhi;
}

// ---------------- parallel scan stage 1: per-tile sums ----------------------
__global__ __launch_bounds__(256) void k_tsum(const int* __restrict__ deg_d,
                                              int* __restrict__ tsum) {
    __shared__ int ws[4];
    int bid = blockIdx.x;               // 9*NT
    int r = bid / NT, t = bid - r * NT;
    int tid = threadIdx.x;
    const int* d = deg_d + r * NN;
    int base = t * TS + tid * 8;
    int s = 0;
#pragma unroll
    for (int j = 0; j < 8; ++j) {
        int n = base + j;
        if (n < NN) s += d[n];
    }
#pragma unroll
    for (int o = 32; o; o >>= 1) s += __shfl_down(s, (unsigned)o);
    int lane = tid & 63, w = tid >> 6;
    if (lane == 0) ws[w] = s;
    __syncthreads();
    if (tid == 0) tsum[bid] = ws[0] + ws[1] + ws[2] + ws[3];
}

// ---------------- parallel scan stage 2: scan tile sums (tiny) --------------
__global__ void k_tscan(int* __restrict__ tsum, int* __restrict__ off) {
    int r = threadIdx.x;
    if (r >= 9) return;
    int acc = 0;
    for (int t = 0; t < NT; ++t) {
        int v = tsum[r * NT + t];
        tsum[r * NT + t] = acc;
        acc += v;
    }
    off[r * (NN + 1) + NN] = acc;
}

// ---------------- parallel scan stage 3: local scan -> off, gcur ------------
__global__ __launch_bounds__(256) void k_scan2(const int* __restrict__ deg_d,
                                               const int* __restrict__ tsum,
                                               int* __restrict__ off,
                                               int* __restrict__ gcur) {
    __shared__ int ws[4];
    int bid = blockIdx.x;               // 9*NT
    int r = bid / NT, t = bid - r * NT;
    int tid = threadIdx.x;
    const int* d = deg_d + r * NN;
    int base = t * TS + tid * 8;
    int v[8];
    int s = 0;
#pragma unroll
    for (int j = 0; j < 8; ++j) {
        int n = base + j;
        v[j] = (n < NN) ? d[n] : 0;
        s += v[j];
    }
    int lane = tid & 63, w = tid >> 6;
    int x = s;
#pragma unroll
    for (int sh = 1; sh < 64; sh <<= 1) {
        int y = __shfl_up(x, (unsigned)sh);
        if (lane >= sh) x += y;
    }
    if (lane == 63) ws[w] = x;
    __syncthreads();
    int wb = 0;
#pragma unroll
    for (int j = 0; j < 3; ++j) wb += (j < w) ? ws[j] : 0;
    int run = tsum[bid] + wb + x - s;    // exclusive prefix for this thread
    int* o = off + r * (NN + 1);
#pragma unroll
    for (int j = 0; j < 8; ++j) {
        int n = base + j;
        if (n < NN) {
            o[n] = run;
            if ((n & (BKW - 1)) == 0) gcur[r * NBK + (n >> 9)] = run;
            run += v[j];
        }
    }
}

// ---------------- pass 1: bucket edges by dst>>9, packed u32 ----------------
__global__ __launch_bounds__(256) void k_bucket(const int* __restrict__ edges,
                                                int* __restrict__ gcur,
                                                unsigned* __restrict__ bpairs) {
    __shared__ int hist[NBK];
    __shared__ int sc[128];
    __shared__ int lofs[NBK + 1];
    __shared__ int lcur[NBK];
    __shared__ int gbase[NBK];
    __shared__ unsigned stage[CH1];
    int bid = blockIdx.x;
    int r = bid / NCH, c = bid - r * NCH;
    int tid = threadIdx.x;
    int e0 = c * CH1;
    int e1 = min(EE, e0 + CH1);
    int n = e1 - e0;
    const int* es = edges + (size_t)r * 2 * EE;
    const int* ed = es + EE;

    for (int i = tid; i < NBK; i += 256) hist[i] = 0;
    __syncthreads();
    for (int e = e0 + tid; e < e1; e += 256)
        atomicAdd(&hist[ed[e] >> 9], 1);
    __syncthreads();
    if (tid < 128) sc[tid] = (tid < NBK) ? hist[tid] : 0;
    __syncthreads();
#pragma unroll
    for (int s = 1; s < 128; s <<= 1) {
        int t = 0;
        if (tid < 128 && tid >= s) t = sc[tid - s];
        __syncthreads();
        if (tid < 128 && tid >= s) sc[tid] += t;
        __syncthreads();
    }
    if (tid < NBK) {
        int ex = sc[tid] - hist[tid];
        lofs[tid] = ex;
        lcur[tid] = ex;
        gbase[tid] = atomicAdd(&gcur[r * NBK + tid], hist[tid]);
    }
    if (tid == 0) lofs[NBK] = n;
    __syncthreads();
    for (int e = e0 + tid; e < e1; e += 256) {
        int dst = ed[e];
        int src = es[e];
        int p = atomicAdd(&lcur[dst >> 9], 1);
        stage[p] = ((unsigned)dst << 16) | (unsigned)src;
    }
    __syncthreads();
    unsigned* bp = bpairs + (size_t)r * EE;
    for (int i = tid; i < n; i += 256) {
        int lo = 0, hi = NBK;
        while (hi - lo > 1) {
            int m = (lo + hi) >> 1;
            if (lofs[m] <= i) lo = m; else hi = m;
        }
        bp[gbase[lo] + (i - lofs[lo])] = stage[i];
    }
}

// ---------------- pass 2: per-bucket LDS scatter -> coalesced esrc ----------
__global__ __launch_bounds__(256) void k_scatter(const unsigned* __restrict__ bpairs,
                                                 const int* __restrict__ off,
                                                 int* __restrict__ esrc) {
    __shared__ int lcur[BKW];
    __shared__ int lout[SCAP];
    int bid = blockIdx.x;
    int r = bid / NBK, b = bid - r * NBK;
    int tid = threadIdx.x;
    int d0 = b * BKW;
    int d1 = min(NN, d0 + BKW);
    const int* o = off + r * (NN + 1);
    int s0 = o[d0], s1 = o[d1];
    int n = s1 - s0;
    for (int i = tid; i < d1 - d0; i += 256) lcur[i] = o[d0 + i] - s0;
    __syncthreads();
    const unsigned* bp = bpairs + (size_t)r * EE + s0;
    int* out = esrc + (size_t)r * EE + s0;
    if (n <= SCAP) {
        for (int i = tid; i < n; i += 256) {
            unsigned pr = bp[i];
            int dst = (int)(pr >> 16), src = (int)(pr & 0xffffu);
            int p = atomicAdd(&lcur[dst - d0], 1);
            lout[p] = src;
        }
        __syncthreads();
        for (int i = tid; i < n; i += 256) out[i] = lout[i];
    } else {
        for (int i = tid; i < n; i += 256) {
            unsigned pr = bp[i];
            int dst = (int)(pr >> 16), src = (int)(pr & 0xffffu);
            int p = atomicAdd(&lcur[dst - d0], 1);
            out[p] = src;
        }
    }
}

// ---------------- x -> fp16 conversion ---------------------------------------
__global__ void k_xprep(const float* __restrict__ x0, const float* __restrict__ x1,
                        const float* __restrict__ x2, __half* __restrict__ xh) {
    int i = blockIdx.x * blockDim.x + threadIdx.x;  // float4 index over 3*NN*32
    const int per = NN * 32;
    if (i >= 3 * per) return;
    int tsel = i / per;
    int o = i - tsel * per;
    const float* xp = (tsel == 0) ? x0 : ((tsel == 1) ? x1 : x2);
    float4 v = *reinterpret_cast<const float4*>(xp + (size_t)o * 4);
    __half* dst = xh + (size_t)tsel * NN * 128 + (size_t)o * 4;
    *reinterpret_cast<__half2*>(dst) = __floats2half2_rn(v.x, v.y);
    *reinterpret_cast<__half2*>(dst + 2) = __floats2half2_rn(v.z, v.w);
}

// ---------------- W prep: fp32 [K][N] -> chunk-major bf16 hi/lo planes ------
__global__ void k_wprep(const float* __restrict__ W1, const float* __restrict__ W2,
                        unsigned short* __restrict__ whi,
                        unsigned short* __restrict__ wlo) {
    int id = blockIdx.x * blockDim.x + threadIdx.x;
    const int total = 2 * 9 * 128 * 128;
    if (id >= total) return;
    int n = id & 127;
    int k = (id >> 7) & 127;
    int rl = id >> 14;  // layer*9 + r
    const float* W = (rl < 9) ? W1 : W2;
    int r = (rl < 9) ? rl : rl - 9;
    float f = W[((size_t)r * 128 + k) * 128 + n];
    unsigned u = __float_as_uint(f);
    unsigned hb = (u + 0x7fffu + ((u >> 16) & 1u)) & 0xffff0000u;
    float lo = f - __uint_as_float(hb);
    unsigned ul = __float_as_uint(lo);
    unsigned short l16 = (unsigned short)((ul + 0x7fffu + ((ul >> 16) & 1u)) >> 16);
    size_t oidx = (((size_t)rl * 4 + (k >> 5)) * 128 + n) * 32 + (k & 31);
    whi[oidx] = (unsigned short)(hb >> 16);
    wlo[oidx] = l16;
}

// ---------------- aggregation (CSR gather of fp16 rows) ----------------------
struct AggT {
    const __half* xin;
    const int* off;
    const int* esrc;
    const float* ns;
    const float* nd;
    unsigned short* Ah;
    unsigned short* Al;
};

template <int RELU>
__global__ __launch_bounds__(256) void k_agg2(AggT ta, AggT tb) {
    AggT t = (blockIdx.y == 0) ? ta : tb;
    int wave = (blockIdx.x * blockDim.x + threadIdx.x) >> 6;
    int lane = threadIdx.x & 63;
    if (wave >= NN) return;
    int e0 = t.off[wave], e1 = t.off[wave + 1];
    const __half* xin = t.xin;
    const int* esrc = t.esrc;
    const float* ns = t.ns;
    float a0 = 0.f, a1 = 0.f, b0 = 0.f, b1 = 0.f;
    float c0 = 0.f, c1 = 0.f, d0 = 0.f, d1 = 0.f;
    int e = e0;
    for (; e + 8 <= e1; e += 8) {
        int s0 = esrc[e], s1 = esrc[e + 1], s2 = esrc[e + 2], s3 = esrc[e + 3];
        int s4 = esrc[e + 4], s5 = esrc[e + 5], s6 = esrc[e + 6], s7 = esrc[e + 7];
        float w0 = ns[s0], w1 = ns[s1], w2 = ns[s2], w3 = ns[s3];
        float w4 = ns[s4], w5 = ns[s5], w6 = ns[s6], w7 = ns[s7];
        float2 v0 = __half22float2(*reinterpret_cast<const __half2*>(xin + (size_t)s0 * 128 + lane * 2));
        float2 v1 = __half22float2(*reinterpret_cast<const __half2*>(xin + (size_t)s1 * 128 + lane * 2));
        float2 v2 = __half22float2(*reinterpret_cast<const __half2*>(xin + (size_t)s2 * 128 + lane * 2));
        float2 v3 = __half22float2(*reinterpret_cast<const __half2*>(xin + (size_t)s3 * 128 + lane * 2));
        float2 v4 = __half22float2(*reinterpret_cast<const __half2*>(xin + (size_t)s4 * 128 + lane * 2));
        float2 v5 = __half22float2(*reinterpret_cast<const __half2*>(xin + (size_t)s5 * 128 + lane * 2));
        float2 v6 = __half22float2(*reinterpret_cast<const __half2*>(xin + (size_t)s6 * 128 + lane * 2));
        float2 v7 = __half22float2(*reinterpret_cast<const __half2*>(xin + (size_t)s7 * 128 + lane * 2));
        if (RELU) {
            v0.x = fmaxf(v0.x, 0.f); v0.y = fmaxf(v0.y, 0.f);
            v1.x = fmaxf(v1.x, 0.f); v1.y = fmaxf(v1.y, 0.f);
            v2.x = fmaxf(v2.x, 0.f); v2.y = fmaxf(v2.y, 0.f);
            v3.x = fmaxf(v3.x, 0.f); v3.y = fmaxf(v3.y, 0.f);
            v4.x = fmaxf(v4.x, 0.f); v4.y = fmaxf(v4.y, 0.f);
            v5.x = fmaxf(v5.x, 0.f); v5.y = fmaxf(v5.y, 0.f);
            v6.x = fmaxf(v6.x, 0.f); v6.y = fmaxf(v6.y, 0.f);
            v7.x = fmaxf(v7.x, 0.f); v7.y = fmaxf(v7.y, 0.f);
        }
        a0 = fmaf(w0, v0.x, a0); a1 = fmaf(w0, v0.y, a1);
        b0 = fmaf(w1, v1.x, b0); b1 = fmaf(w1, v1.y, b1);
        c0 = fmaf(w2, v2.x, c0); c1 = fmaf(w2, v2.y, c1);
        d0 = fmaf(w3, v3.x, d0); d1 = fmaf(w3, v3.y, d1);
        a0 = fmaf(w4, v4.x, a0); a1 = fmaf(w4, v4.y, a1);
        b0 = fmaf(w5, v5.x, b0); b1 = fmaf(w5, v5.y, b1);
        c0 = fmaf(w6, v6.x, c0); c1 = fmaf(w6, v6.y, c1);
        d0 = fmaf(w7, v7.x, d0); d1 = fmaf(w7, v7.y, d1);
    }
    if (e + 4 <= e1) {
        int s0 = esrc[e], s1 = esrc[e + 1], s2 = esrc[e + 2], s3 = esrc[e + 3];
        float w0 = ns[s0], w1 = ns[s1], w2 = ns[s2], w3 = ns[s3];
        float2 v0 = __half22float2(*reinterpret_cast<const __half2*>(xin + (size_t)s0 * 128 + lane * 2));
        float2 v1 = __half22float2(*reinterpret_cast<const __half2*>(xin + (size_t)s1 * 128 + lane * 2));
        float2 v2 = __half22float2(*reinterpret_cast<const __half2*>(xin + (size_t)s2 * 128 + lane * 2));
        float2 v3 = __half22float2(*reinterpret_cast<const __half2*>(xin + (size_t)s3 * 128 + lane * 2));
        if (RELU) {
            v0.x = fmaxf(v0.x, 0.f); v0.y = fmaxf(v0.y, 0.f);
            v1.x = fmaxf(v1.x, 0.f); v1.y = fmaxf(v1.y, 0.f);
            v2.x = fmaxf(v2.x, 0.f); v2.y = fmaxf(v2.y, 0.f);
            v3.x = fmaxf(v3.x, 0.f); v3.y = fmaxf(v3.y, 0.f);
        }
        a0 = fmaf(w0, v0.x, a0); a1 = fmaf(w0, v0.y, a1);
        b0 = fmaf(w1, v1.x, b0); b1 = fmaf(w1, v1.y, b1);
        c0 = fmaf(w2, v2.x, c0); c1 = fmaf(w2, v2.y, c1);
        d0 = fmaf(w3, v3.x, d0); d1 = fmaf(w3, v3.y, d1);
        e += 4;
    }
    for (; e < e1; ++e) {
        int s = esrc[e];
        float w = ns[s];
        float2 v = __half22float2(*reinterpret_cast<const __half2*>(xin + (size_t)s * 128 + lane * 2));
        if (RELU) { v.x = fmaxf(v.x, 0.f); v.y = fmaxf(v.y, 0.f); }
        a0 = fmaf(w, v.x, a0); a1 = fmaf(w, v.y, a1);
    }
    float nr = t.nd[wave];
    float r0 = ((a0 + b0) + (c0 + d0)) * nr;
    float r1 = ((a1 + b1) + (c1 + d1)) * nr;
    unsigned u0 = __float_as_uint(r0);
    unsigned h0b = (u0 + 0x7fffu + ((u0 >> 16) & 1u)) & 0xffff0000u;
    unsigned ul0 = __float_as_uint(r0 - __uint_as_float(h0b));
    unsigned u1 = __float_as_uint(r1);
    unsigned h1b = (u1 + 0x7fffu + ((u1 >> 16) & 1u)) & 0xffff0000u;
    unsigned ul1 = __float_as_uint(r1 - __uint_as_float(h1b));
    ushort2 hv, lv;
    hv.x = (unsigned short)(h0b >> 16);
    hv.y = (unsigned short)(h1b >> 16);
    lv.x = (unsigned short)((ul0 + 0x7fffu + ((ul0 >> 16) & 1u)) >> 16);
    lv.y = (unsigned short)((ul1 + 0x7fffu + ((ul1 >> 16) & 1u)) >> 16);
    *reinterpret_cast<ushort2*>(t.Ah + (size_t)wave * 128 + lane * 2) = hv;
    *reinterpret_cast<ushort2*>(t.Al + (size_t)wave * 128 + lane * 2) = lv;
}

// ---------------- MFMA GEMM: H (=|+=) sum_s A_s @ W_s + bias ----------------
__device__ __forceinline__ float ld_val(const float* p) { return *p; }
__device__ __forceinline__ float ld_val(const __half* p) { return __half2float(*p); }
__device__ __forceinline__ void st_val(float* p, float v) { *p = v; }
__device__ __forceinline__ void st_val(__half* p, float v) { *p = __float2half_rn(v); }

template <int NS, int STORE, typename TH>
__global__ __launch_bounds__(256) void k_gemm_mfma(
    const unsigned short* __restrict__ Ah, const unsigned short* __restrict__ Al,
    const unsigned short* __restrict__ wha, const unsigned short* __restrict__ wla,
    const unsigned short* __restrict__ whb, const unsigned short* __restrict__ wlb,
    const float* __restrict__ ba, const float* __restrict__ bb,
    TH* __restrict__ H) {
    int tid = threadIdx.x;
    int w = tid >> 6, lane = tid & 63;
    int row0 = blockIdx.x * 64;
    int colbase = w * 32;
    int r16 = lane & 15;
    int koff = (lane >> 4) * 8;

    f32x4 acc[4][2];
#pragma unroll
    for (int rt = 0; rt < 4; ++rt)
#pragma unroll
        for (int nt = 0; nt < 2; ++nt)
            acc[rt][nt] = f32x4{0.f, 0.f, 0.f, 0.f};

#pragma unroll
    for (int s = 0; s < NS; ++s) {
        const unsigned short* A_h = Ah + (size_t)s * NN * 128;
        const unsigned short* A_l = Al + (size_t)s * NN * 128;
        const unsigned short* w_h = (s == 0) ? wha : whb;
        const unsigned short* w_l = (s == 0) ? wla : wlb;
#pragma unroll
        for (int c = 0; c < 4; ++c) {
            int kbase = c * 32 + koff;
            bf16x8 ah[4], al[4], bh[2], bl[2];
#pragma unroll
            for (int rt = 0; rt < 4; ++rt) {
                int rr = rt * 16 + r16;
                int rc = (row0 + rr < NN) ? rr : 0;
                ah[rt] = *reinterpret_cast<const bf16x8*>(
                    A_h + ((size_t)(row0 + rc)) * 128 + kbase);
                al[rt] = *reinterpret_cast<const bf16x8*>(
                    A_l + ((size_t)(row0 + rc)) * 128 + kbase);
            }
#pragma unroll
            for (int nt = 0; nt < 2; ++nt) {
                int col = colbase + nt * 16 + r16;
                size_t widx = ((size_t)c * 128 + col) * 32 + koff;
                bh[nt] = *reinterpret_cast<const bf16x8*>(w_h + widx);
                bl[nt] = *reinterpret_cast<const bf16x8*>(w_l + widx);
            }
#pragma unroll
            for (int rt = 0; rt < 4; ++rt)
#pragma unroll
                for (int nt = 0; nt < 2; ++nt) {
                    acc[rt][nt] = MFMA16(ah[rt], bh[nt], acc[rt][nt]);
                    acc[rt][nt] = MFMA16(ah[rt], bl[nt], acc[rt][nt]);
                    acc[rt][nt] = MFMA16(al[rt], bh[nt], acc[rt][nt]);
                }
        }
    }

    int orow = (lane >> 4) * 4;
#pragma unroll
    for (int nt = 0; nt < 2; ++nt) {
        int col = colbase + nt * 16 + r16;
        float bias = ba[col];
        if (NS == 2) bias += bb[col];
#pragma unroll
        for (int rt = 0; rt < 4; ++rt) {
#pragma unroll
            for (int j = 0; j < 4; ++j) {
                int grow = row0 + rt * 16 + orow + j;
                if (grow < NN) {
                    TH* hp = H + (size_t)grow * 128 + col;
                    float v = acc[rt][nt][j] + bias;
                    if (!STORE) v += ld_val(hp);
                    st_val(hp, v);
                }
            }
        }
    }
}

// ---------------- classifier: out = relu(H) @ Wc + bc -----------------------
__global__ __launch_bounds__(256) void k_classifier(const float* __restrict__ H,
                                                    const float* __restrict__ Wc,
                                                    const float* __restrict__ bc,
                                                    float* __restrict__ out) {
    __shared__ float sW[128 * 16];
    __shared__ float sb[16];
    int tid = threadIdx.x;
#pragma unroll
    for (int i = tid; i < 2048; i += 256) sW[i] = Wc[i];
    if (tid < 16) sb[tid] = bc[tid];
    __syncthreads();
    int node = blockIdx.x * 64 + (tid >> 2);
    if (node >= 3 * NN) return;
    int cg = (tid & 3) << 2;
    const float* h = H + (size_t)node * 128;
    float acc0 = 0.f, acc1 = 0.f, acc2 = 0.f, acc3 = 0.f;
#pragma unroll 4
    for (int k0 = 0; k0 < 128; k0 += 4) {
        float4 a4 = *reinterpret_cast<const float4*>(h + k0);
        float a;
        a = fmaxf(a4.x, 0.f);
        { float4 wv = *reinterpret_cast<const float4*>(&sW[(k0 + 0) * 16 + cg]);
          acc0 = fmaf(a, wv.x, acc0); acc1 = fmaf(a, wv.y, acc1);
          acc2 = fmaf(a, wv.z, acc2); acc3 = fmaf(a, wv.w, acc3); }
        a = fmaxf(a4.y, 0.f);
        { float4 wv = *reinterpret_cast<const float4*>(&sW[(k0 + 1) * 16 + cg]);
          acc0 = fmaf(a, wv.x, acc0); acc1 = fmaf(a, wv.y, acc1);
          acc2 = fmaf(a, wv.z, acc2); acc3 = fmaf(a, wv.w, acc3); }
        a = fmaxf(a4.z, 0.f);
        { float4 wv = *reinterpret_cast<const float4*>(&sW[(k0 + 2) * 16 + cg]);
          acc0 = fmaf(a, wv.x, acc0); acc1 = fmaf(a, wv.y, acc1);
          acc2 = fmaf(a, wv.z, acc2); acc3 = fmaf(a, wv.w, acc3); }
        a = fmaxf(a4.w, 0.f);
        { float4 wv = *reinterpret_cast<const float4*>(&sW[(k0 + 3) * 16 + cg]);
          acc0 = fmaf(a, wv.x, acc0); acc1 = fmaf(a, wv.y, acc1);
          acc2 = fmaf(a, wv.z, acc2); acc3 = fmaf(a, wv.w, acc3); }
    }
    float4 o = make_float4(acc0 + sb[cg], acc1 + sb[cg + 1],
                           acc2 + sb[cg + 2], acc3 + sb[cg + 3]);
    *reinterpret_cast<float4*>(out + (size_t)node * 16 + cg) = o;
}

// ---------------------------------------------------------------------------
extern "C" void kernel_launch(void* const* d_in, const int* in_sizes, int n_in,
                              void* d_out, int out_size, void* d_ws, size_t ws_size,
                              hipStream_t stream) {
    const float* x0 = (const float*)d_in[0];
    const float* x1 = (const float*)d_in[1];
    const float* x2 = (const float*)d_in[2];
    const float* W1 = (const float*)d_in[3];
    const float* b1 = (const float*)d_in[4];
    const float* W2 = (const float*)d_in[5];
    const float* b2 = (const float*)d_in[6];
    const float* Wc = (const float*)d_in[7];
    const float* bc = (const float*)d_in[8];
    const int* edges = (const int*)d_in[9];

    const int REL_S[9] = {0, 1, 1, 0, 2, 2, 0, 2, 1};

    // ---- workspace carve-up with overlays (~227 MB peak) ----
    char* p = (char*)d_ws;
    auto alloc = [&](size_t bytes) -> void* {
        void* r = (void*)p;
        p += (bytes + 255) & ~(size_t)255;
        return r;
    };
    float* h2 = (float*)alloc((size_t)3 * NN * 128 * sizeof(float));  // 76.8 MB
    // aliases inside h2 (all dead before first h2 write at layer-2 GEMM):
    unsigned* hist = (unsigned*)h2;                          // 14.4 MB, dead after k_sums
    int* deg_d = (int*)((char*)h2 + 16 * 1024 * 1024);       // 1.8 MB, dead after k_scan2
    unsigned* bpairs = (unsigned*)((char*)h2 + 20 * 1024 * 1024); // 14.4 MB, dead after k_scatter
    int* tsum = (int*)((char*)h2 + 36 * 1024 * 1024);        // 900 B, dead after k_scan2
    __half* xh  = (__half*)alloc((size_t)3 * NN * 128 * sizeof(__half));  // 38.4 MB
    __half* h1h = (__half*)alloc((size_t)3 * NN * 128 * sizeof(__half));  // 38.4 MB
    unsigned short* Ah = (unsigned short*)alloc((size_t)2 * NN * 128 * 2);  // 25.6 MB
    unsigned short* Al = (unsigned short*)alloc((size_t)2 * NN * 128 * 2);  // 25.6 MB
    int* off = (int*)alloc((size_t)9 * (NN + 1) * sizeof(int));
    float* ns = (float*)alloc((size_t)9 * NN * sizeof(float));
    float* nd = (float*)alloc((size_t)9 * NN * sizeof(float));
    int* esrc = (int*)alloc((size_t)9 * EE * sizeof(int));            // 14.4 MB
    unsigned short* whi = (unsigned short*)alloc((size_t)2 * 9 * 128 * 128 * 2);
    unsigned short* wlo = (unsigned short*)alloc((size_t)2 * 9 * 128 * 128 * 2);
    int* gcur = (int*)alloc((size_t)9 * NBK * sizeof(int));
    unsigned short* Ah1 = Ah + (size_t)NN * 128;
    unsigned short* Al1 = Al + (size_t)NN * 128;
    const __half* xph[3] = {xh, xh + (size_t)NN * 128, xh + (size_t)2 * NN * 128};

    // ---- CSR build (2-pass bucketed, parallel scan) + input/weight prep ----
    k_hist<<<288, 256, 0, stream>>>(edges, hist);
    k_xprep<<<(3 * NN * 32 + 255) / 256, 256, 0, stream>>>(x0, x1, x2, xh);
    k_sums<<<(9 * (NN / 2) + 255) / 256, 256, 0, stream>>>(hist, ns, nd, deg_d);
    k_tsum<<<9 * NT, 256, 0, stream>>>(deg_d, tsum);
    k_tscan<<<1, 64, 0, stream>>>(tsum, off);
    k_scan2<<<9 * NT, 256, 0, stream>>>(deg_d, tsum, off, gcur);
    k_bucket<<<9 * NCH, 256, 0, stream>>>(edges, gcur, bpairs);
    k_scatter<<<9 * NBK, 256, 0, stream>>>(bpairs, off, esrc);
    k_wprep<<<(2 * 9 * 128 * 128 + 255) / 256, 256, 0, stream>>>(W1, W2, whi, wlo);

    const dim3 agg2_grid(12500, 2);
    const dim3 agg1_grid(12500, 1);
    const int gemm_blocks = (NN + 63) / 64;   // 782

    auto mk = [&](int r, const __half* xin, unsigned short* ah, unsigned short* al) -> AggT {
        return AggT{xin, off + r * (NN + 1), esrc + (size_t)r * EE,
                    ns + r * NN, nd + r * NN, ah, al};
    };
    auto wp = [&](int layer, int r) { return (size_t)(layer * 9 + r) * 16384; };

    // ======== layer 1 (inputs xh fp16, no relu) -> h1h fp16 ========
    {
        const float* b = b1; const int L = 0;
        k_agg2<0><<<agg2_grid, 256, 0, stream>>>(mk(3, xph[REL_S[3]], Ah, Al),
                                                 mk(6, xph[REL_S[6]], Ah1, Al1));
        k_gemm_mfma<2, 1, __half><<<gemm_blocks, 256, 0, stream>>>(
            Ah, Al, whi + wp(L, 3), wlo + wp(L, 3), whi + wp(L, 6), wlo + wp(L, 6),
            b + 3 * 128, b + 6 * 128, h1h + (size_t)0 * NN * 128);
        k_agg2<0><<<agg2_grid, 256, 0, stream>>>(mk(2, xph[REL_S[2]], Ah, Al),
                                                 mk(5, xph[REL_S[5]], Ah1, Al1));
        k_gemm_mfma<2, 0, __half><<<gemm_blocks, 256, 0, stream>>>(
            Ah, Al, whi + wp(L, 2), wlo + wp(L, 2), whi + wp(L, 5), wlo + wp(L, 5),
            b + 2 * 128, b + 5 * 128, h1h + (size_t)0 * NN * 128);
        k_agg2<0><<<agg2_grid, 256, 0, stream>>>(mk(4, xph[REL_S[4]], Ah, Al),
                                                 mk(8, xph[REL_S[8]], Ah1, Al1));
        k_gemm_mfma<2, 1, __half><<<gemm_blocks, 256, 0, stream>>>(
            Ah, Al, whi + wp(L, 4), wlo + wp(L, 4), whi + wp(L, 8), wlo + wp(L, 8),
            b + 4 * 128, b + 8 * 128, h1h + (size_t)1 * NN * 128);
        k_agg2<0><<<agg2_grid, 256, 0, stream>>>(mk(0, xph[REL_S[0]], Ah, Al),
                                                 mk(1, xph[REL_S[1]], Ah1, Al1));
        k_gemm_mfma<2, 1, __half><<<gemm_blocks, 256, 0, stream>>>(
            Ah, Al, whi + wp(L, 0), wlo + wp(L, 0), whi + wp(L, 1), wlo + wp(L, 1),
            b + 0 * 128, b + 1 * 128, h1h + (size_t)2 * NN * 128);
        k_agg2<0><<<agg1_grid, 256, 0, stream>>>(mk(7, xph[REL_S[7]], Ah, Al),
                                                 mk(7, xph[REL_S[7]], Ah, Al));
        k_gemm_mfma<1, 0, __half><<<gemm_blocks, 256, 0, stream>>>(
            Ah, Al, whi + wp(L, 7), wlo + wp(L, 7), whi + wp(L, 7), wlo + wp(L, 7),
            b + 7 * 128, b + 7 * 128, h1h + (size_t)2 * NN * 128);
    }

    // ======== layer 2 (inputs relu(h1h) fp16, folded into gather) -> h2 fp32 ==
    {
        const float* b = b2; const int L = 1;
        auto hin = [&](int r) { return (const __half*)(h1h + (size_t)REL_S[r] * NN * 128); };
        k_agg2<1><<<agg2_grid, 256, 0, stream>>>(mk(3, hin(3), Ah, Al),
                                                 mk(6, hin(6), Ah1, Al1));
        k_gemm_mfma<2, 1, float><<<gemm_blocks, 256, 0, stream>>>(
            Ah, Al, whi + wp(L, 3), wlo + wp(L, 3), whi + wp(L, 6), wlo + wp(L, 6),
            b + 3 * 128, b + 6 * 128, h2 + (size_t)0 * NN * 128);
        k_agg2<1><<<agg2_grid, 256, 0, stream>>>(mk(2, hin(2), Ah, Al),
                                                 mk(5, hin(5), Ah1, Al1));
        k_gemm_mfma<2, 0, float><<<gemm_blocks, 256, 0, stream>>>(
            Ah, Al, whi + wp(L, 2), wlo + wp(L, 2), whi + wp(L, 5), wlo + wp(L, 5),
            b + 2 * 128, b + 5 * 128, h2 + (size_t)0 * NN * 128);
        k_agg2<1><<<agg2_grid, 256, 0, stream>>>(mk(4, hin(4), Ah, Al),
                                                 mk(8, hin(8), Ah1, Al1));
        k_gemm_mfma<2, 1, float><<<gemm_blocks, 256, 0, stream>>>(
            Ah, Al, whi + wp(L, 4), wlo + wp(L, 4), whi + wp(L, 8), wlo + wp(L, 8),
            b + 4 * 128, b + 8 * 128, h2 + (size_t)1 * NN * 128);
        k_agg2<1><<<agg2_grid, 256, 0, stream>>>(mk(0, hin(0), Ah, Al),
                                                 mk(1, hin(1), Ah1, Al1));
        k_gemm_mfma<2, 1, float><<<gemm_blocks, 256, 0, stream>>>(
            Ah, Al, whi + wp(L, 0), wlo + wp(L, 0), whi + wp(L, 1), wlo + wp(L, 1),
            b + 0 * 128, b + 1 * 128, h2 + (size_t)2 * NN * 128);
        k_agg2<1><<<agg1_grid, 256, 0, stream>>>(mk(7, hin(7), Ah, Al),
                                                 mk(7, hin(7), Ah, Al));
        k_gemm_mfma<1, 0, float><<<gemm_blocks, 256, 0, stream>>>(
            Ah, Al, whi + wp(L, 7), wlo + wp(L, 7), whi + wp(L, 7), wlo + wp(L, 7),
            b + 7 * 128, b + 7 * 128, h2 + (size_t)2 * NN * 128);
    }

    // ---- classifier: out = relu(h2) @ Wc + bc ----
    k_classifier<<<(3 * NN + 63) / 64, 256, 0, stream>>>(h2, Wc, bc, (float*)d_out);
}

// Round 13
// 1017.938 us; speedup vs baseline: 1.4229x; 1.0186x over previous
//
#include <hip/hip_runtime.h>
#include <hip/hip_bf16.h>
#include <hip/hip_fp16.h>

// ---------------------------------------------------------------------------
// Hetero-GCN (3 node types, 9 relations), 2 GraphConv layers + classifier.
// Round 13:
//  - k_hist: HCH 8->32 (grid 288->1152): round-12 profile showed 97us @ 11%
//    occupancy (1.1 blocks/CU; LDS allows 3). Same TLP-starvation class as
//    the serial scans.
//  - k_agg2 rewritten per G13 (vectorize!): 16 lanes x 4 edge-slots per wave,
//    16B float4 loads (was 4B __half2) -> one load instr covers 4 edges' rows;
//    tail = weight-0 clamp to hot row; __shfl_xor(16/32) group reduce.
//  - everything else frozen (bucketed fill, parallel scan, split-bf16 MFMA).
// ---------------------------------------------------------------------------

#define NN 50000
#define EE 400000
#define NRG 2            // node ranges for histogram
#define RGN (NN / NRG)   // 25000 nodes per range
#define HCH 32           // edge chunks (round 13: was 8)
#define HEG (EE / HCH)   // 12500 edges per chunk
#define NBK 98           // dst buckets (dst>>9)
#define BKW 512          // dsts per bucket
#define CH1 8192         // bucket pass-1 edges per chunk
#define NCH ((EE + CH1 - 1) / CH1)   // 49
#define SCAP 6656        // bucket pass-2 LDS segment capacity
#define TS 2048          // scan tile (nodes per block)
#define NT 25            // ceil(NN/TS)

typedef __attribute__((ext_vector_type(8))) short bf16x8;
typedef __attribute__((ext_vector_type(8))) unsigned short u16x8;
typedef __attribute__((ext_vector_type(4))) float f32x4;
#define MFMA16(a, b, c) __builtin_amdgcn_mfma_f32_16x16x32_bf16(a, b, c, 0, 0, 0)

// ---------------- degree histogram (chunked, LDS, no global atomics) --------
// grid: 18 tasks (9 rel x {src,dst}) x NRG x HCH = 1152 blocks
__global__ __launch_bounds__(256) void k_hist(const int* __restrict__ edges,
                                              unsigned* __restrict__ hist) {
    __shared__ unsigned bins[RGN / 2];  // 12500 u32 = 50 KB
    int bid = blockIdx.x;
    int task = bid >> 6;           // NRG*HCH = 64 blocks per task
    int rem = bid & 63;
    int rg = rem >> 5;
    int c = rem & 31;
    int r = task >> 1, side = task & 1;
    int tid = threadIdx.x;
    for (int i = tid; i < RGN / 2; i += 256) bins[i] = 0;
    __syncthreads();
    const int* ea = edges + (size_t)r * 2 * EE + (size_t)side * EE + (size_t)c * HEG;
    int base = rg * RGN;
    for (int e = tid; e < HEG; e += 256) {
        int idx = __builtin_nontemporal_load(&ea[e]) - base;
        if ((unsigned)idx < (unsigned)RGN)
            atomicAdd(&bins[idx >> 1], (idx & 1) ? 65536u : 1u);
    }
    __syncthreads();
    unsigned* ho = hist + ((size_t)(task * NRG + rg) * HCH + c) * (RGN / 2);
    for (int i = tid; i < RGN / 2; i += 256) ho[i] = bins[i];
}

// ---------------- reduce histograms -> ns, nd, deg_d ------------------------
__global__ void k_sums(const unsigned* __restrict__ hist, float* __restrict__ ns,
                       float* __restrict__ nd, int* __restrict__ deg_d) {
    int i = blockIdx.x * blockDim.x + threadIdx.x;
    if (i >= 9 * (NN / 2)) return;
    int r = i / (NN / 2);
    int ps = i - r * (NN / 2);
    int rg = ps / (RGN / 2);
    int slot = ps - rg * (RGN / 2);
    const unsigned* hs = hist + ((size_t)((r * 2 + 0) * NRG + rg) * HCH) * (RGN / 2) + slot;
    const unsigned* hd = hist + ((size_t)((r * 2 + 1) * NRG + rg) * HCH) * (RGN / 2) + slot;
    unsigned slo = 0, shi = 0, dlo = 0, dhi = 0;
#pragma unroll
    for (int c = 0; c < HCH; ++c) {
        unsigned a = hs[(size_t)c * (RGN / 2)];
        unsigned b = hd[(size_t)c * (RGN / 2)];
        slo += a & 0xffffu; shi += a >> 16;
        dlo += b & 0xffffu; dhi += b >> 16;
    }
    int n0 = 2 * ps;
    ns[r * NN + n0]     = slo ? rsqrtf((float)slo) : 0.f;
    ns[r * NN + n0 + 1] = shi ? rsqrtf((float)shi) : 0.f;
    nd[r * NN + n0]     = dlo ? rsqrtf((float)dlo) : 0.f;
    nd[r * NN + n0 + 1] = dhi ? rsqrtf((float)dhi) : 0.f;
    deg_d[r * NN + n0]     = (int)dlo;
    deg_d[r * NN + n0 + 1] = (int)dhi;
}

// ---------------- parallel scan stage 1: per-tile sums ----------------------
__global__ __launch_bounds__(256) void k_tsum(const int* __restrict__ deg_d,
                                              int* __restrict__ tsum) {
    __shared__ int ws[4];
    int bid = blockIdx.x;               // 9*NT
    int r = bid / NT, t = bid - r * NT;
    int tid = threadIdx.x;
    const int* d = deg_d + r * NN;
    int base = t * TS + tid * 8;
    int s = 0;
#pragma unroll
    for (int j = 0; j < 8; ++j) {
        int n = base + j;
        if (n < NN) s += d[n];
    }
#pragma unroll
    for (int o = 32; o; o >>= 1) s += __shfl_down(s, (unsigned)o);
    int lane = tid & 63, w = tid >> 6;
    if (lane == 0) ws[w] = s;
    __syncthreads();
    if (tid == 0) tsum[bid] = ws[0] + ws[1] + ws[2] + ws[3];
}

// ---------------- parallel scan stage 2: scan tile sums (tiny) --------------
__global__ void k_tscan(int* __restrict__ tsum, int* __restrict__ off) {
    int r = threadIdx.x;
    if (r >= 9) return;
    int acc = 0;
    for (int t = 0; t < NT; ++t) {
        int v = tsum[r * NT + t];
        tsum[r * NT + t] = acc;
        acc += v;
    }
    off[r * (NN + 1) + NN] = acc;
}

// ---------------- parallel scan stage 3: local scan -> off, gcur ------------
__global__ __launch_bounds__(256) void k_scan2(const int* __restrict__ deg_d,
                                               const int* __restrict__ tsum,
                                               int* __restrict__ off,
                                               int* __restrict__ gcur) {
    __shared__ int ws[4];
    int bid = blockIdx.x;               // 9*NT
    int r = bid / NT, t = bid - r * NT;
    int tid = threadIdx.x;
    const int* d = deg_d + r * NN;
    int base = t * TS + tid * 8;
    int v[8];
    int s = 0;
#pragma unroll
    for (int j = 0; j < 8; ++j) {
        int n = base + j;
        v[j] = (n < NN) ? d[n] : 0;
        s += v[j];
    }
    int lane = tid & 63, w = tid >> 6;
    int x = s;
#pragma unroll
    for (int sh = 1; sh < 64; sh <<= 1) {
        int y = __shfl_up(x, (unsigned)sh);
        if (lane >= sh) x += y;
    }
    if (lane == 63) ws[w] = x;
    __syncthreads();
    int wb = 0;
#pragma unroll
    for (int j = 0; j < 3; ++j) wb += (j < w) ? ws[j] : 0;
    int run = tsum[bid] + wb + x - s;    // exclusive prefix for this thread
    int* o = off + r * (NN + 1);
#pragma unroll
    for (int j = 0; j < 8; ++j) {
        int n = base + j;
        if (n < NN) {
            o[n] = run;
            if ((n & (BKW - 1)) == 0) gcur[r * NBK + (n >> 9)] = run;
            run += v[j];
        }
    }
}

// ---------------- pass 1: bucket edges by dst>>9, packed u32 ----------------
__global__ __launch_bounds__(256) void k_bucket(const int* __restrict__ edges,
                                                int* __restrict__ gcur,
                                                unsigned* __restrict__ bpairs) {
    __shared__ int hist[NBK];
    __shared__ int sc[128];
    __shared__ int lofs[NBK + 1];
    __shared__ int lcur[NBK];
    __shared__ int gbase[NBK];
    __shared__ unsigned stage[CH1];
    int bid = blockIdx.x;
    int r = bid / NCH, c = bid - r * NCH;
    int tid = threadIdx.x;
    int e0 = c * CH1;
    int e1 = min(EE, e0 + CH1);
    int n = e1 - e0;
    const int* es = edges + (size_t)r * 2 * EE;
    const int* ed = es + EE;

    for (int i = tid; i < NBK; i += 256) hist[i] = 0;
    __syncthreads();
    for (int e = e0 + tid; e < e1; e += 256)
        atomicAdd(&hist[ed[e] >> 9], 1);
    __syncthreads();
    if (tid < 128) sc[tid] = (tid < NBK) ? hist[tid] : 0;
    __syncthreads();
#pragma unroll
    for (int s = 1; s < 128; s <<= 1) {
        int t = 0;
        if (tid < 128 && tid >= s) t = sc[tid - s];
        __syncthreads();
        if (tid < 128 && tid >= s) sc[tid] += t;
        __syncthreads();
    }
    if (tid < NBK) {
        int ex = sc[tid] - hist[tid];
        lofs[tid] = ex;
        lcur[tid] = ex;
        gbase[tid] = atomicAdd(&gcur[r * NBK + tid], hist[tid]);
    }
    if (tid == 0) lofs[NBK] = n;
    __syncthreads();
    for (int e = e0 + tid; e < e1; e += 256) {
        int dst = ed[e];
        int src = es[e];
        int p = atomicAdd(&lcur[dst >> 9], 1);
        stage[p] = ((unsigned)dst << 16) | (unsigned)src;
    }
    __syncthreads();
    unsigned* bp = bpairs + (size_t)r * EE;
    for (int i = tid; i < n; i += 256) {
        int lo = 0, hi = NBK;
        while (hi - lo > 1) {
            int m = (lo + hi) >> 1;
            if (lofs[m] <= i) lo = m; else hi = m;
        }
        bp[gbase[lo] + (i - lofs[lo])] = stage[i];
    }
}

// ---------------- pass 2: per-bucket LDS scatter -> coalesced esrc ----------
__global__ __launch_bounds__(256) void k_scatter(const unsigned* __restrict__ bpairs,
                                                 const int* __restrict__ off,
                                                 int* __restrict__ esrc) {
    __shared__ int lcur[BKW];
    __shared__ int lout[SCAP];
    int bid = blockIdx.x;
    int r = bid / NBK, b = bid - r * NBK;
    int tid = threadIdx.x;
    int d0 = b * BKW;
    int d1 = min(NN, d0 + BKW);
    const int* o = off + r * (NN + 1);
    int s0 = o[d0], s1 = o[d1];
    int n = s1 - s0;
    for (int i = tid; i < d1 - d0; i += 256) lcur[i] = o[d0 + i] - s0;
    __syncthreads();
    const unsigned* bp = bpairs + (size_t)r * EE + s0;
    int* out = esrc + (size_t)r * EE + s0;
    if (n <= SCAP) {
        for (int i = tid; i < n; i += 256) {
            unsigned pr = bp[i];
            int dst = (int)(pr >> 16), src = (int)(pr & 0xffffu);
            int p = atomicAdd(&lcur[dst - d0], 1);
            lout[p] = src;
        }
        __syncthreads();
        for (int i = tid; i < n; i += 256) out[i] = lout[i];
    } else {
        for (int i = tid; i < n; i += 256) {
            unsigned pr = bp[i];
            int dst = (int)(pr >> 16), src = (int)(pr & 0xffffu);
            int p = atomicAdd(&lcur[dst - d0], 1);
            out[p] = src;
        }
    }
}

// ---------------- x -> fp16 conversion ---------------------------------------
__global__ void k_xprep(const float* __restrict__ x0, const float* __restrict__ x1,
                        const float* __restrict__ x2, __half* __restrict__ xh) {
    int i = blockIdx.x * blockDim.x + threadIdx.x;  // float4 index over 3*NN*32
    const int per = NN * 32;
    if (i >= 3 * per) return;
    int tsel = i / per;
    int o = i - tsel * per;
    const float* xp = (tsel == 0) ? x0 : ((tsel == 1) ? x1 : x2);
    float4 v = *reinterpret_cast<const float4*>(xp + (size_t)o * 4);
    __half* dst = xh + (size_t)tsel * NN * 128 + (size_t)o * 4;
    *reinterpret_cast<__half2*>(dst) = __floats2half2_rn(v.x, v.y);
    *reinterpret_cast<__half2*>(dst + 2) = __floats2half2_rn(v.z, v.w);
}

// ---------------- W prep: fp32 [K][N] -> chunk-major bf16 hi/lo planes ------
__global__ void k_wprep(const float* __restrict__ W1, const float* __restrict__ W2,
                        unsigned short* __restrict__ whi,
                        unsigned short* __restrict__ wlo) {
    int id = blockIdx.x * blockDim.x + threadIdx.x;
    const int total = 2 * 9 * 128 * 128;
    if (id >= total) return;
    int n = id & 127;
    int k = (id >> 7) & 127;
    int rl = id >> 14;  // layer*9 + r
    const float* W = (rl < 9) ? W1 : W2;
    int r = (rl < 9) ? rl : rl - 9;
    float f = W[((size_t)r * 128 + k) * 128 + n];
    unsigned u = __float_as_uint(f);
    unsigned hb = (u + 0x7fffu + ((u >> 16) & 1u)) & 0xffff0000u;
    float lo = f - __uint_as_float(hb);
    unsigned ul = __float_as_uint(lo);
    unsigned short l16 = (unsigned short)((ul + 0x7fffu + ((ul >> 16) & 1u)) >> 16);
    size_t oidx = (((size_t)rl * 4 + (k >> 5)) * 128 + n) * 32 + (k & 31);
    whi[oidx] = (unsigned short)(hb >> 16);
    wlo[oidx] = l16;
}

// ---------------- aggregation (vectorized CSR gather) ------------------------
// One wave per dst row: 4 edge-slots (g) x 16 column-lanes (c). Each lane
// loads 16B (8 halves) -> one load instruction covers 4 edges' row-slices.
// Tail slots clamp to a hot row with weight 0. Cross-slot shfl_xor reduce.
struct AggT {
    const __half* xin;
    const int* off;
    const int* esrc;
    const float* ns;
    const float* nd;
    unsigned short* Ah;
    unsigned short* Al;
};

template <int RELU>
__global__ __launch_bounds__(256) void k_agg2(AggT ta, AggT tb) {
    AggT t = (blockIdx.y == 0) ? ta : tb;
    int wave = (blockIdx.x * blockDim.x + threadIdx.x) >> 6;
    int lane = threadIdx.x & 63;
    if (wave >= NN) return;
    int g = lane >> 4;       // edge slot 0..3
    int c = lane & 15;       // column group: cols c*8 .. c*8+7
    int e0 = t.off[wave], e1 = t.off[wave + 1];
    const __half* xin = t.xin;
    const int* esrc = t.esrc;
    const float* ns = t.ns;
    float acc[8] = {};
    for (int e = e0; e < e1; e += 8) {
        int ea = e + g;
        int eb = e + 4 + g;
        bool va = ea < e1, vb = eb < e1;
        int sa = va ? esrc[ea] : esrc[e];   // clamp to hot line
        int sb = vb ? esrc[eb] : esrc[e];
        float wa = va ? ns[sa] : 0.f;
        float wb = vb ? ns[sb] : 0.f;
        float4 ra = *reinterpret_cast<const float4*>(xin + (size_t)sa * 128 + c * 8);
        float4 rb = *reinterpret_cast<const float4*>(xin + (size_t)sb * 128 + c * 8);
        const __half2* pa = reinterpret_cast<const __half2*>(&ra);
        const __half2* pb = reinterpret_cast<const __half2*>(&rb);
#pragma unroll
        for (int j = 0; j < 4; ++j) {
            float2 fa = __half22float2(pa[j]);
            float2 fb = __half22float2(pb[j]);
            if (RELU) {
                fa.x = fmaxf(fa.x, 0.f); fa.y = fmaxf(fa.y, 0.f);
                fb.x = fmaxf(fb.x, 0.f); fb.y = fmaxf(fb.y, 0.f);
            }
            acc[2 * j]     = fmaf(wa, fa.x, acc[2 * j]);
            acc[2 * j + 1] = fmaf(wa, fa.y, acc[2 * j + 1]);
            acc[2 * j]     = fmaf(wb, fb.x, acc[2 * j]);
            acc[2 * j + 1] = fmaf(wb, fb.y, acc[2 * j + 1]);
        }
    }
    // reduce across the 4 edge slots (lane xor 16, 32)
#pragma unroll
    for (int j = 0; j < 8; ++j) {
        acc[j] += __shfl_xor(acc[j], 16);
        acc[j] += __shfl_xor(acc[j], 32);
    }
    if (g == 0) {
        float nr = t.nd[wave];
        u16x8 hv, lv;
#pragma unroll
        for (int j = 0; j < 8; ++j) {
            float v = acc[j] * nr;
            unsigned u = __float_as_uint(v);
            unsigned hb = (u + 0x7fffu + ((u >> 16) & 1u)) & 0xffff0000u;
            unsigned ul = __float_as_uint(v - __uint_as_float(hb));
            hv[j] = (unsigned short)(hb >> 16);
            lv[j] = (unsigned short)((ul + 0x7fffu + ((ul >> 16) & 1u)) >> 16);
        }
        *reinterpret_cast<u16x8*>(t.Ah + (size_t)wave * 128 + c * 8) = hv;
        *reinterpret_cast<u16x8*>(t.Al + (size_t)wave * 128 + c * 8) = lv;
    }
}

// ---------------- MFMA GEMM: H (=|+=) sum_s A_s @ W_s + bias ----------------
__device__ __forceinline__ float ld_val(const float* p) { return *p; }
__device__ __forceinline__ float ld_val(const __half* p) { return __half2float(*p); }
__device__ __forceinline__ void st_val(float* p, float v) { *p = v; }
__device__ __forceinline__ void st_val(__half* p, float v) { *p = __float2half_rn(v); }

template <int NS, int STORE, typename TH>
__global__ __launch_bounds__(256) void k_gemm_mfma(
    const unsigned short* __restrict__ Ah, const unsigned short* __restrict__ Al,
    const unsigned short* __restrict__ wha, const unsigned short* __restrict__ wla,
    const unsigned short* __restrict__ whb, const unsigned short* __restrict__ wlb,
    const float* __restrict__ ba, const float* __restrict__ bb,
    TH* __restrict__ H) {
    int tid = threadIdx.x;
    int w = tid >> 6, lane = tid & 63;
    int row0 = blockIdx.x * 64;
    int colbase = w * 32;
    int r16 = lane & 15;
    int koff = (lane >> 4) * 8;

    f32x4 acc[4][2];
#pragma unroll
    for (int rt = 0; rt < 4; ++rt)
#pragma unroll
        for (int nt = 0; nt < 2; ++nt)
            acc[rt][nt] = f32x4{0.f, 0.f, 0.f, 0.f};

#pragma unroll
    for (int s = 0; s < NS; ++s) {
        const unsigned short* A_h = Ah + (size_t)s * NN * 128;
        const unsigned short* A_l = Al + (size_t)s * NN * 128;
        const unsigned short* w_h = (s == 0) ? wha : whb;
        const unsigned short* w_l = (s == 0) ? wla : wlb;
#pragma unroll
        for (int c = 0; c < 4; ++c) {
            int kbase = c * 32 + koff;
            bf16x8 ah[4], al[4], bh[2], bl[2];
#pragma unroll
            for (int rt = 0; rt < 4; ++rt) {
                int rr = rt * 16 + r16;
                int rc = (row0 + rr < NN) ? rr : 0;
                ah[rt] = *reinterpret_cast<const bf16x8*>(
                    A_h + ((size_t)(row0 + rc)) * 128 + kbase);
                al[rt] = *reinterpret_cast<const bf16x8*>(
                    A_l + ((size_t)(row0 + rc)) * 128 + kbase);
            }
#pragma unroll
            for (int nt = 0; nt < 2; ++nt) {
                int col = colbase + nt * 16 + r16;
                size_t widx = ((size_t)c * 128 + col) * 32 + koff;
                bh[nt] = *reinterpret_cast<const bf16x8*>(w_h + widx);
                bl[nt] = *reinterpret_cast<const bf16x8*>(w_l + widx);
            }
#pragma unroll
            for (int rt = 0; rt < 4; ++rt)
#pragma unroll
                for (int nt = 0; nt < 2; ++nt) {
                    acc[rt][nt] = MFMA16(ah[rt], bh[nt], acc[rt][nt]);
                    acc[rt][nt] = MFMA16(ah[rt], bl[nt], acc[rt][nt]);
                    acc[rt][nt] = MFMA16(al[rt], bh[nt], acc[rt][nt]);
                }
        }
    }

    int orow = (lane >> 4) * 4;
#pragma unroll
    for (int nt = 0; nt < 2; ++nt) {
        int col = colbase + nt * 16 + r16;
        float bias = ba[col];
        if (NS == 2) bias += bb[col];
#pragma unroll
        for (int rt = 0; rt < 4; ++rt) {
#pragma unroll
            for (int j = 0; j < 4; ++j) {
                int grow = row0 + rt * 16 + orow + j;
                if (grow < NN) {
                    TH* hp = H + (size_t)grow * 128 + col;
                    float v = acc[rt][nt][j] + bias;
                    if (!STORE) v += ld_val(hp);
                    st_val(hp, v);
                }
            }
        }
    }
}

// ---------------- classifier: out = relu(H) @ Wc + bc -----------------------
__global__ __launch_bounds__(256) void k_classifier(const float* __restrict__ H,
                                                    const float* __restrict__ Wc,
                                                    const float* __restrict__ bc,
                                                    float* __restrict__ out) {
    __shared__ float sW[128 * 16];
    __shared__ float sb[16];
    int tid = threadIdx.x;
#pragma unroll
    for (int i = tid; i < 2048; i += 256) sW[i] = Wc[i];
    if (tid < 16) sb[tid] = bc[tid];
    __syncthreads();
    int node = blockIdx.x * 64 + (tid >> 2);
    if (node >= 3 * NN) return;
    int cg = (tid & 3) << 2;
    const float* h = H + (size_t)node * 128;
    float acc0 = 0.f, acc1 = 0.f, acc2 = 0.f, acc3 = 0.f;
#pragma unroll 4
    for (int k0 = 0; k0 < 128; k0 += 4) {
        float4 a4 = *reinterpret_cast<const float4*>(h + k0);
        float a;
        a = fmaxf(a4.x, 0.f);
        { float4 wv = *reinterpret_cast<const float4*>(&sW[(k0 + 0) * 16 + cg]);
          acc0 = fmaf(a, wv.x, acc0); acc1 = fmaf(a, wv.y, acc1);
          acc2 = fmaf(a, wv.z, acc2); acc3 = fmaf(a, wv.w, acc3); }
        a = fmaxf(a4.y, 0.f);
        { float4 wv = *reinterpret_cast<const float4*>(&sW[(k0 + 1) * 16 + cg]);
          acc0 = fmaf(a, wv.x, acc0); acc1 = fmaf(a, wv.y, acc1);
          acc2 = fmaf(a, wv.z, acc2); acc3 = fmaf(a, wv.w, acc3); }
        a = fmaxf(a4.z, 0.f);
        { float4 wv = *reinterpret_cast<const float4*>(&sW[(k0 + 2) * 16 + cg]);
          acc0 = fmaf(a, wv.x, acc0); acc1 = fmaf(a, wv.y, acc1);
          acc2 = fmaf(a, wv.z, acc2); acc3 = fmaf(a, wv.w, acc3); }
        a = fmaxf(a4.w, 0.f);
        { float4 wv = *reinterpret_cast<const float4*>(&sW[(k0 + 3) * 16 + cg]);
          acc0 = fmaf(a, wv.x, acc0); acc1 = fmaf(a, wv.y, acc1);
          acc2 = fmaf(a, wv.z, acc2); acc3 = fmaf(a, wv.w, acc3); }
    }
    float4 o = make_float4(acc0 + sb[cg], acc1 + sb[cg + 1],
                           acc2 + sb[cg + 2], acc3 + sb[cg + 3]);
    *reinterpret_cast<float4*>(out + (size_t)node * 16 + cg) = o;
}

// ---------------------------------------------------------------------------
extern "C" void kernel_launch(void* const* d_in, const int* in_sizes, int n_in,
                              void* d_out, int out_size, void* d_ws, size_t ws_size,
                              hipStream_t stream) {
    const float* x0 = (const float*)d_in[0];
    const float* x1 = (const float*)d_in[1];
    const float* x2 = (const float*)d_in[2];
    const float* W1 = (const float*)d_in[3];
    const float* b1 = (const float*)d_in[4];
    const float* W2 = (const float*)d_in[5];
    const float* b2 = (const float*)d_in[6];
    const float* Wc = (const float*)d_in[7];
    const float* bc = (const float*)d_in[8];
    const int* edges = (const int*)d_in[9];

    const int REL_S[9] = {0, 1, 1, 0, 2, 2, 0, 2, 1};

    // ---- workspace carve-up with overlays (~227 MB peak) ----
    char* p = (char*)d_ws;
    auto alloc = [&](size_t bytes) -> void* {
        void* r = (void*)p;
        p += (bytes + 255) & ~(size_t)255;
        return r;
    };
    float* h2 = (float*)alloc((size_t)3 * NN * 128 * sizeof(float));  // 76.8 MB
    // aliases inside h2 (all dead before first h2 write at layer-2 GEMM).
    // hist (57.6 MB) live [k_hist, k_sums); bpairs (14.4 MB) live
    // [k_bucket, k_scatter) — temporally disjoint, both at offset 0.
    unsigned* hist = (unsigned*)h2;
    unsigned* bpairs = (unsigned*)h2;
    int* deg_d = (int*)((char*)h2 + 60 * 1024 * 1024);       // 1.8 MB, dead after k_scan2
    int* tsum = (int*)((char*)h2 + 63 * 1024 * 1024);        // 900 B, dead after k_scan2
    __half* xh  = (__half*)alloc((size_t)3 * NN * 128 * sizeof(__half));  // 38.4 MB
    __half* h1h = (__half*)alloc((size_t)3 * NN * 128 * sizeof(__half));  // 38.4 MB
    unsigned short* Ah = (unsigned short*)alloc((size_t)2 * NN * 128 * 2);  // 25.6 MB
    unsigned short* Al = (unsigned short*)alloc((size_t)2 * NN * 128 * 2);  // 25.6 MB
    int* off = (int*)alloc((size_t)9 * (NN + 1) * sizeof(int));
    float* ns = (float*)alloc((size_t)9 * NN * sizeof(float));
    float* nd = (float*)alloc((size_t)9 * NN * sizeof(float));
    int* esrc = (int*)alloc((size_t)9 * EE * sizeof(int));            // 14.4 MB
    unsigned short* whi = (unsigned short*)alloc((size_t)2 * 9 * 128 * 128 * 2);
    unsigned short* wlo = (unsigned short*)alloc((size_t)2 * 9 * 128 * 128 * 2);
    int* gcur = (int*)alloc((size_t)9 * NBK * sizeof(int));
    unsigned short* Ah1 = Ah + (size_t)NN * 128;
    unsigned short* Al1 = Al + (size_t)NN * 128;
    const __half* xph[3] = {xh, xh + (size_t)NN * 128, xh + (size_t)2 * NN * 128};

    // ---- CSR build (2-pass bucketed, parallel scan) + input/weight prep ----
    k_hist<<<18 * NRG * HCH, 256, 0, stream>>>(edges, hist);
    k_xprep<<<(3 * NN * 32 + 255) / 256, 256, 0, stream>>>(x0, x1, x2, xh);
    k_sums<<<(9 * (NN / 2) + 255) / 256, 256, 0, stream>>>(hist, ns, nd, deg_d);
    k_tsum<<<9 * NT, 256, 0, stream>>>(deg_d, tsum);
    k_tscan<<<1, 64, 0, stream>>>(tsum, off);
    k_scan2<<<9 * NT, 256, 0, stream>>>(deg_d, tsum, off, gcur);
    k_bucket<<<9 * NCH, 256, 0, stream>>>(edges, gcur, bpairs);
    k_scatter<<<9 * NBK, 256, 0, stream>>>(bpairs, off, esrc);
    k_wprep<<<(2 * 9 * 128 * 128 + 255) / 256, 256, 0, stream>>>(W1, W2, whi, wlo);

    const dim3 agg2_grid(12500, 2);
    const dim3 agg1_grid(12500, 1);
    const int gemm_blocks = (NN + 63) / 64;   // 782

    auto mk = [&](int r, const __half* xin, unsigned short* ah, unsigned short* al) -> AggT {
        return AggT{xin, off + r * (NN + 1), esrc + (size_t)r * EE,
                    ns + r * NN, nd + r * NN, ah, al};
    };
    auto wp = [&](int layer, int r) { return (size_t)(layer * 9 + r) * 16384; };

    // ======== layer 1 (inputs xh fp16, no relu) -> h1h fp16 ========
    {
        const float* b = b1; const int L = 0;
        k_agg2<0><<<agg2_grid, 256, 0, stream>>>(mk(3, xph[REL_S[3]], Ah, Al),
                                                 mk(6, xph[REL_S[6]], Ah1, Al1));
        k_gemm_mfma<2, 1, __half><<<gemm_blocks, 256, 0, stream>>>(
            Ah, Al, whi + wp(L, 3), wlo + wp(L, 3), whi + wp(L, 6), wlo + wp(L, 6),
            b + 3 * 128, b + 6 * 128, h1h + (size_t)0 * NN * 128);
        k_agg2<0><<<agg2_grid, 256, 0, stream>>>(mk(2, xph[REL_S[2]], Ah, Al),
                                                 mk(5, xph[REL_S[5]], Ah1, Al1));
        k_gemm_mfma<2, 0, __half><<<gemm_blocks, 256, 0, stream>>>(
            Ah, Al, whi + wp(L, 2), wlo + wp(L, 2), whi + wp(L, 5), wlo + wp(L, 5),
            b + 2 * 128, b + 5 * 128, h1h + (size_t)0 * NN * 128);
        k_agg2<0><<<agg2_grid, 256, 0, stream>>>(mk(4, xph[REL_S[4]], Ah, Al),
                                                 mk(8, xph[REL_S[8]], Ah1, Al1));
        k_gemm_mfma<2, 1, __half><<<gemm_blocks, 256, 0, stream>>>(
            Ah, Al, whi + wp(L, 4), wlo + wp(L, 4), whi + wp(L, 8), wlo + wp(L, 8),
            b + 4 * 128, b + 8 * 128, h1h + (size_t)1 * NN * 128);
        k_agg2<0><<<agg2_grid, 256, 0, stream>>>(mk(0, xph[REL_S[0]], Ah, Al),
                                                 mk(1, xph[REL_S[1]], Ah1, Al1));
        k_gemm_mfma<2, 1, __half><<<gemm_blocks, 256, 0, stream>>>(
            Ah, Al, whi + wp(L, 0), wlo + wp(L, 0), whi + wp(L, 1), wlo + wp(L, 1),
            b + 0 * 128, b + 1 * 128, h1h + (size_t)2 * NN * 128);
        k_agg2<0><<<agg1_grid, 256, 0, stream>>>(mk(7, xph[REL_S[7]], Ah, Al),
                                                 mk(7, xph[REL_S[7]], Ah, Al));
        k_gemm_mfma<1, 0, __half><<<gemm_blocks, 256, 0, stream>>>(
            Ah, Al, whi + wp(L, 7), wlo + wp(L, 7), whi + wp(L, 7), wlo + wp(L, 7),
            b + 7 * 128, b + 7 * 128, h1h + (size_t)2 * NN * 128);
    }

    // ======== layer 2 (inputs relu(h1h) fp16, folded into gather) -> h2 fp32 ==
    {
        const float* b = b2; const int L = 1;
        auto hin = [&](int r) { return (const __half*)(h1h + (size_t)REL_S[r] * NN * 128); };
        k_agg2<1><<<agg2_grid, 256, 0, stream>>>(mk(3, hin(3), Ah, Al),
                                                 mk(6, hin(6), Ah1, Al1));
        k_gemm_mfma<2, 1, float><<<gemm_blocks, 256, 0, stream>>>(
            Ah, Al, whi + wp(L, 3), wlo + wp(L, 3), whi + wp(L, 6), wlo + wp(L, 6),
            b + 3 * 128, b + 6 * 128, h2 + (size_t)0 * NN * 128);
        k_agg2<1><<<agg2_grid, 256, 0, stream>>>(mk(2, hin(2), Ah, Al),
                                                 mk(5, hin(5), Ah1, Al1));
        k_gemm_mfma<2, 0, float><<<gemm_blocks, 256, 0, stream>>>(
            Ah, Al, whi + wp(L, 2), wlo + wp(L, 2), whi + wp(L, 5), wlo + wp(L, 5),
            b + 2 * 128, b + 5 * 128, h2 + (size_t)0 * NN * 128);
        k_agg2<1><<<agg2_grid, 256, 0, stream>>>(mk(4, hin(4), Ah, Al),
                                                 mk(8, hin(8), Ah1, Al1));
        k_gemm_mfma<2, 1, float><<<gemm_blocks, 256, 0, stream>>>(
            Ah, Al, whi + wp(L, 4), wlo + wp(L, 4), whi + wp(L, 8), wlo + wp(L, 8),
            b + 4 * 128, b + 8 * 128, h2 + (size_t)1 * NN * 128);
        k_agg2<1><<<agg2_grid, 256, 0, stream>>>(mk(0, hin(0), Ah, Al),
                                                 mk(1, hin(1), Ah1, Al1));
        k_gemm_mfma<2, 1, float><<<gemm_blocks, 256, 0, stream>>>(
            Ah, Al, whi + wp(L, 0), wlo + wp(L, 0), whi + wp(L, 1), wlo + wp(L, 1),
            b + 0 * 128, b + 1 * 128, h2 + (size_t)2 * NN * 128);
        k_agg2<1><<<agg1_grid, 256, 0, stream>>>(mk(7, hin(7), Ah, Al),
                                                 mk(7, hin(7), Ah, Al));
        k_gemm_mfma<1, 0, float><<<gemm_blocks, 256, 0, stream>>>(
            Ah, Al, whi + wp(L, 7), wlo + wp(L, 7), whi + wp(L, 7), wlo + wp(L, 7),
            b + 7 * 128, b + 7 * 128, h2 + (size_t)2 * NN * 128);
    }

    // ---- classifier: out = relu(h2) @ Wc + bc ----
    k_classifier<<<(3 * NN + 63) / 64, 256, 0, stream>>>(h2, Wc, bc, (float*)d_out);
}

// Round 14
// 864.180 us; speedup vs baseline: 1.6761x; 1.1779x over previous
//
#include <hip/hip_runtime.h>
#include <hip/hip_bf16.h>
#include <hip/hip_fp16.h>

// ---------------------------------------------------------------------------
// Hetero-GCN (3 node types, 9 relations), 2 GraphConv layers + classifier.
// Round 14:
//  - A planes: single fp16 (inputs are already fp16-precision; split-bf16 A
//    was wasted bits). Agg writes and GEMM A-reads halve.
//  - GEMM: f16 MFMA 2-pass. W = Wh(fp16) + Wl(fp16, scaled x2048 to avoid
//    fp16 denormal flush), separate accumulators, epilogue accH+accL/2048.
//  - Src-batched agg: relations grouped by SRC plane ({0,3,6},{1,2,8},
//    {4,5,7}), bid%3 interleave -> resident blocks share the src plane in
//    each XCD L2 (agg is at the L3 random-line service floor; only fewer
//    L3 lines help). GEMMs re-paired by dst: (3,6)S,(0)S,(8,4)S,(2,5)A,(1,7)A.
//  - h2 fp16 (classifier reads halve). k_hist NRG=4/HCH=16 (25KB LDS, 6/CU).
// ---------------------------------------------------------------------------

#define NN 50000
#define EE 400000
#define NRG 4            // node ranges for histogram
#define RGN (NN / NRG)   // 12500 nodes per range
#define HCH 16           // edge chunks
#define HEG (EE / HCH)   // 25000 edges per chunk
#define NBK 98           // dst buckets (dst>>9)
#define BKW 512          // dsts per bucket
#define CH1 8192         // bucket pass-1 edges per chunk
#define NCH ((EE + CH1 - 1) / CH1)   // 49
#define SCAP 6656        // bucket pass-2 LDS segment capacity
#define TS 2048          // scan tile (nodes per block)
#define NT 25            // ceil(NN/TS)

typedef __attribute__((ext_vector_type(8))) _Float16 f16x8;
typedef __attribute__((ext_vector_type(4))) float f32x4;
#define MFMAH(a, b, c) __builtin_amdgcn_mfma_f32_16x16x32_f16(a, b, c, 0, 0, 0)

// ---------------- degree histogram (chunked, LDS, no global atomics) --------
// grid: 18 tasks (9 rel x {src,dst}) x NRG x HCH = 1152 blocks, 25KB LDS
__global__ __launch_bounds__(256) void k_hist(const int* __restrict__ edges,
                                              unsigned* __restrict__ hist) {
    __shared__ unsigned bins[RGN / 2];  // 6250 u32 = 25 KB
    int bid = blockIdx.x;
    int task = bid >> 6;           // NRG*HCH = 64 blocks per task
    int rem = bid & 63;
    int rg = rem >> 4;
    int c = rem & 15;
    int r = task >> 1, side = task & 1;
    int tid = threadIdx.x;
    for (int i = tid; i < RGN / 2; i += 256) bins[i] = 0;
    __syncthreads();
    const int* ea = edges + (size_t)r * 2 * EE + (size_t)side * EE + (size_t)c * HEG;
    int base = rg * RGN;
    for (int e = tid; e < HEG; e += 256) {
        int idx = __builtin_nontemporal_load(&ea[e]) - base;
        if ((unsigned)idx < (unsigned)RGN)
            atomicAdd(&bins[idx >> 1], (idx & 1) ? 65536u : 1u);
    }
    __syncthreads();
    unsigned* ho = hist + ((size_t)(task * NRG + rg) * HCH + c) * (RGN / 2);
    for (int i = tid; i < RGN / 2; i += 256) ho[i] = bins[i];
}

// ---------------- reduce histograms -> ns, nd, deg_d ------------------------
__global__ void k_sums(const unsigned* __restrict__ hist, float* __restrict__ ns,
                       float* __restrict__ nd, int* __restrict__ deg_d) {
    int i = blockIdx.x * blockDim.x + threadIdx.x;
    if (i >= 9 * (NN / 2)) return;
    int r = i / (NN / 2);
    int ps = i - r * (NN / 2);
    int rg = ps / (RGN / 2);
    int slot = ps - rg * (RGN / 2);
    const unsigned* hs = hist + ((size_t)((r * 2 + 0) * NRG + rg) * HCH) * (RGN / 2) + slot;
    const unsigned* hd = hist + ((size_t)((r * 2 + 1) * NRG + rg) * HCH) * (RGN / 2) + slot;
    unsigned slo = 0, shi = 0, dlo = 0, dhi = 0;
#pragma unroll
    for (int c = 0; c < HCH; ++c) {
        unsigned a = hs[(size_t)c * (RGN / 2)];
        unsigned b = hd[(size_t)c * (RGN / 2)];
        slo += a & 0xffffu; shi += a >> 16;
        dlo += b & 0xffffu; dhi += b >> 16;
    }
    int n0 = 2 * ps;
    ns[r * NN + n0]     = slo ? rsqrtf((float)slo) : 0.f;
    ns[r * NN + n0 + 1] = shi ? rsqrtf((float)shi) : 0.f;
    nd[r * NN + n0]     = dlo ? rsqrtf((float)dlo) : 0.f;
    nd[r * NN + n0 + 1] = dhi ? rsqrtf((float)dhi) : 0.f;
    deg_d[r * NN + n0]     = (int)dlo;
    deg_d[r * NN + n0 + 1] = (int)dhi;
}

// ---------------- parallel scan stage 1: per-tile sums ----------------------
__global__ __launch_bounds__(256) void k_tsum(const int* __restrict__ deg_d,
                                              int* __restrict__ tsum) {
    __shared__ int ws[4];
    int bid = blockIdx.x;               // 9*NT
    int r = bid / NT, t = bid - r * NT;
    int tid = threadIdx.x;
    const int* d = deg_d + r * NN;
    int base = t * TS + tid * 8;
    int s = 0;
#pragma unroll
    for (int j = 0; j < 8; ++j) {
        int n = base + j;
        if (n < NN) s += d[n];
    }
#pragma unroll
    for (int o = 32; o; o >>= 1) s += __shfl_down(s, (unsigned)o);
    int lane = tid & 63, w = tid >> 6;
    if (lane == 0) ws[w] = s;
    __syncthreads();
    if (tid == 0) tsum[bid] = ws[0] + ws[1] + ws[2] + ws[3];
}

// ---------------- parallel scan stage 2: scan tile sums (tiny) --------------
__global__ void k_tscan(int* __restrict__ tsum, int* __restrict__ off) {
    int r = threadIdx.x;
    if (r >= 9) return;
    int acc = 0;
    for (int t = 0; t < NT; ++t) {
        int v = tsum[r * NT + t];
        tsum[r * NT + t] = acc;
        acc += v;
    }
    off[r * (NN + 1) + NN] = acc;
}

// ---------------- parallel scan stage 3: local scan -> off, gcur ------------
__global__ __launch_bounds__(256) void k_scan2(const int* __restrict__ deg_d,
                                               const int* __restrict__ tsum,
                                               int* __restrict__ off,
                                               int* __restrict__ gcur) {
    __shared__ int ws[4];
    int bid = blockIdx.x;               // 9*NT
    int r = bid / NT, t = bid - r * NT;
    int tid = threadIdx.x;
    const int* d = deg_d + r * NN;
    int base = t * TS + tid * 8;
    int v[8];
    int s = 0;
#pragma unroll
    for (int j = 0; j < 8; ++j) {
        int n = base + j;
        v[j] = (n < NN) ? d[n] : 0;
        s += v[j];
    }
    int lane = tid & 63, w = tid >> 6;
    int x = s;
#pragma unroll
    for (int sh = 1; sh < 64; sh <<= 1) {
        int y = __shfl_up(x, (unsigned)sh);
        if (lane >= sh) x += y;
    }
    if (lane == 63) ws[w] = x;
    __syncthreads();
    int wb = 0;
#pragma unroll
    for (int j = 0; j < 3; ++j) wb += (j < w) ? ws[j] : 0;
    int run = tsum[bid] + wb + x - s;    // exclusive prefix for this thread
    int* o = off + r * (NN + 1);
#pragma unroll
    for (int j = 0; j < 8; ++j) {
        int n = base + j;
        if (n < NN) {
            o[n] = run;
            if ((n & (BKW - 1)) == 0) gcur[r * NBK + (n >> 9)] = run;
            run += v[j];
        }
    }
}

// ---------------- pass 1: bucket edges by dst>>9, packed u32 ----------------
__global__ __launch_bounds__(256) void k_bucket(const int* __restrict__ edges,
                                                int* __restrict__ gcur,
                                                unsigned* __restrict__ bpairs) {
    __shared__ int hist[NBK];
    __shared__ int sc[128];
    __shared__ int lofs[NBK + 1];
    __shared__ int lcur[NBK];
    __shared__ int gbase[NBK];
    __shared__ unsigned stage[CH1];
    int bid = blockIdx.x;
    int r = bid / NCH, c = bid - r * NCH;
    int tid = threadIdx.x;
    int e0 = c * CH1;
    int e1 = min(EE, e0 + CH1);
    int n = e1 - e0;
    const int* es = edges + (size_t)r * 2 * EE;
    const int* ed = es + EE;

    for (int i = tid; i < NBK; i += 256) hist[i] = 0;
    __syncthreads();
    for (int e = e0 + tid; e < e1; e += 256)
        atomicAdd(&hist[ed[e] >> 9], 1);
    __syncthreads();
    if (tid < 128) sc[tid] = (tid < NBK) ? hist[tid] : 0;
    __syncthreads();
#pragma unroll
    for (int s = 1; s < 128; s <<= 1) {
        int t = 0;
        if (tid < 128 && tid >= s) t = sc[tid - s];
        __syncthreads();
        if (tid < 128 && tid >= s) sc[tid] += t;
        __syncthreads();
    }
    if (tid < NBK) {
        int ex = sc[tid] - hist[tid];
        lofs[tid] = ex;
        lcur[tid] = ex;
        gbase[tid] = atomicAdd(&gcur[r * NBK + tid], hist[tid]);
    }
    if (tid == 0) lofs[NBK] = n;
    __syncthreads();
    for (int e = e0 + tid; e < e1; e += 256) {
        int dst = ed[e];
        int src = es[e];
        int p = atomicAdd(&lcur[dst >> 9], 1);
        stage[p] = ((unsigned)dst << 16) | (unsigned)src;
    }
    __syncthreads();
    unsigned* bp = bpairs + (size_t)r * EE;
    for (int i = tid; i < n; i += 256) {
        int lo = 0, hi = NBK;
        while (hi - lo > 1) {
            int m = (lo + hi) >> 1;
            if (lofs[m] <= i) lo = m; else hi = m;
        }
        bp[gbase[lo] + (i - lofs[lo])] = stage[i];
    }
}

// ---------------- pass 2: per-bucket LDS scatter -> coalesced esrc ----------
__global__ __launch_bounds__(256) void k_scatter(const unsigned* __restrict__ bpairs,
                                                 const int* __restrict__ off,
                                                 int* __restrict__ esrc) {
    __shared__ int lcur[BKW];
    __shared__ int lout[SCAP];
    int bid = blockIdx.x;
    int r = bid / NBK, b = bid - r * NBK;
    int tid = threadIdx.x;
    int d0 = b * BKW;
    int d1 = min(NN, d0 + BKW);
    const int* o = off + r * (NN + 1);
    int s0 = o[d0], s1 = o[d1];
    int n = s1 - s0;
    for (int i = tid; i < d1 - d0; i += 256) lcur[i] = o[d0 + i] - s0;
    __syncthreads();
    const unsigned* bp = bpairs + (size_t)r * EE + s0;
    int* out = esrc + (size_t)r * EE + s0;
    if (n <= SCAP) {
        for (int i = tid; i < n; i += 256) {
            unsigned pr = bp[i];
            int dst = (int)(pr >> 16), src = (int)(pr & 0xffffu);
            int p = atomicAdd(&lcur[dst - d0], 1);
            lout[p] = src;
        }
        __syncthreads();
        for (int i = tid; i < n; i += 256) out[i] = lout[i];
    } else {
        for (int i = tid; i < n; i += 256) {
            unsigned pr = bp[i];
            int dst = (int)(pr >> 16), src = (int)(pr & 0xffffu);
            int p = atomicAdd(&lcur[dst - d0], 1);
            out[p] = src;
        }
    }
}

// ---------------- x -> fp16 conversion ---------------------------------------
__global__ void k_xprep(const float* __restrict__ x0, const float* __restrict__ x1,
                        const float* __restrict__ x2, __half* __restrict__ xh) {
    int i = blockIdx.x * blockDim.x + threadIdx.x;  // float4 index over 3*NN*32
    const int per = NN * 32;
    if (i >= 3 * per) return;
    int tsel = i / per;
    int o = i - tsel * per;
    const float* xp = (tsel == 0) ? x0 : ((tsel == 1) ? x1 : x2);
    float4 v = *reinterpret_cast<const float4*>(xp + (size_t)o * 4);
    __half* dst = xh + (size_t)tsel * NN * 128 + (size_t)o * 4;
    *reinterpret_cast<__half2*>(dst) = __floats2half2_rn(v.x, v.y);
    *reinterpret_cast<__half2*>(dst + 2) = __floats2half2_rn(v.z, v.w);
}

// ---------------- W prep: fp32 [K][N] -> chunk-major fp16 hi/lo planes ------
// Wl stored scaled x2048 (raw residual ~2^-11*W would be fp16-subnormal).
__global__ void k_wprep(const float* __restrict__ W1, const float* __restrict__ W2,
                        __half* __restrict__ whi, __half* __restrict__ wlo) {
    int id = blockIdx.x * blockDim.x + threadIdx.x;
    const int total = 2 * 9 * 128 * 128;
    if (id >= total) return;
    int n = id & 127;
    int k = (id >> 7) & 127;
    int rl = id >> 14;  // layer*9 + r
    const float* W = (rl < 9) ? W1 : W2;
    int r = (rl < 9) ? rl : rl - 9;
    float f = W[((size_t)r * 128 + k) * 128 + n];
    __half h = __float2half_rn(f);
    float res = f - __half2float(h);
    __half l = __float2half_rn(res * 2048.0f);
    size_t oidx = (((size_t)rl * 4 + (k >> 5)) * 128 + n) * 32 + (k & 31);
    whi[oidx] = h;
    wlo[oidx] = l;
}

// ---------------- aggregation (vectorized CSR gather, 3 src-sharing tasks) --
// 1-D grid 3*12500; task = bid%3 so resident blocks interleave the three
// relations reading the SAME src plane (XCD-L2 sharing). One wave per dst
// row: 4 edge-slots x 16 col-lanes, 16B loads, shfl_xor reduce. fp16 A out.
struct AggT {
    const __half* xin;
    const int* off;
    const int* esrc;
    const float* ns;
    const float* nd;
    __half* A;
};

template <int RELU>
__global__ __launch_bounds__(256) void k_agg3(AggT t0, AggT t1, AggT t2) {
    int bid = blockIdx.x;
    int task = bid % 3;
    AggT t = (task == 0) ? t0 : ((task == 1) ? t1 : t2);
    int wave = (bid / 3) * 4 + (threadIdx.x >> 6);
    int lane = threadIdx.x & 63;
    if (wave >= NN) return;
    int g = lane >> 4;       // edge slot 0..3
    int c = lane & 15;       // column group: cols c*8 .. c*8+7
    int e0 = t.off[wave], e1 = t.off[wave + 1];
    const __half* xin = t.xin;
    const int* esrc = t.esrc;
    const float* ns = t.ns;
    float acc[8] = {};
    for (int e = e0; e < e1; e += 8) {
        int ea = e + g;
        int eb = e + 4 + g;
        bool va = ea < e1, vb = eb < e1;
        int sa = va ? esrc[ea] : esrc[e];   // clamp to hot line
        int sb = vb ? esrc[eb] : esrc[e];
        float wa = va ? ns[sa] : 0.f;
        float wb = vb ? ns[sb] : 0.f;
        float4 ra = *reinterpret_cast<const float4*>(xin + (size_t)sa * 128 + c * 8);
        float4 rb = *reinterpret_cast<const float4*>(xin + (size_t)sb * 128 + c * 8);
        const __half2* pa = reinterpret_cast<const __half2*>(&ra);
        const __half2* pb = reinterpret_cast<const __half2*>(&rb);
#pragma unroll
        for (int j = 0; j < 4; ++j) {
            float2 fa = __half22float2(pa[j]);
            float2 fb = __half22float2(pb[j]);
            if (RELU) {
                fa.x = fmaxf(fa.x, 0.f); fa.y = fmaxf(fa.y, 0.f);
                fb.x = fmaxf(fb.x, 0.f); fb.y = fmaxf(fb.y, 0.f);
            }
            acc[2 * j]     = fmaf(wa, fa.x, acc[2 * j]);
            acc[2 * j + 1] = fmaf(wa, fa.y, acc[2 * j + 1]);
            acc[2 * j]     = fmaf(wb, fb.x, acc[2 * j]);
            acc[2 * j + 1] = fmaf(wb, fb.y, acc[2 * j + 1]);
        }
    }
#pragma unroll
    for (int j = 0; j < 8; ++j) {
        acc[j] += __shfl_xor(acc[j], 16);
        acc[j] += __shfl_xor(acc[j], 32);
    }
    if (g == 0) {
        float nr = t.nd[wave];
        f16x8 hv;
#pragma unroll
        for (int j = 0; j < 8; ++j) hv[j] = (_Float16)(acc[j] * nr);
        *reinterpret_cast<f16x8*>(t.A + (size_t)wave * 128 + c * 8) = hv;
    }
}

// ---------------- f16 MFMA GEMM: H (=|+=) sum_s A_s @ (Wh_s + Wl_s/2048) ----
// A: fp16 [NN][128]. W planes chunk-major [4][128][32] fp16 (Wl scaled 2048).
// Separate accumulators for hi/lo passes; epilogue accH + accL/2048 + bias.
template <int NS, int STORE>
__global__ __launch_bounds__(256) void k_gemm_mfma(
    const __half* __restrict__ Aa, const __half* __restrict__ Ab,
    const __half* __restrict__ wha, const __half* __restrict__ wla,
    const __half* __restrict__ whb, const __half* __restrict__ wlb,
    const float* __restrict__ ba, const float* __restrict__ bb,
    __half* __restrict__ H) {
    int tid = threadIdx.x;
    int w = tid >> 6, lane = tid & 63;
    int row0 = blockIdx.x * 64;
    int colbase = w * 32;
    int r16 = lane & 15;
    int koff = (lane >> 4) * 8;

    f32x4 accH[4][2], accL[4][2];
#pragma unroll
    for (int rt = 0; rt < 4; ++rt)
#pragma unroll
        for (int nt = 0; nt < 2; ++nt) {
            accH[rt][nt] = f32x4{0.f, 0.f, 0.f, 0.f};
            accL[rt][nt] = f32x4{0.f, 0.f, 0.f, 0.f};
        }

#pragma unroll
    for (int s = 0; s < NS; ++s) {
        const __half* A = (s == 0) ? Aa : Ab;
        const __half* w_h = (s == 0) ? wha : whb;
        const __half* w_l = (s == 0) ? wla : wlb;
#pragma unroll
        for (int c = 0; c < 4; ++c) {
            int kbase = c * 32 + koff;
            f16x8 av[4], bh[2], bl[2];
#pragma unroll
            for (int rt = 0; rt < 4; ++rt) {
                int rr = rt * 16 + r16;
                int rc = (row0 + rr < NN) ? rr : 0;
                av[rt] = *reinterpret_cast<const f16x8*>(
                    A + ((size_t)(row0 + rc)) * 128 + kbase);
            }
#pragma unroll
            for (int nt = 0; nt < 2; ++nt) {
                int col = colbase + nt * 16 + r16;
                size_t widx = ((size_t)c * 128 + col) * 32 + koff;
                bh[nt] = *reinterpret_cast<const f16x8*>(w_h + widx);
                bl[nt] = *reinterpret_cast<const f16x8*>(w_l + widx);
            }
#pragma unroll
            for (int rt = 0; rt < 4; ++rt)
#pragma unroll
                for (int nt = 0; nt < 2; ++nt) {
                    accH[rt][nt] = MFMAH(av[rt], bh[nt], accH[rt][nt]);
                    accL[rt][nt] = MFMAH(av[rt], bl[nt], accL[rt][nt]);
                }
        }
    }

    int orow = (lane >> 4) * 4;
    const float inv = 1.0f / 2048.0f;
#pragma unroll
    for (int nt = 0; nt < 2; ++nt) {
        int col = colbase + nt * 16 + r16;
        float bias = ba[col];
        if (NS == 2) bias += bb[col];
#pragma unroll
        for (int rt = 0; rt < 4; ++rt) {
#pragma unroll
            for (int j = 0; j < 4; ++j) {
                int grow = row0 + rt * 16 + orow + j;
                if (grow < NN) {
                    __half* hp = H + (size_t)grow * 128 + col;
                    float v = accH[rt][nt][j] + accL[rt][nt][j] * inv + bias;
                    if (!STORE) v += __half2float(*hp);
                    *hp = __float2half_rn(v);
                }
            }
        }
    }
}

// ---------------- classifier: out = relu(H_fp16) @ Wc + bc ------------------
__global__ __launch_bounds__(256) void k_classifier(const __half* __restrict__ H,
                                                    const float* __restrict__ Wc,
                                                    const float* __restrict__ bc,
                                                    float* __restrict__ out) {
    __shared__ float sW[128 * 16];
    __shared__ float sb[16];
    int tid = threadIdx.x;
#pragma unroll
    for (int i = tid; i < 2048; i += 256) sW[i] = Wc[i];
    if (tid < 16) sb[tid] = bc[tid];
    __syncthreads();
    int node = blockIdx.x * 64 + (tid >> 2);
    if (node >= 3 * NN) return;
    int cg = (tid & 3) << 2;
    const __half* h = H + (size_t)node * 128;
    float acc0 = 0.f, acc1 = 0.f, acc2 = 0.f, acc3 = 0.f;
#pragma unroll 2
    for (int k0 = 0; k0 < 128; k0 += 8) {
        float4 raw = *reinterpret_cast<const float4*>(h + k0);  // 8 halves
        const __half2* hp2 = reinterpret_cast<const __half2*>(&raw);
#pragma unroll
        for (int jj = 0; jj < 4; ++jj) {
            float2 f = __half22float2(hp2[jj]);
            float a;
            a = fmaxf(f.x, 0.f);
            { float4 wv = *reinterpret_cast<const float4*>(&sW[(k0 + 2 * jj) * 16 + cg]);
              acc0 = fmaf(a, wv.x, acc0); acc1 = fmaf(a, wv.y, acc1);
              acc2 = fmaf(a, wv.z, acc2); acc3 = fmaf(a, wv.w, acc3); }
            a = fmaxf(f.y, 0.f);
            { float4 wv = *reinterpret_cast<const float4*>(&sW[(k0 + 2 * jj + 1) * 16 + cg]);
              acc0 = fmaf(a, wv.x, acc0); acc1 = fmaf(a, wv.y, acc1);
              acc2 = fmaf(a, wv.z, acc2); acc3 = fmaf(a, wv.w, acc3); }
        }
    }
    float4 o = make_float4(acc0 + sb[cg], acc1 + sb[cg + 1],
                           acc2 + sb[cg + 2], acc3 + sb[cg + 3]);
    *reinterpret_cast<float4*>(out + (size_t)node * 16 + cg) = o;
}

// ---------------------------------------------------------------------------
extern "C" void kernel_launch(void* const* d_in, const int* in_sizes, int n_in,
                              void* d_out, int out_size, void* d_ws, size_t ws_size,
                              hipStream_t stream) {
    const float* x0 = (const float*)d_in[0];
    const float* x1 = (const float*)d_in[1];
    const float* x2 = (const float*)d_in[2];
    const float* W1 = (const float*)d_in[3];
    const float* b1 = (const float*)d_in[4];
    const float* W2 = (const float*)d_in[5];
    const float* b2 = (const float*)d_in[6];
    const float* Wc = (const float*)d_in[7];
    const float* bc = (const float*)d_in[8];
    const int* edges = (const int*)d_in[9];

    // ---- workspace carve-up with overlays (~213 MB peak) ----
    char* p = (char*)d_ws;
    auto alloc = [&](size_t bytes) -> void* {
        void* r = (void*)p;
        p += (bytes + 255) & ~(size_t)255;
        return r;
    };
    __half* h2h = (__half*)alloc((size_t)3 * NN * 128 * sizeof(__half));  // 38.4 MB
    // aliases inside h2h (all dead before first h2h write at layer-2 GEMM):
    unsigned* hist = (unsigned*)h2h;                          // 28.8 MB, dead after k_sums
    unsigned* bpairs = (unsigned*)h2h;                        // 14.4 MB, [k_bucket,k_scatter)
    int* deg_d = (int*)((char*)h2h + 30 * 1024 * 1024);       // 1.8 MB, dead after k_scan2
    int* tsum = (int*)((char*)h2h + 33 * 1024 * 1024);        // 900 B, dead after k_scan2
    __half* xh  = (__half*)alloc((size_t)3 * NN * 128 * sizeof(__half));  // 38.4 MB
    __half* h1h = (__half*)alloc((size_t)3 * NN * 128 * sizeof(__half));  // 38.4 MB
    __half* A6  = (__half*)alloc((size_t)6 * NN * 128 * sizeof(__half));  // 76.8 MB
    int* off = (int*)alloc((size_t)9 * (NN + 1) * sizeof(int));
    float* ns = (float*)alloc((size_t)9 * NN * sizeof(float));
    float* nd = (float*)alloc((size_t)9 * NN * sizeof(float));
    int* esrc = (int*)alloc((size_t)9 * EE * sizeof(int));                // 14.4 MB
    __half* whi = (__half*)alloc((size_t)2 * 9 * 128 * 128 * sizeof(__half));
    __half* wlo = (__half*)alloc((size_t)2 * 9 * 128 * 128 * sizeof(__half));
    int* gcur = (int*)alloc((size_t)9 * NBK * sizeof(int));
    __half* P[6];
    for (int j = 0; j < 6; ++j) P[j] = A6 + (size_t)j * NN * 128;
    const __half* xph[3] = {xh, xh + (size_t)NN * 128, xh + (size_t)2 * NN * 128};

    // ---- CSR build (2-pass bucketed, parallel scan) + input/weight prep ----
    k_hist<<<18 * NRG * HCH, 256, 0, stream>>>(edges, hist);
    k_xprep<<<(3 * NN * 32 + 255) / 256, 256, 0, stream>>>(x0, x1, x2, xh);
    k_sums<<<(9 * (NN / 2) + 255) / 256, 256, 0, stream>>>(hist, ns, nd, deg_d);
    k_tsum<<<9 * NT, 256, 0, stream>>>(deg_d, tsum);
    k_tscan<<<1, 64, 0, stream>>>(tsum, off);
    k_scan2<<<9 * NT, 256, 0, stream>>>(deg_d, tsum, off, gcur);
    k_bucket<<<9 * NCH, 256, 0, stream>>>(edges, gcur, bpairs);
    k_scatter<<<9 * NBK, 256, 0, stream>>>(bpairs, off, esrc);
    k_wprep<<<(2 * 9 * 128 * 128 + 255) / 256, 256, 0, stream>>>(W1, W2, whi, wlo);

    const int agg_grid = 3 * 12500;
    const int gemm_blocks = (NN + 63) / 64;   // 782

    auto mk = [&](int r, const __half* xin, __half* slot) -> AggT {
        return AggT{xin, off + r * (NN + 1), esrc + (size_t)r * EE,
                    ns + r * NN, nd + r * NN, slot};
    };
    auto wp = [&](int layer, int r) { return (size_t)(layer * 9 + r) * 16384; };

    // src groups: S0={0,3,6} (src type0), S1={1,2,8} (type1), S2={4,5,7} (type2)
    // dst map: r0->2 r1->2 r2->0 r3->0 r4->1 r5->0 r6->0 r7->2 r8->1
    for (int L = 0; L < 2; ++L) {
        const float* b = (L == 0) ? b1 : b2;
        __half* o0 = ((L == 0) ? h1h : h2h) + (size_t)0 * NN * 128;
        __half* o1 = ((L == 0) ? h1h : h2h) + (size_t)1 * NN * 128;
        __half* o2 = ((L == 0) ? h1h : h2h) + (size_t)2 * NN * 128;
        const __half* in0 = (L == 0) ? xph[0] : h1h + (size_t)0 * NN * 128;
        const __half* in1 = (L == 0) ? xph[1] : h1h + (size_t)1 * NN * 128;
        const __half* in2 = (L == 0) ? xph[2] : h1h + (size_t)2 * NN * 128;

        // aggS0: rels {0,3,6} all read in0  -> slots P0,P1,P2
        if (L == 0)
            k_agg3<0><<<agg_grid, 256, 0, stream>>>(mk(0, in0, P[0]), mk(3, in0, P[1]),
                                                    mk(6, in0, P[2]));
        else
            k_agg3<1><<<agg_grid, 256, 0, stream>>>(mk(0, in0, P[0]), mk(3, in0, P[1]),
                                                    mk(6, in0, P[2]));
        // gemm (3,6) -> o0 STORE ; gemm (0) -> o2 STORE
        k_gemm_mfma<2, 1><<<gemm_blocks, 256, 0, stream>>>(
            P[1], P[2], whi + wp(L, 3), wlo + wp(L, 3), whi + wp(L, 6), wlo + wp(L, 6),
            b + 3 * 128, b + 6 * 128, o0);
        k_gemm_mfma<1, 1><<<gemm_blocks, 256, 0, stream>>>(
            P[0], P[0], whi + wp(L, 0), wlo + wp(L, 0), whi + wp(L, 0), wlo + wp(L, 0),
            b + 0 * 128, b + 0 * 128, o2);

        // aggS1: rels {1,2,8} all read in1 -> slots P3,P4,P5
        if (L == 0)
            k_agg3<0><<<agg_grid, 256, 0, stream>>>(mk(1, in1, P[3]), mk(2, in1, P[4]),
                                                    mk(8, in1, P[5]));
        else
            k_agg3<1><<<agg_grid, 256, 0, stream>>>(mk(1, in1, P[3]), mk(2, in1, P[4]),
                                                    mk(8, in1, P[5]));
        // aggS2: rels {4,5,7} all read in2 -> slots P0,P1,P2 (S0's, consumed)
        if (L == 0)
            k_agg3<0><<<agg_grid, 256, 0, stream>>>(mk(4, in2, P[0]), mk(5, in2, P[1]),
                                                    mk(7, in2, P[2]));
        else
            k_agg3<1><<<agg_grid, 256, 0, stream>>>(mk(4, in2, P[0]), mk(5, in2, P[1]),
                                                    mk(7, in2, P[2]));

        // gemm (8,4) -> o1 STORE ; (2,5) -> o0 ACC ; (1,7) -> o2 ACC
        k_gemm_mfma<2, 1><<<gemm_blocks, 256, 0, stream>>>(
            P[5], P[0], whi + wp(L, 8), wlo + wp(L, 8), whi + wp(L, 4), wlo + wp(L, 4),
            b + 8 * 128, b + 4 * 128, o1);
        k_gemm_mfma<2, 0><<<gemm_blocks, 256, 0, stream>>>(
            P[4], P[1], whi + wp(L, 2), wlo + wp(L, 2), whi + wp(L, 5), wlo + wp(L, 5),
            b + 2 * 128, b + 5 * 128, o0);
        k_gemm_mfma<2, 0><<<gemm_blocks, 256, 0, stream>>>(
            P[3], P[2], whi + wp(L, 1), wlo + wp(L, 1), whi + wp(L, 7), wlo + wp(L, 7),
            b + 1 * 128, b + 7 * 128, o2);
    }

    // ---- classifier: out = relu(h2h) @ Wc + bc ----
    k_classifier<<<(3 * NN + 63) / 64, 256, 0, stream>>>(h2h, Wc, bc, (float*)d_out);
}

// Round 15
// 798.375 us; speedup vs baseline: 1.8143x; 1.0824x over previous
//
#include <hip/hip_runtime.h>
#include <hip/hip_bf16.h>
#include <hip/hip_fp16.h>

// ---------------------------------------------------------------------------
// Hetero-GCN (3 node types, 9 relations), 2 GraphConv layers + classifier.
// Round 15:
//  - GEMM single-pass f16 W (Wl dropped): W-quant error ~3e-4/layer, an order
//    under the existing fp16-h noise. MFMA count and W loads halve.
//  - CSR build restructured: dst-degree pipeline (dst-hist half, scans) was
//    redundant with the bucket pass. New: src-only k_hist -> k_sums(ns) ->
//    k_bcount (98-bin) -> k_bscan (bases) -> k_bucket -> k_scatter derives
//    in-bucket degrees/offsets from its own pairs (512-bin LDS hist+scan),
//    writes off/nd coalesced. ~43 MB less traffic, 3 fewer launches.
//  - agg (fp16 src-grouped gather) unchanged: confirmed ~70us/dispatch at
//    VALU 51% / L2-service bound.
// ---------------------------------------------------------------------------

#define NN 50000
#define EE 400000
#define NRG 4            // node ranges for src histogram
#define RGN (NN / NRG)   // 12500 nodes per range
#define HCH 16           // edge chunks
#define HEG (EE / HCH)   // 25000 edges per chunk
#define NBK 98           // dst buckets (dst>>9)
#define BKW 512          // dsts per bucket
#define CH1 8192         // bucket pass-1 edges per chunk
#define NCH ((EE + CH1 - 1) / CH1)   // 49
#define SCAP 6656        // bucket pass-2 LDS segment capacity

typedef __attribute__((ext_vector_type(8))) _Float16 f16x8;
typedef __attribute__((ext_vector_type(4))) float f32x4;
#define MFMAH(a, b, c) __builtin_amdgcn_mfma_f32_16x16x32_f16(a, b, c, 0, 0, 0)

// ---------------- src-degree histogram (chunked, LDS) -----------------------
// grid: 9 rel x NRG x HCH = 576 blocks, 25KB LDS
__global__ __launch_bounds__(256) void k_hist(const int* __restrict__ edges,
                                              unsigned* __restrict__ hist) {
    __shared__ unsigned bins[RGN / 2];  // 6250 u32 = 25 KB
    int bid = blockIdx.x;
    int r = bid >> 6;              // NRG*HCH = 64 blocks per relation
    int rem = bid & 63;
    int rg = rem >> 4;
    int c = rem & 15;
    int tid = threadIdx.x;
    for (int i = tid; i < RGN / 2; i += 256) bins[i] = 0;
    __syncthreads();
    const int* ea = edges + (size_t)r * 2 * EE + (size_t)c * HEG;  // src side
    int base = rg * RGN;
    for (int e = tid; e < HEG; e += 256) {
        int idx = __builtin_nontemporal_load(&ea[e]) - base;
        if ((unsigned)idx < (unsigned)RGN)
            atomicAdd(&bins[idx >> 1], (idx & 1) ? 65536u : 1u);
    }
    __syncthreads();
    unsigned* ho = hist + ((size_t)(r * NRG + rg) * HCH + c) * (RGN / 2);
    for (int i = tid; i < RGN / 2; i += 256) ho[i] = bins[i];
}

// ---------------- reduce histograms -> ns -----------------------------------
__global__ void k_sums(const unsigned* __restrict__ hist, float* __restrict__ ns) {
    int i = blockIdx.x * blockDim.x + threadIdx.x;
    if (i >= 9 * (NN / 2)) return;
    int r = i / (NN / 2);
    int ps = i - r * (NN / 2);
    int rg = ps / (RGN / 2);
    int slot = ps - rg * (RGN / 2);
    const unsigned* hs = hist + ((size_t)(r * NRG + rg) * HCH) * (RGN / 2) + slot;
    unsigned slo = 0, shi = 0;
#pragma unroll
    for (int c = 0; c < HCH; ++c) {
        unsigned a = hs[(size_t)c * (RGN / 2)];
        slo += a & 0xffffu; shi += a >> 16;
    }
    int n0 = 2 * ps;
    ns[r * NN + n0]     = slo ? rsqrtf((float)slo) : 0.f;
    ns[r * NN + n0 + 1] = shi ? rsqrtf((float)shi) : 0.f;
}

// ---------------- per-bucket edge counts ------------------------------------
// grid: 9 rel x NCH chunks = 441 blocks; bcount must be zeroed beforehand.
__global__ __launch_bounds__(256) void k_bcount(const int* __restrict__ edges,
                                                int* __restrict__ bcount) {
    __shared__ int bins[NBK];
    int bid = blockIdx.x;
    int r = bid / NCH, c = bid - r * NCH;
    int tid = threadIdx.x;
    for (int i = tid; i < NBK; i += 256) bins[i] = 0;
    __syncthreads();
    int e0 = c * CH1, e1 = min(EE, e0 + CH1);
    const int* ed = edges + (size_t)r * 2 * EE + EE;
    for (int e = e0 + tid; e < e1; e += 256)
        atomicAdd(&bins[__builtin_nontemporal_load(&ed[e]) >> 9], 1);
    __syncthreads();
    for (int i = tid; i < NBK; i += 256)
        if (bins[i]) atomicAdd(&bcount[r * NBK + i], bins[i]);
}

// ---------------- scan bucket counts -> bases, gcur seeds, off[NN] ----------
__global__ void k_bscan(const int* __restrict__ bcount, int* __restrict__ bbase,
                        int* __restrict__ gcur, int* __restrict__ off) {
    int r = threadIdx.x;
    if (r >= 9) return;
    int acc = 0;
    for (int b = 0; b < NBK; ++b) {
        bbase[r * (NBK + 1) + b] = acc;
        gcur[r * NBK + b] = acc;
        acc += bcount[r * NBK + b];
    }
    bbase[r * (NBK + 1) + NBK] = acc;
    off[r * (NN + 1) + NN] = acc;   // == EE
}

// ---------------- pass 1: bucket edges by dst>>9, packed u32 ----------------
__global__ __launch_bounds__(256) void k_bucket(const int* __restrict__ edges,
                                                int* __restrict__ gcur,
                                                unsigned* __restrict__ bpairs) {
    __shared__ int hist[NBK];
    __shared__ int sc[128];
    __shared__ int lofs[NBK + 1];
    __shared__ int lcur[NBK];
    __shared__ int gbase[NBK];
    __shared__ unsigned stage[CH1];
    int bid = blockIdx.x;
    int r = bid / NCH, c = bid - r * NCH;
    int tid = threadIdx.x;
    int e0 = c * CH1;
    int e1 = min(EE, e0 + CH1);
    int n = e1 - e0;
    const int* es = edges + (size_t)r * 2 * EE;
    const int* ed = es + EE;

    for (int i = tid; i < NBK; i += 256) hist[i] = 0;
    __syncthreads();
    for (int e = e0 + tid; e < e1; e += 256)
        atomicAdd(&hist[ed[e] >> 9], 1);
    __syncthreads();
    if (tid < 128) sc[tid] = (tid < NBK) ? hist[tid] : 0;
    __syncthreads();
#pragma unroll
    for (int s = 1; s < 128; s <<= 1) {
        int t = 0;
        if (tid < 128 && tid >= s) t = sc[tid - s];
        __syncthreads();
        if (tid < 128 && tid >= s) sc[tid] += t;
        __syncthreads();
    }
    if (tid < NBK) {
        int ex = sc[tid] - hist[tid];
        lofs[tid] = ex;
        lcur[tid] = ex;
        gbase[tid] = atomicAdd(&gcur[r * NBK + tid], hist[tid]);
    }
    if (tid == 0) lofs[NBK] = n;
    __syncthreads();
    for (int e = e0 + tid; e < e1; e += 256) {
        int dst = ed[e];
        int src = es[e];
        int p = atomicAdd(&lcur[dst >> 9], 1);
        stage[p] = ((unsigned)dst << 16) | (unsigned)src;
    }
    __syncthreads();
    unsigned* bp = bpairs + (size_t)r * EE;
    for (int i = tid; i < n; i += 256) {
        int lo = 0, hi = NBK;
        while (hi - lo > 1) {
            int m = (lo + hi) >> 1;
            if (lofs[m] <= i) lo = m; else hi = m;
        }
        bp[gbase[lo] + (i - lofs[lo])] = stage[i];
    }
}

// ---------------- pass 2: per-bucket degrees + offsets + LDS scatter --------
// Each block owns one bucket's contiguous segment. Derives in-bucket degrees
// from its pairs (512-bin LDS hist + scan), writes off/nd coalesced, then
// scatters src ids in LDS and streams out.
__global__ __launch_bounds__(256) void k_scatter(const unsigned* __restrict__ bpairs,
                                                 const int* __restrict__ bbase,
                                                 int* __restrict__ off,
                                                 float* __restrict__ nd,
                                                 int* __restrict__ esrc) {
    __shared__ int bins[BKW];
    __shared__ int lcur[BKW];
    __shared__ int wsum[4];
    __shared__ int lout[SCAP];
    int bid = blockIdx.x;
    int r = bid / NBK, b = bid - r * NBK;
    int tid = threadIdx.x;
    int d0 = b * BKW;
    int d1 = min(NN, d0 + BKW);
    int nb = d1 - d0;
    int s0 = bbase[r * (NBK + 1) + b];
    int s1 = bbase[r * (NBK + 1) + b + 1];
    int n = s1 - s0;
    for (int i = tid; i < BKW; i += 256) bins[i] = 0;
    __syncthreads();
    const unsigned* bp = bpairs + (size_t)r * EE + s0;
    for (int i = tid; i < n; i += 256)
        atomicAdd(&bins[(int)(bp[i] >> 16) - d0], 1);
    __syncthreads();
    // exclusive scan over 512 bins; thread t owns bins 2t, 2t+1
    int v0 = bins[2 * tid], v1 = bins[2 * tid + 1];
    int s = v0 + v1;
    int lane = tid & 63, w = tid >> 6;
    int x = s;
#pragma unroll
    for (int sh = 1; sh < 64; sh <<= 1) {
        int y = __shfl_up(x, (unsigned)sh);
        if (lane >= sh) x += y;
    }
    if (lane == 63) wsum[w] = x;
    __syncthreads();
    int wb = 0;
#pragma unroll
    for (int j = 0; j < 3; ++j) wb += (j < w) ? wsum[j] : 0;
    int ex = wb + x - s;      // exclusive prefix for bin 2t
    int* o = off + r * (NN + 1);
    if (2 * tid < nb) {
        o[d0 + 2 * tid] = s0 + ex;
        nd[r * NN + d0 + 2 * tid] = v0 ? rsqrtf((float)v0) : 0.f;
    }
    if (2 * tid + 1 < nb) {
        o[d0 + 2 * tid + 1] = s0 + ex + v0;
        nd[r * NN + d0 + 2 * tid + 1] = v1 ? rsqrtf((float)v1) : 0.f;
    }
    lcur[2 * tid] = ex;
    lcur[2 * tid + 1] = ex + v0;
    __syncthreads();
    int* out = esrc + (size_t)r * EE + s0;
    if (n <= SCAP) {
        for (int i = tid; i < n; i += 256) {
            unsigned pr = bp[i];
            int p = atomicAdd(&lcur[(int)(pr >> 16) - d0], 1);
            lout[p] = (int)(pr & 0xffffu);
        }
        __syncthreads();
        for (int i = tid; i < n; i += 256) out[i] = lout[i];
    } else {  // statistically unreachable safety path
        for (int i = tid; i < n; i += 256) {
            unsigned pr = bp[i];
            int p = atomicAdd(&lcur[(int)(pr >> 16) - d0], 1);
            out[p] = (int)(pr & 0xffffu);
        }
    }
}

// ---------------- x -> fp16 conversion ---------------------------------------
__global__ void k_xprep(const float* __restrict__ x0, const float* __restrict__ x1,
                        const float* __restrict__ x2, __half* __restrict__ xh) {
    int i = blockIdx.x * blockDim.x + threadIdx.x;  // float4 index over 3*NN*32
    const int per = NN * 32;
    if (i >= 3 * per) return;
    int tsel = i / per;
    int o = i - tsel * per;
    const float* xp = (tsel == 0) ? x0 : ((tsel == 1) ? x1 : x2);
    float4 v = *reinterpret_cast<const float4*>(xp + (size_t)o * 4);
    __half* dst = xh + (size_t)tsel * NN * 128 + (size_t)o * 4;
    *reinterpret_cast<__half2*>(dst) = __floats2half2_rn(v.x, v.y);
    *reinterpret_cast<__half2*>(dst + 2) = __floats2half2_rn(v.z, v.w);
}

// ---------------- W prep: fp32 [K][N] -> chunk-major fp16 plane -------------
__global__ void k_wprep(const float* __restrict__ W1, const float* __restrict__ W2,
                        __half* __restrict__ whi) {
    int id = blockIdx.x * blockDim.x + threadIdx.x;
    const int total = 2 * 9 * 128 * 128;
    if (id >= total) return;
    int n = id & 127;
    int k = (id >> 7) & 127;
    int rl = id >> 14;  // layer*9 + r
    const float* W = (rl < 9) ? W1 : W2;
    int r = (rl < 9) ? rl : rl - 9;
    float f = W[((size_t)r * 128 + k) * 128 + n];
    size_t oidx = (((size_t)rl * 4 + (k >> 5)) * 128 + n) * 32 + (k & 31);
    whi[oidx] = __float2half_rn(f);
}

// ---------------- aggregation (vectorized CSR gather, 3 src-sharing tasks) --
struct AggT {
    const __half* xin;
    const int* off;
    const int* esrc;
    const float* ns;
    const float* nd;
    __half* A;
};

template <int RELU>
__global__ __launch_bounds__(256) void k_agg3(AggT t0, AggT t1, AggT t2) {
    int bid = blockIdx.x;
    int task = bid % 3;
    AggT t = (task == 0) ? t0 : ((task == 1) ? t1 : t2);
    int wave = (bid / 3) * 4 + (threadIdx.x >> 6);
    int lane = threadIdx.x & 63;
    if (wave >= NN) return;
    int g = lane >> 4;       // edge slot 0..3
    int c = lane & 15;       // column group: cols c*8 .. c*8+7
    int e0 = t.off[wave], e1 = t.off[wave + 1];
    const __half* xin = t.xin;
    const int* esrc = t.esrc;
    const float* ns = t.ns;
    float acc[8] = {};
    for (int e = e0; e < e1; e += 8) {
        int ea = e + g;
        int eb = e + 4 + g;
        bool va = ea < e1, vb = eb < e1;
        int sa = va ? esrc[ea] : esrc[e];   // clamp to hot line
        int sb = vb ? esrc[eb] : esrc[e];
        float wa = va ? ns[sa] : 0.f;
        float wb = vb ? ns[sb] : 0.f;
        float4 ra = *reinterpret_cast<const float4*>(xin + (size_t)sa * 128 + c * 8);
        float4 rb = *reinterpret_cast<const float4*>(xin + (size_t)sb * 128 + c * 8);
        const __half2* pa = reinterpret_cast<const __half2*>(&ra);
        const __half2* pb = reinterpret_cast<const __half2*>(&rb);
#pragma unroll
        for (int j = 0; j < 4; ++j) {
            float2 fa = __half22float2(pa[j]);
            float2 fb = __half22float2(pb[j]);
            if (RELU) {
                fa.x = fmaxf(fa.x, 0.f); fa.y = fmaxf(fa.y, 0.f);
                fb.x = fmaxf(fb.x, 0.f); fb.y = fmaxf(fb.y, 0.f);
            }
            acc[2 * j]     = fmaf(wa, fa.x, acc[2 * j]);
            acc[2 * j + 1] = fmaf(wa, fa.y, acc[2 * j + 1]);
            acc[2 * j]     = fmaf(wb, fb.x, acc[2 * j]);
            acc[2 * j + 1] = fmaf(wb, fb.y, acc[2 * j + 1]);
        }
    }
#pragma unroll
    for (int j = 0; j < 8; ++j) {
        acc[j] += __shfl_xor(acc[j], 16);
        acc[j] += __shfl_xor(acc[j], 32);
    }
    if (g == 0) {
        float nr = t.nd[wave];
        f16x8 hv;
#pragma unroll
        for (int j = 0; j < 8; ++j) hv[j] = (_Float16)(acc[j] * nr);
        *reinterpret_cast<f16x8*>(t.A + (size_t)wave * 128 + c * 8) = hv;
    }
}

// ---------------- f16 MFMA GEMM: H (=|+=) sum_s A_s @ W_s + bias ------------
template <int NS, int STORE>
__global__ __launch_bounds__(256) void k_gemm_mfma(
    const __half* __restrict__ Aa, const __half* __restrict__ Ab,
    const __half* __restrict__ wha, const __half* __restrict__ whb,
    const float* __restrict__ ba, const float* __restrict__ bb,
    __half* __restrict__ H) {
    int tid = threadIdx.x;
    int w = tid >> 6, lane = tid & 63;
    int row0 = blockIdx.x * 64;
    int colbase = w * 32;
    int r16 = lane & 15;
    int koff = (lane >> 4) * 8;

    f32x4 acc[4][2];
#pragma unroll
    for (int rt = 0; rt < 4; ++rt)
#pragma unroll
        for (int nt = 0; nt < 2; ++nt)
            acc[rt][nt] = f32x4{0.f, 0.f, 0.f, 0.f};

#pragma unroll
    for (int s = 0; s < NS; ++s) {
        const __half* A = (s == 0) ? Aa : Ab;
        const __half* w_h = (s == 0) ? wha : whb;
#pragma unroll
        for (int c = 0; c < 4; ++c) {
            int kbase = c * 32 + koff;
            f16x8 av[4], bh[2];
#pragma unroll
            for (int rt = 0; rt < 4; ++rt) {
                int rr = rt * 16 + r16;
                int rc = (row0 + rr < NN) ? rr : 0;
                av[rt] = *reinterpret_cast<const f16x8*>(
                    A + ((size_t)(row0 + rc)) * 128 + kbase);
            }
#pragma unroll
            for (int nt = 0; nt < 2; ++nt) {
                int col = colbase + nt * 16 + r16;
                size_t widx = ((size_t)c * 128 + col) * 32 + koff;
                bh[nt] = *reinterpret_cast<const f16x8*>(w_h + widx);
            }
#pragma unroll
            for (int rt = 0; rt < 4; ++rt)
#pragma unroll
                for (int nt = 0; nt < 2; ++nt)
                    acc[rt][nt] = MFMAH(av[rt], bh[nt], acc[rt][nt]);
        }
    }

    int orow = (lane >> 4) * 4;
#pragma unroll
    for (int nt = 0; nt < 2; ++nt) {
        int col = colbase + nt * 16 + r16;
        float bias = ba[col];
        if (NS == 2) bias += bb[col];
#pragma unroll
        for (int rt = 0; rt < 4; ++rt) {
#pragma unroll
            for (int j = 0; j < 4; ++j) {
                int grow = row0 + rt * 16 + orow + j;
                if (grow < NN) {
                    __half* hp = H + (size_t)grow * 128 + col;
                    float v = acc[rt][nt][j] + bias;
                    if (!STORE) v += __half2float(*hp);
                    *hp = __float2half_rn(v);
                }
            }
        }
    }
}

// ---------------- classifier: out = relu(H_fp16) @ Wc + bc ------------------
__global__ __launch_bounds__(256) void k_classifier(const __half* __restrict__ H,
                                                    const float* __restrict__ Wc,
                                                    const float* __restrict__ bc,
                                                    float* __restrict__ out) {
    __shared__ float sW[128 * 16];
    __shared__ float sb[16];
    int tid = threadIdx.x;
#pragma unroll
    for (int i = tid; i < 2048; i += 256) sW[i] = Wc[i];
    if (tid < 16) sb[tid] = bc[tid];
    __syncthreads();
    int node = blockIdx.x * 64 + (tid >> 2);
    if (node >= 3 * NN) return;
    int cg = (tid & 3) << 2;
    const __half* h = H + (size_t)node * 128;
    float acc0 = 0.f, acc1 = 0.f, acc2 = 0.f, acc3 = 0.f;
#pragma unroll 2
    for (int k0 = 0; k0 < 128; k0 += 8) {
        float4 raw = *reinterpret_cast<const float4*>(h + k0);  // 8 halves
        const __half2* hp2 = reinterpret_cast<const __half2*>(&raw);
#pragma unroll
        for (int jj = 0; jj < 4; ++jj) {
            float2 f = __half22float2(hp2[jj]);
            float a;
            a = fmaxf(f.x, 0.f);
            { float4 wv = *reinterpret_cast<const float4*>(&sW[(k0 + 2 * jj) * 16 + cg]);
              acc0 = fmaf(a, wv.x, acc0); acc1 = fmaf(a, wv.y, acc1);
              acc2 = fmaf(a, wv.z, acc2); acc3 = fmaf(a, wv.w, acc3); }
            a = fmaxf(f.y, 0.f);
            { float4 wv = *reinterpret_cast<const float4*>(&sW[(k0 + 2 * jj + 1) * 16 + cg]);
              acc0 = fmaf(a, wv.x, acc0); acc1 = fmaf(a, wv.y, acc1);
              acc2 = fmaf(a, wv.z, acc2); acc3 = fmaf(a, wv.w, acc3); }
        }
    }
    float4 o = make_float4(acc0 + sb[cg], acc1 + sb[cg + 1],
                           acc2 + sb[cg + 2], acc3 + sb[cg + 3]);
    *reinterpret_cast<float4*>(out + (size_t)node * 16 + cg) = o;
}

// ---------------------------------------------------------------------------
extern "C" void kernel_launch(void* const* d_in, const int* in_sizes, int n_in,
                              void* d_out, int out_size, void* d_ws, size_t ws_size,
                              hipStream_t stream) {
    const float* x0 = (const float*)d_in[0];
    const float* x1 = (const float*)d_in[1];
    const float* x2 = (const float*)d_in[2];
    const float* W1 = (const float*)d_in[3];
    const float* b1 = (const float*)d_in[4];
    const float* W2 = (const float*)d_in[5];
    const float* b2 = (const float*)d_in[6];
    const float* Wc = (const float*)d_in[7];
    const float* bc = (const float*)d_in[8];
    const int* edges = (const int*)d_in[9];

    // ---- workspace carve-up with overlays (~212 MB peak) ----
    char* p = (char*)d_ws;
    auto alloc = [&](size_t bytes) -> void* {
        void* r = (void*)p;
        p += (bytes + 255) & ~(size_t)255;
        return r;
    };
    __half* h2h = (__half*)alloc((size_t)3 * NN * 128 * sizeof(__half));  // 38.4 MB
    // aliases inside h2h (dead before first h2h write at layer-2 GEMM):
    unsigned* hist = (unsigned*)h2h;     // 14.4 MB, live [k_hist, k_sums)
    unsigned* bpairs = (unsigned*)h2h;   // 14.4 MB, live [k_bucket, k_scatter)
    __half* xh  = (__half*)alloc((size_t)3 * NN * 128 * sizeof(__half));  // 38.4 MB
    __half* h1h = (__half*)alloc((size_t)3 * NN * 128 * sizeof(__half));  // 38.4 MB
    __half* A6  = (__half*)alloc((size_t)6 * NN * 128 * sizeof(__half));  // 76.8 MB
    int* off = (int*)alloc((size_t)9 * (NN + 1) * sizeof(int));
    float* ns = (float*)alloc((size_t)9 * NN * sizeof(float));
    float* nd = (float*)alloc((size_t)9 * NN * sizeof(float));
    int* esrc = (int*)alloc((size_t)9 * EE * sizeof(int));                // 14.4 MB
    __half* whi = (__half*)alloc((size_t)2 * 9 * 128 * 128 * sizeof(__half));
    int* gcur = (int*)alloc((size_t)9 * NBK * sizeof(int));
    int* bcount = (int*)alloc((size_t)9 * NBK * sizeof(int));
    int* bbase = (int*)alloc((size_t)9 * (NBK + 1) * sizeof(int));
    __half* P[6];
    for (int j = 0; j < 6; ++j) P[j] = A6 + (size_t)j * NN * 128;
    const __half* xph[3] = {xh, xh + (size_t)NN * 128, xh + (size_t)2 * NN * 128};

    // ---- CSR build + input/weight prep (reused by both layers) ----
    k_hist<<<9 * NRG * HCH, 256, 0, stream>>>(edges, hist);
    k_xprep<<<(3 * NN * 32 + 255) / 256, 256, 0, stream>>>(x0, x1, x2, xh);
    k_sums<<<(9 * (NN / 2) + 255) / 256, 256, 0, stream>>>(hist, ns);
    hipMemsetAsync(bcount, 0, (size_t)9 * NBK * sizeof(int), stream);
    k_bcount<<<9 * NCH, 256, 0, stream>>>(edges, bcount);
    k_bscan<<<1, 64, 0, stream>>>(bcount, bbase, gcur, off);
    k_bucket<<<9 * NCH, 256, 0, stream>>>(edges, gcur, bpairs);
    k_scatter<<<9 * NBK, 256, 0, stream>>>(bpairs, bbase, off, nd, esrc);
    k_wprep<<<(2 * 9 * 128 * 128 + 255) / 256, 256, 0, stream>>>(W1, W2, whi);

    const int agg_grid = 3 * 12500;
    const int gemm_blocks = (NN + 63) / 64;   // 782

    auto mk = [&](int r, const __half* xin, __half* slot) -> AggT {
        return AggT{xin, off + r * (NN + 1), esrc + (size_t)r * EE,
                    ns + r * NN, nd + r * NN, slot};
    };
    auto wp = [&](int layer, int r) { return (size_t)(layer * 9 + r) * 16384; };

    // src groups: S0={0,3,6} (src type0), S1={1,2,8} (type1), S2={4,5,7} (type2)
    // dst map: r0->2 r1->2 r2->0 r3->0 r4->1 r5->0 r6->0 r7->2 r8->1
    for (int L = 0; L < 2; ++L) {
        const float* b = (L == 0) ? b1 : b2;
        __half* o0 = ((L == 0) ? h1h : h2h) + (size_t)0 * NN * 128;
        __half* o1 = ((L == 0) ? h1h : h2h) + (size_t)1 * NN * 128;
        __half* o2 = ((L == 0) ? h1h : h2h) + (size_t)2 * NN * 128;
        const __half* in0 = (L == 0) ? xph[0] : h1h + (size_t)0 * NN * 128;
        const __half* in1 = (L == 0) ? xph[1] : h1h + (size_t)1 * NN * 128;
        const __half* in2 = (L == 0) ? xph[2] : h1h + (size_t)2 * NN * 128;

        // aggS0: rels {0,3,6} all read in0 -> slots P0,P1,P2
        if (L == 0)
            k_agg3<0><<<agg_grid, 256, 0, stream>>>(mk(0, in0, P[0]), mk(3, in0, P[1]),
                                                    mk(6, in0, P[2]));
        else
            k_agg3<1><<<agg_grid, 256, 0, stream>>>(mk(0, in0, P[0]), mk(3, in0, P[1]),
                                                    mk(6, in0, P[2]));
        // gemm (3,6) -> o0 STORE ; gemm (0) -> o2 STORE
        k_gemm_mfma<2, 1><<<gemm_blocks, 256, 0, stream>>>(
            P[1], P[2], whi + wp(L, 3), whi + wp(L, 6),
            b + 3 * 128, b + 6 * 128, o0);
        k_gemm_mfma<1, 1><<<gemm_blocks, 256, 0, stream>>>(
            P[0], P[0], whi + wp(L, 0), whi + wp(L, 0),
            b + 0 * 128, b + 0 * 128, o2);

        // aggS1: rels {1,2,8} all read in1 -> slots P3,P4,P5
        if (L == 0)
            k_agg3<0><<<agg_grid, 256, 0, stream>>>(mk(1, in1, P[3]), mk(2, in1, P[4]),
                                                    mk(8, in1, P[5]));
        else
            k_agg3<1><<<agg_grid, 256, 0, stream>>>(mk(1, in1, P[3]), mk(2, in1, P[4]),
                                                    mk(8, in1, P[5]));
        // aggS2: rels {4,5,7} all read in2 -> slots P0,P1,P2 (S0's, consumed)
        if (L == 0)
            k_agg3<0><<<agg_grid, 256, 0, stream>>>(mk(4, in2, P[0]), mk(5, in2, P[1]),
                                                    mk(7, in2, P[2]));
        else
            k_agg3<1><<<agg_grid, 256, 0, stream>>>(mk(4, in2, P[0]), mk(5, in2, P[1]),
                                                    mk(7, in2, P[2]));

        // gemm (8,4) -> o1 STORE ; (2,5) -> o0 ACC ; (1,7) -> o2 ACC
        k_gemm_mfma<2, 1><<<gemm_blocks, 256, 0, stream>>>(
            P[5], P[0], whi + wp(L, 8), whi + wp(L, 4),
            b + 8 * 128, b + 4 * 128, o1);
        k_gemm_mfma<2, 0><<<gemm_blocks, 256, 0, stream>>>(
            P[4], P[1], whi + wp(L, 2), whi + wp(L, 5),
            b + 2 * 128, b + 5 * 128, o0);
        k_gemm_mfma<2, 0><<<gemm_blocks, 256, 0, stream>>>(
            P[3], P[2], whi + wp(L, 1), whi + wp(L, 7),
            b + 1 * 128, b + 7 * 128, o2);
    }

    // ---- classifier: out = relu(h2h) @ Wc + bc ----
    k_classifier<<<(3 * NN + 63) / 64, 256, 0, stream>>>(h2h, Wc, bc, (float*)d_out);
}

// Round 16
// 753.537 us; speedup vs baseline: 1.9222x; 1.0595x over previous
//
#include <hip/hip_runtime.h>
#include <hip/hip_bf16.h>
#include <hip/hip_fp16.h>

// ---------------------------------------------------------------------------
// Hetero-GCN (3 node types, 9 relations), 2 GraphConv layers + classifier.
// Round 16 (agg was 53% of total; VALUBusy 50%):
//  - k_agg3: packed-fp16 accumulation (v_pk_fma_f16/v_pk_max_f16) into 4
//    independent half2 accumulator sets (<=4 fp16 adds each at deg~8),
//    combined in fp32 before the cross-slot shfl reduce. ~3x fewer VALU ops.
//  - esn packs {ns_fp16<<16 | src} (src<2^16): one load gives index+weight,
//    deleting the dependent ns load from the gather chain.
//  - 16 edges/iteration (4 slot-batches): 95% of rows finish in ONE
//    dependent-load round-trip (was 2 for ~45% at Poisson(8) degree).
//  - everything else frozen (single-pass f16 GEMM, bucketed CSR).
// ---------------------------------------------------------------------------

#define NN 50000
#define EE 400000
#define NRG 4            // node ranges for src histogram
#define RGN (NN / NRG)   // 12500 nodes per range
#define HCH 16           // edge chunks
#define HEG (EE / HCH)   // 25000 edges per chunk
#define NBK 98           // dst buckets (dst>>9)
#define BKW 512          // dsts per bucket
#define CH1 8192         // bucket pass-1 edges per chunk
#define NCH ((EE + CH1 - 1) / CH1)   // 49
#define SCAP 6656        // bucket pass-2 LDS segment capacity

typedef __attribute__((ext_vector_type(8))) _Float16 f16x8;
typedef __attribute__((ext_vector_type(2))) _Float16 h2f;
typedef __attribute__((ext_vector_type(4))) float f32x4;
#define MFMAH(a, b, c) __builtin_amdgcn_mfma_f32_16x16x32_f16(a, b, c, 0, 0, 0)

// ---------------- src-degree histogram (chunked, LDS) -----------------------
__global__ __launch_bounds__(256) void k_hist(const int* __restrict__ edges,
                                              unsigned* __restrict__ hist) {
    __shared__ unsigned bins[RGN / 2];  // 6250 u32 = 25 KB
    int bid = blockIdx.x;
    int r = bid >> 6;              // NRG*HCH = 64 blocks per relation
    int rem = bid & 63;
    int rg = rem >> 4;
    int c = rem & 15;
    int tid = threadIdx.x;
    for (int i = tid; i < RGN / 2; i += 256) bins[i] = 0;
    __syncthreads();
    const int* ea = edges + (size_t)r * 2 * EE + (size_t)c * HEG;  // src side
    int base = rg * RGN;
    for (int e = tid; e < HEG; e += 256) {
        int idx = __builtin_nontemporal_load(&ea[e]) - base;
        if ((unsigned)idx < (unsigned)RGN)
            atomicAdd(&bins[idx >> 1], (idx & 1) ? 65536u : 1u);
    }
    __syncthreads();
    unsigned* ho = hist + ((size_t)(r * NRG + rg) * HCH + c) * (RGN / 2);
    for (int i = tid; i < RGN / 2; i += 256) ho[i] = bins[i];
}

// ---------------- reduce histograms -> ns (fp16) ----------------------------
__global__ void k_sums(const unsigned* __restrict__ hist, __half* __restrict__ nsh) {
    int i = blockIdx.x * blockDim.x + threadIdx.x;
    if (i >= 9 * (NN / 2)) return;
    int r = i / (NN / 2);
    int ps = i - r * (NN / 2);
    int rg = ps / (RGN / 2);
    int slot = ps - rg * (RGN / 2);
    const unsigned* hs = hist + ((size_t)(r * NRG + rg) * HCH) * (RGN / 2) + slot;
    unsigned slo = 0, shi = 0;
#pragma unroll
    for (int c = 0; c < HCH; ++c) {
        unsigned a = hs[(size_t)c * (RGN / 2)];
        slo += a & 0xffffu; shi += a >> 16;
    }
    int n0 = 2 * ps;
    nsh[r * NN + n0]     = slo ? __float2half_rn(rsqrtf((float)slo)) : __half(0.f);
    nsh[r * NN + n0 + 1] = shi ? __float2half_rn(rsqrtf((float)shi)) : __half(0.f);
}

// ---------------- per-bucket edge counts ------------------------------------
__global__ __launch_bounds__(256) void k_bcount(const int* __restrict__ edges,
                                                int* __restrict__ bcount) {
    __shared__ int bins[NBK];
    int bid = blockIdx.x;
    int r = bid / NCH, c = bid - r * NCH;
    int tid = threadIdx.x;
    for (int i = tid; i < NBK; i += 256) bins[i] = 0;
    __syncthreads();
    int e0 = c * CH1, e1 = min(EE, e0 + CH1);
    const int* ed = edges + (size_t)r * 2 * EE + EE;
    for (int e = e0 + tid; e < e1; e += 256)
        atomicAdd(&bins[__builtin_nontemporal_load(&ed[e]) >> 9], 1);
    __syncthreads();
    for (int i = tid; i < NBK; i += 256)
        if (bins[i]) atomicAdd(&bcount[r * NBK + i], bins[i]);
}

// ---------------- scan bucket counts -> bases, gcur seeds, off[NN] ----------
__global__ void k_bscan(const int* __restrict__ bcount, int* __restrict__ bbase,
                        int* __restrict__ gcur, int* __restrict__ off) {
    int r = threadIdx.x;
    if (r >= 9) return;
    int acc = 0;
    for (int b = 0; b < NBK; ++b) {
        bbase[r * (NBK + 1) + b] = acc;
        gcur[r * NBK + b] = acc;
        acc += bcount[r * NBK + b];
    }
    bbase[r * (NBK + 1) + NBK] = acc;
    off[r * (NN + 1) + NN] = acc;   // == EE
}

// ---------------- pass 1: bucket edges by dst>>9, packed u32 ----------------
__global__ __launch_bounds__(256) void k_bucket(const int* __restrict__ edges,
                                                int* __restrict__ gcur,
                                                unsigned* __restrict__ bpairs) {
    __shared__ int hist[NBK];
    __shared__ int sc[128];
    __shared__ int lofs[NBK + 1];
    __shared__ int lcur[NBK];
    __shared__ int gbase[NBK];
    __shared__ unsigned stage[CH1];
    int bid = blockIdx.x;
    int r = bid / NCH, c = bid - r * NCH;
    int tid = threadIdx.x;
    int e0 = c * CH1;
    int e1 = min(EE, e0 + CH1);
    int n = e1 - e0;
    const int* es = edges + (size_t)r * 2 * EE;
    const int* ed = es + EE;

    for (int i = tid; i < NBK; i += 256) hist[i] = 0;
    __syncthreads();
    for (int e = e0 + tid; e < e1; e += 256)
        atomicAdd(&hist[ed[e] >> 9], 1);
    __syncthreads();
    if (tid < 128) sc[tid] = (tid < NBK) ? hist[tid] : 0;
    __syncthreads();
#pragma unroll
    for (int s = 1; s < 128; s <<= 1) {
        int t = 0;
        if (tid < 128 && tid >= s) t = sc[tid - s];
        __syncthreads();
        if (tid < 128 && tid >= s) sc[tid] += t;
        __syncthreads();
    }
    if (tid < NBK) {
        int ex = sc[tid] - hist[tid];
        lofs[tid] = ex;
        lcur[tid] = ex;
        gbase[tid] = atomicAdd(&gcur[r * NBK + tid], hist[tid]);
    }
    if (tid == 0) lofs[NBK] = n;
    __syncthreads();
    for (int e = e0 + tid; e < e1; e += 256) {
        int dst = ed[e];
        int src = es[e];
        int p = atomicAdd(&lcur[dst >> 9], 1);
        stage[p] = ((unsigned)dst << 16) | (unsigned)src;
    }
    __syncthreads();
    unsigned* bp = bpairs + (size_t)r * EE;
    for (int i = tid; i < n; i += 256) {
        int lo = 0, hi = NBK;
        while (hi - lo > 1) {
            int m = (lo + hi) >> 1;
            if (lofs[m] <= i) lo = m; else hi = m;
        }
        bp[gbase[lo] + (i - lofs[lo])] = stage[i];
    }
}

// ---------------- pass 2: per-bucket degrees + offsets + LDS scatter --------
// Writes esn packed {ns_fp16<<16 | src}.
__global__ __launch_bounds__(256) void k_scatter(const unsigned* __restrict__ bpairs,
                                                 const int* __restrict__ bbase,
                                                 const __half* __restrict__ nsh,
                                                 int* __restrict__ off,
                                                 float* __restrict__ nd,
                                                 unsigned* __restrict__ esn) {
    __shared__ int bins[BKW];
    __shared__ int lcur[BKW];
    __shared__ int wsum[4];
    __shared__ unsigned lout[SCAP];
    int bid = blockIdx.x;
    int r = bid / NBK, b = bid - r * NBK;
    int tid = threadIdx.x;
    int d0 = b * BKW;
    int d1 = min(NN, d0 + BKW);
    int nb = d1 - d0;
    int s0 = bbase[r * (NBK + 1) + b];
    int s1 = bbase[r * (NBK + 1) + b + 1];
    int n = s1 - s0;
    for (int i = tid; i < BKW; i += 256) bins[i] = 0;
    __syncthreads();
    const unsigned* bp = bpairs + (size_t)r * EE + s0;
    for (int i = tid; i < n; i += 256)
        atomicAdd(&bins[(int)(bp[i] >> 16) - d0], 1);
    __syncthreads();
    int v0 = bins[2 * tid], v1 = bins[2 * tid + 1];
    int s = v0 + v1;
    int lane = tid & 63, w = tid >> 6;
    int x = s;
#pragma unroll
    for (int sh = 1; sh < 64; sh <<= 1) {
        int y = __shfl_up(x, (unsigned)sh);
        if (lane >= sh) x += y;
    }
    if (lane == 63) wsum[w] = x;
    __syncthreads();
    int wb = 0;
#pragma unroll
    for (int j = 0; j < 3; ++j) wb += (j < w) ? wsum[j] : 0;
    int ex = wb + x - s;      // exclusive prefix for bin 2t
    int* o = off + r * (NN + 1);
    if (2 * tid < nb) {
        o[d0 + 2 * tid] = s0 + ex;
        nd[r * NN + d0 + 2 * tid] = v0 ? rsqrtf((float)v0) : 0.f;
    }
    if (2 * tid + 1 < nb) {
        o[d0 + 2 * tid + 1] = s0 + ex + v0;
        nd[r * NN + d0 + 2 * tid + 1] = v1 ? rsqrtf((float)v1) : 0.f;
    }
    lcur[2 * tid] = ex;
    lcur[2 * tid + 1] = ex + v0;
    __syncthreads();
    const __half* nsr = nsh + (size_t)r * NN;
    unsigned* out = esn + (size_t)r * EE + s0;
    if (n <= SCAP) {
        for (int i = tid; i < n; i += 256) {
            unsigned pr = bp[i];
            int src = (int)(pr & 0xffffu);
            unsigned wbits = (unsigned)__half_as_ushort(nsr[src]);
            int p = atomicAdd(&lcur[(int)(pr >> 16) - d0], 1);
            lout[p] = (wbits << 16) | (unsigned)src;
        }
        __syncthreads();
        for (int i = tid; i < n; i += 256) out[i] = lout[i];
    } else {  // statistically unreachable safety path
        for (int i = tid; i < n; i += 256) {
            unsigned pr = bp[i];
            int src = (int)(pr & 0xffffu);
            unsigned wbits = (unsigned)__half_as_ushort(nsr[src]);
            int p = atomicAdd(&lcur[(int)(pr >> 16) - d0], 1);
            out[p] = (wbits << 16) | (unsigned)src;
        }
    }
}

// ---------------- x -> fp16 conversion ---------------------------------------
__global__ void k_xprep(const float* __restrict__ x0, const float* __restrict__ x1,
                        const float* __restrict__ x2, __half* __restrict__ xh) {
    int i = blockIdx.x * blockDim.x + threadIdx.x;  // float4 index over 3*NN*32
    const int per = NN * 32;
    if (i >= 3 * per) return;
    int tsel = i / per;
    int o = i - tsel * per;
    const float* xp = (tsel == 0) ? x0 : ((tsel == 1) ? x1 : x2);
    float4 v = *reinterpret_cast<const float4*>(xp + (size_t)o * 4);
    __half* dst = xh + (size_t)tsel * NN * 128 + (size_t)o * 4;
    *reinterpret_cast<__half2*>(dst) = __floats2half2_rn(v.x, v.y);
    *reinterpret_cast<__half2*>(dst + 2) = __floats2half2_rn(v.z, v.w);
}

// ---------------- W prep: fp32 [K][N] -> chunk-major fp16 plane -------------
__global__ void k_wprep(const float* __restrict__ W1, const float* __restrict__ W2,
                        __half* __restrict__ whi) {
    int id = blockIdx.x * blockDim.x + threadIdx.x;
    const int total = 2 * 9 * 128 * 128;
    if (id >= total) return;
    int n = id & 127;
    int k = (id >> 7) & 127;
    int rl = id >> 14;  // layer*9 + r
    const float* W = (rl < 9) ? W1 : W2;
    int r = (rl < 9) ? rl : rl - 9;
    float f = W[((size_t)r * 128 + k) * 128 + n];
    size_t oidx = (((size_t)rl * 4 + (k >> 5)) * 128 + n) * 32 + (k & 31);
    whi[oidx] = __float2half_rn(f);
}

// ---------------- aggregation (packed-fp16 CSR gather, 3 src-sharing tasks) -
// One wave per dst row: 4 edge-slots x 16 col-lanes, 16 edges/iteration in 4
// batches, pk_fma into 4 independent half2 accumulator sets, fp32 combine +
// cross-slot shfl reduce. esn packs {ns_fp16<<16|src} (one load = idx+weight).
struct AggT {
    const __half* xin;
    const int* off;
    const unsigned* esn;
    const float* nd;
    __half* A;
};

template <int RELU>
__global__ __launch_bounds__(256) void k_agg3(AggT t0, AggT t1, AggT t2) {
    int bid = blockIdx.x;
    int task = bid % 3;
    AggT t = (task == 0) ? t0 : ((task == 1) ? t1 : t2);
    int wave = (bid / 3) * 4 + (threadIdx.x >> 6);
    int lane = threadIdx.x & 63;
    if (wave >= NN) return;
    int g = lane >> 4;       // edge slot 0..3
    int c = lane & 15;       // column group: cols c*8 .. c*8+7
    int e0 = t.off[wave], e1 = t.off[wave + 1];
    const __half* xin = t.xin;
    const unsigned* esn = t.esn;
    const h2f zz = {(_Float16)0.f, (_Float16)0.f};
    h2f accA[4] = {zz, zz, zz, zz};
    h2f accB[4] = {zz, zz, zz, zz};
    h2f accC[4] = {zz, zz, zz, zz};
    h2f accD[4] = {zz, zz, zz, zz};
    for (int e = e0; e < e1; e += 16) {
        int ea = e + g, eb = e + 4 + g, ec = e + 8 + g, ed = e + 12 + g;
        bool va = ea < e1, vb = eb < e1, vc = ec < e1, vd = ed < e1;
        unsigned ua = esn[va ? ea : e];
        unsigned ub = esn[vb ? eb : e];
        unsigned uc = esn[vc ? ec : e];
        unsigned ud = esn[vd ? ed : e];
        int sa = ua & 0xffffu, sb = ub & 0xffffu, sc_ = uc & 0xffffu, sd = ud & 0xffffu;
        _Float16 wa = va ? __builtin_bit_cast(_Float16, (unsigned short)(ua >> 16)) : (_Float16)0.f;
        _Float16 wb = vb ? __builtin_bit_cast(_Float16, (unsigned short)(ub >> 16)) : (_Float16)0.f;
        _Float16 wc = vc ? __builtin_bit_cast(_Float16, (unsigned short)(uc >> 16)) : (_Float16)0.f;
        _Float16 wd = vd ? __builtin_bit_cast(_Float16, (unsigned short)(ud >> 16)) : (_Float16)0.f;
        h2f wav = {wa, wa}, wbv = {wb, wb}, wcv = {wc, wc}, wdv = {wd, wd};
        float4 ra = *reinterpret_cast<const float4*>(xin + (size_t)sa * 128 + c * 8);
        float4 rb = *reinterpret_cast<const float4*>(xin + (size_t)sb * 128 + c * 8);
        float4 rc = *reinterpret_cast<const float4*>(xin + (size_t)sc_ * 128 + c * 8);
        float4 rd = *reinterpret_cast<const float4*>(xin + (size_t)sd * 128 + c * 8);
        const h2f* pa = reinterpret_cast<const h2f*>(&ra);
        const h2f* pb = reinterpret_cast<const h2f*>(&rb);
        const h2f* pc = reinterpret_cast<const h2f*>(&rc);
        const h2f* pd = reinterpret_cast<const h2f*>(&rd);
#pragma unroll
        for (int j = 0; j < 4; ++j) {
            h2f fa = pa[j], fb = pb[j], fc = pc[j], fd = pd[j];
            if (RELU) {
                fa = __builtin_elementwise_max(fa, zz);
                fb = __builtin_elementwise_max(fb, zz);
                fc = __builtin_elementwise_max(fc, zz);
                fd = __builtin_elementwise_max(fd, zz);
            }
            accA[j] = wav * fa + accA[j];   // v_pk_fma_f16
            accB[j] = wbv * fb + accB[j];
            accC[j] = wcv * fc + accC[j];
            accD[j] = wdv * fd + accD[j];
        }
    }
    float acc[8];
#pragma unroll
    for (int j = 0; j < 4; ++j) {
        acc[2 * j]     = ((float)accA[j][0] + (float)accB[j][0]) +
                         ((float)accC[j][0] + (float)accD[j][0]);
        acc[2 * j + 1] = ((float)accA[j][1] + (float)accB[j][1]) +
                         ((float)accC[j][1] + (float)accD[j][1]);
    }
#pragma unroll
    for (int j = 0; j < 8; ++j) {
        acc[j] += __shfl_xor(acc[j], 16);
        acc[j] += __shfl_xor(acc[j], 32);
    }
    if (g == 0) {
        float nr = t.nd[wave];
        f16x8 hv;
#pragma unroll
        for (int j = 0; j < 8; ++j) hv[j] = (_Float16)(acc[j] * nr);
        *reinterpret_cast<f16x8*>(t.A + (size_t)wave * 128 + c * 8) = hv;
    }
}

// ---------------- f16 MFMA GEMM: H (=|+=) sum_s A_s @ W_s + bias ------------
template <int NS, int STORE>
__global__ __launch_bounds__(256) void k_gemm_mfma(
    const __half* __restrict__ Aa, const __half* __restrict__ Ab,
    const __half* __restrict__ wha, const __half* __restrict__ whb,
    const float* __restrict__ ba, const float* __restrict__ bb,
    __half* __restrict__ H) {
    int tid = threadIdx.x;
    int w = tid >> 6, lane = tid & 63;
    int row0 = blockIdx.x * 64;
    int colbase = w * 32;
    int r16 = lane & 15;
    int koff = (lane >> 4) * 8;

    f32x4 acc[4][2];
#pragma unroll
    for (int rt = 0; rt < 4; ++rt)
#pragma unroll
        for (int nt = 0; nt < 2; ++nt)
            acc[rt][nt] = f32x4{0.f, 0.f, 0.f, 0.f};

#pragma unroll
    for (int s = 0; s < NS; ++s) {
        const __half* A = (s == 0) ? Aa : Ab;
        const __half* w_h = (s == 0) ? wha : whb;
#pragma unroll
        for (int c = 0; c < 4; ++c) {
            int kbase = c * 32 + koff;
            f16x8 av[4], bh[2];
#pragma unroll
            for (int rt = 0; rt < 4; ++rt) {
                int rr = rt * 16 + r16;
                int rc = (row0 + rr < NN) ? rr : 0;
                av[rt] = *reinterpret_cast<const f16x8*>(
                    A + ((size_t)(row0 + rc)) * 128 + kbase);
            }
#pragma unroll
            for (int nt = 0; nt < 2; ++nt) {
                int col = colbase + nt * 16 + r16;
                size_t widx = ((size_t)c * 128 + col) * 32 + koff;
                bh[nt] = *reinterpret_cast<const f16x8*>(w_h + widx);
            }
#pragma unroll
            for (int rt = 0; rt < 4; ++rt)
#pragma unroll
                for (int nt = 0; nt < 2; ++nt)
                    acc[rt][nt] = MFMAH(av[rt], bh[nt], acc[rt][nt]);
        }
    }

    int orow = (lane >> 4) * 4;
#pragma unroll
    for (int nt = 0; nt < 2; ++nt) {
        int col = colbase + nt * 16 + r16;
        float bias = ba[col];
        if (NS == 2) bias += bb[col];
#pragma unroll
        for (int rt = 0; rt < 4; ++rt) {
#pragma unroll
            for (int j = 0; j < 4; ++j) {
                int grow = row0 + rt * 16 + orow + j;
                if (grow < NN) {
                    __half* hp = H + (size_t)grow * 128 + col;
                    float v = acc[rt][nt][j] + bias;
                    if (!STORE) v += __half2float(*hp);
                    *hp = __float2half_rn(v);
                }
            }
        }
    }
}

// ---------------- classifier: out = relu(H_fp16) @ Wc + bc ------------------
__global__ __launch_bounds__(256) void k_classifier(const __half* __restrict__ H,
                                                    const float* __restrict__ Wc,
                                                    const float* __restrict__ bc,
                                                    float* __restrict__ out) {
    __shared__ float sW[128 * 16];
    __shared__ float sb[16];
    int tid = threadIdx.x;
#pragma unroll
    for (int i = tid; i < 2048; i += 256) sW[i] = Wc[i];
    if (tid < 16) sb[tid] = bc[tid];
    __syncthreads();
    int node = blockIdx.x * 64 + (tid >> 2);
    if (node >= 3 * NN) return;
    int cg = (tid & 3) << 2;
    const __half* h = H + (size_t)node * 128;
    float acc0 = 0.f, acc1 = 0.f, acc2 = 0.f, acc3 = 0.f;
#pragma unroll 2
    for (int k0 = 0; k0 < 128; k0 += 8) {
        float4 raw = *reinterpret_cast<const float4*>(h + k0);  // 8 halves
        const __half2* hp2 = reinterpret_cast<const __half2*>(&raw);
#pragma unroll
        for (int jj = 0; jj < 4; ++jj) {
            float2 f = __half22float2(hp2[jj]);
            float a;
            a = fmaxf(f.x, 0.f);
            { float4 wv = *reinterpret_cast<const float4*>(&sW[(k0 + 2 * jj) * 16 + cg]);
              acc0 = fmaf(a, wv.x, acc0); acc1 = fmaf(a, wv.y, acc1);
              acc2 = fmaf(a, wv.z, acc2); acc3 = fmaf(a, wv.w, acc3); }
            a = fmaxf(f.y, 0.f);
            { float4 wv = *reinterpret_cast<const float4*>(&sW[(k0 + 2 * jj + 1) * 16 + cg]);
              acc0 = fmaf(a, wv.x, acc0); acc1 = fmaf(a, wv.y, acc1);
              acc2 = fmaf(a, wv.z, acc2); acc3 = fmaf(a, wv.w, acc3); }
        }
    }
    float4 o = make_float4(acc0 + sb[cg], acc1 + sb[cg + 1],
                           acc2 + sb[cg + 2], acc3 + sb[cg + 3]);
    *reinterpret_cast<float4*>(out + (size_t)node * 16 + cg) = o;
}

// ---------------------------------------------------------------------------
extern "C" void kernel_launch(void* const* d_in, const int* in_sizes, int n_in,
                              void* d_out, int out_size, void* d_ws, size_t ws_size,
                              hipStream_t stream) {
    const float* x0 = (const float*)d_in[0];
    const float* x1 = (const float*)d_in[1];
    const float* x2 = (const float*)d_in[2];
    const float* W1 = (const float*)d_in[3];
    const float* b1 = (const float*)d_in[4];
    const float* W2 = (const float*)d_in[5];
    const float* b2 = (const float*)d_in[6];
    const float* Wc = (const float*)d_in[7];
    const float* bc = (const float*)d_in[8];
    const int* edges = (const int*)d_in[9];

    // ---- workspace carve-up with overlays (~212 MB peak) ----
    char* p = (char*)d_ws;
    auto alloc = [&](size_t bytes) -> void* {
        void* r = (void*)p;
        p += (bytes + 255) & ~(size_t)255;
        return r;
    };
    __half* h2h = (__half*)alloc((size_t)3 * NN * 128 * sizeof(__half));  // 38.4 MB
    // aliases inside h2h (dead before first h2h write at layer-2 GEMM):
    unsigned* hist = (unsigned*)h2h;     // 14.4 MB, live [k_hist, k_sums)
    unsigned* bpairs = (unsigned*)h2h;   // 14.4 MB, live [k_bucket, k_scatter)
    __half* xh  = (__half*)alloc((size_t)3 * NN * 128 * sizeof(__half));  // 38.4 MB
    __half* h1h = (__half*)alloc((size_t)3 * NN * 128 * sizeof(__half));  // 38.4 MB
    __half* A6  = (__half*)alloc((size_t)6 * NN * 128 * sizeof(__half));  // 76.8 MB
    int* off = (int*)alloc((size_t)9 * (NN + 1) * sizeof(int));
    __half* nsh = (__half*)alloc((size_t)9 * NN * sizeof(__half));
    float* nd = (float*)alloc((size_t)9 * NN * sizeof(float));
    unsigned* esn = (unsigned*)alloc((size_t)9 * EE * sizeof(unsigned));  // 14.4 MB
    __half* whi = (__half*)alloc((size_t)2 * 9 * 128 * 128 * sizeof(__half));
    int* gcur = (int*)alloc((size_t)9 * NBK * sizeof(int));
    int* bcount = (int*)alloc((size_t)9 * NBK * sizeof(int));
    int* bbase = (int*)alloc((size_t)9 * (NBK + 1) * sizeof(int));
    __half* P[6];
    for (int j = 0; j < 6; ++j) P[j] = A6 + (size_t)j * NN * 128;
    const __half* xph[3] = {xh, xh + (size_t)NN * 128, xh + (size_t)2 * NN * 128};

    // ---- CSR build + input/weight prep (reused by both layers) ----
    k_hist<<<9 * NRG * HCH, 256, 0, stream>>>(edges, hist);
    k_xprep<<<(3 * NN * 32 + 255) / 256, 256, 0, stream>>>(x0, x1, x2, xh);
    k_sums<<<(9 * (NN / 2) + 255) / 256, 256, 0, stream>>>(hist, nsh);
    hipMemsetAsync(bcount, 0, (size_t)9 * NBK * sizeof(int), stream);
    k_bcount<<<9 * NCH, 256, 0, stream>>>(edges, bcount);
    k_bscan<<<1, 64, 0, stream>>>(bcount, bbase, gcur, off);
    k_bucket<<<9 * NCH, 256, 0, stream>>>(edges, gcur, bpairs);
    k_scatter<<<9 * NBK, 256, 0, stream>>>(bpairs, bbase, nsh, off, nd, esn);
    k_wprep<<<(2 * 9 * 128 * 128 + 255) / 256, 256, 0, stream>>>(W1, W2, whi);

    const int agg_grid = 3 * 12500;
    const int gemm_blocks = (NN + 63) / 64;   // 782

    auto mk = [&](int r, const __half* xin, __half* slot) -> AggT {
        return AggT{xin, off + r * (NN + 1), esn + (size_t)r * EE,
                    nd + r * NN, slot};
    };
    auto wp = [&](int layer, int r) { return (size_t)(layer * 9 + r) * 16384; };

    // src groups: S0={0,3,6} (src type0), S1={1,2,8} (type1), S2={4,5,7} (type2)
    // dst map: r0->2 r1->2 r2->0 r3->0 r4->1 r5->0 r6->0 r7->2 r8->1
    for (int L = 0; L < 2; ++L) {
        const float* b = (L == 0) ? b1 : b2;
        __half* o0 = ((L == 0) ? h1h : h2h) + (size_t)0 * NN * 128;
        __half* o1 = ((L == 0) ? h1h : h2h) + (size_t)1 * NN * 128;
        __half* o2 = ((L == 0) ? h1h : h2h) + (size_t)2 * NN * 128;
        const __half* in0 = (L == 0) ? xph[0] : h1h + (size_t)0 * NN * 128;
        const __half* in1 = (L == 0) ? xph[1] : h1h + (size_t)1 * NN * 128;
        const __half* in2 = (L == 0) ? xph[2] : h1h + (size_t)2 * NN * 128;

        // aggS0: rels {0,3,6} all read in0 -> slots P0,P1,P2
        if (L == 0)
            k_agg3<0><<<agg_grid, 256, 0, stream>>>(mk(0, in0, P[0]), mk(3, in0, P[1]),
                                                    mk(6, in0, P[2]));
        else
            k_agg3<1><<<agg_grid, 256, 0, stream>>>(mk(0, in0, P[0]), mk(3, in0, P[1]),
                                                    mk(6, in0, P[2]));
        // gemm (3,6) -> o0 STORE ; gemm (0) -> o2 STORE
        k_gemm_mfma<2, 1><<<gemm_blocks, 256, 0, stream>>>(
            P[1], P[2], whi + wp(L, 3), whi + wp(L, 6),
            b + 3 * 128, b + 6 * 128, o0);
        k_gemm_mfma<1, 1><<<gemm_blocks, 256, 0, stream>>>(
            P[0], P[0], whi + wp(L, 0), whi + wp(L, 0),
            b + 0 * 128, b + 0 * 128, o2);

        // aggS1: rels {1,2,8} all read in1 -> slots P3,P4,P5
        if (L == 0)
            k_agg3<0><<<agg_grid, 256, 0, stream>>>(mk(1, in1, P[3]), mk(2, in1, P[4]),
                                                    mk(8, in1, P[5]));
        else
            k_agg3<1><<<agg_grid, 256, 0, stream>>>(mk(1, in1, P[3]), mk(2, in1, P[4]),
                                                    mk(8, in1, P[5]));
        // aggS2: rels {4,5,7} all read in2 -> slots P0,P1,P2 (S0's, consumed)
        if (L == 0)
            k_agg3<0><<<agg_grid, 256, 0, stream>>>(mk(4, in2, P[0]), mk(5, in2, P[1]),
                                                    mk(7, in2, P[2]));
        else
            k_agg3<1><<<agg_grid, 256, 0, stream>>>(mk(4, in2, P[0]), mk(5, in2, P[1]),
                                                    mk(7, in2, P[2]));

        // gemm (8,4) -> o1 STORE ; (2,5) -> o0 ACC ; (1,7) -> o2 ACC
        k_gemm_mfma<2, 1><<<gemm_blocks, 256, 0, stream>>>(
            P[5], P[0], whi + wp(L, 8), whi + wp(L, 4),
            b + 8 * 128, b + 4 * 128, o1);
        k_gemm_mfma<2, 0><<<gemm_blocks, 256, 0, stream>>>(
            P[4], P[1], whi + wp(L, 2), whi + wp(L, 5),
            b + 2 * 128, b + 5 * 128, o0);
        k_gemm_mfma<2, 0><<<gemm_blocks, 256, 0, stream>>>(
            P[3], P[2], whi + wp(L, 1), whi + wp(L, 7),
            b + 1 * 128, b + 7 * 128, o2);
    }

    // ---- classifier: out = relu(h2h) @ Wc + bc ----
    k_classifier<<<(3 * NN + 63) / 64, 256, 0, stream>>>(h2h, Wc, bc, (float*)d_out);
}

// Round 17
// 752.772 us; speedup vs baseline: 1.9242x; 1.0010x over previous
//
#include <hip/hip_runtime.h>
#include <hip/hip_bf16.h>
#include <hip/hip_fp16.h>

// ---------------------------------------------------------------------------
// Hetero-GCN (3 node types, 9 relations), 2 GraphConv layers + classifier.
// Round 17 (agg is VALU-bound: 82% VALUBusy after esn fusion):
//  - k_agg3: batches C,D behind a WAVE-UNIFORM branch (e+8 < e1) — deg<=8
//    rows (~55%) skip half the body. e0/e1 are wave-scalars -> s_cbranch,
//    no divergence.
//  - ReLU moved from agg into the GEMM epilogue of each plane's FINAL writer
//    (fp32 max before fp16 store; bit-identical). Kills all pk_max in the
//    layer-2 gathers; agg is now a single kernel for both layers.
//  - everything else frozen.
// ---------------------------------------------------------------------------

#define NN 50000
#define EE 400000
#define NRG 4            // node ranges for src histogram
#define RGN (NN / NRG)   // 12500 nodes per range
#define HCH 16           // edge chunks
#define HEG (EE / HCH)   // 25000 edges per chunk
#define NBK 98           // dst buckets (dst>>9)
#define BKW 512          // dsts per bucket
#define CH1 8192         // bucket pass-1 edges per chunk
#define NCH ((EE + CH1 - 1) / CH1)   // 49
#define SCAP 6656        // bucket pass-2 LDS segment capacity

typedef __attribute__((ext_vector_type(8))) _Float16 f16x8;
typedef __attribute__((ext_vector_type(2))) _Float16 h2f;
typedef __attribute__((ext_vector_type(4))) float f32x4;
#define MFMAH(a, b, c) __builtin_amdgcn_mfma_f32_16x16x32_f16(a, b, c, 0, 0, 0)

// ---------------- src-degree histogram (chunked, LDS) -----------------------
__global__ __launch_bounds__(256) void k_hist(const int* __restrict__ edges,
                                              unsigned* __restrict__ hist) {
    __shared__ unsigned bins[RGN / 2];  // 6250 u32 = 25 KB
    int bid = blockIdx.x;
    int r = bid >> 6;              // NRG*HCH = 64 blocks per relation
    int rem = bid & 63;
    int rg = rem >> 4;
    int c = rem & 15;
    int tid = threadIdx.x;
    for (int i = tid; i < RGN / 2; i += 256) bins[i] = 0;
    __syncthreads();
    const int* ea = edges + (size_t)r * 2 * EE + (size_t)c * HEG;  // src side
    int base = rg * RGN;
    for (int e = tid; e < HEG; e += 256) {
        int idx = __builtin_nontemporal_load(&ea[e]) - base;
        if ((unsigned)idx < (unsigned)RGN)
            atomicAdd(&bins[idx >> 1], (idx & 1) ? 65536u : 1u);
    }
    __syncthreads();
    unsigned* ho = hist + ((size_t)(r * NRG + rg) * HCH + c) * (RGN / 2);
    for (int i = tid; i < RGN / 2; i += 256) ho[i] = bins[i];
}

// ---------------- reduce histograms -> ns (fp16) ----------------------------
__global__ void k_sums(const unsigned* __restrict__ hist, __half* __restrict__ nsh) {
    int i = blockIdx.x * blockDim.x + threadIdx.x;
    if (i >= 9 * (NN / 2)) return;
    int r = i / (NN / 2);
    int ps = i - r * (NN / 2);
    int rg = ps / (RGN / 2);
    int slot = ps - rg * (RGN / 2);
    const unsigned* hs = hist + ((size_t)(r * NRG + rg) * HCH) * (RGN / 2) + slot;
    unsigned slo = 0, shi = 0;
#pragma unroll
    for (int c = 0; c < HCH; ++c) {
        unsigned a = hs[(size_t)c * (RGN / 2)];
        slo += a & 0xffffu; shi += a >> 16;
    }
    int n0 = 2 * ps;
    nsh[r * NN + n0]     = slo ? __float2half_rn(rsqrtf((float)slo)) : __half(0.f);
    nsh[r * NN + n0 + 1] = shi ? __float2half_rn(rsqrtf((float)shi)) : __half(0.f);
}

// ---------------- per-bucket edge counts ------------------------------------
__global__ __launch_bounds__(256) void k_bcount(const int* __restrict__ edges,
                                                int* __restrict__ bcount) {
    __shared__ int bins[NBK];
    int bid = blockIdx.x;
    int r = bid / NCH, c = bid - r * NCH;
    int tid = threadIdx.x;
    for (int i = tid; i < NBK; i += 256) bins[i] = 0;
    __syncthreads();
    int e0 = c * CH1, e1 = min(EE, e0 + CH1);
    const int* ed = edges + (size_t)r * 2 * EE + EE;
    for (int e = e0 + tid; e < e1; e += 256)
        atomicAdd(&bins[__builtin_nontemporal_load(&ed[e]) >> 9], 1);
    __syncthreads();
    for (int i = tid; i < NBK; i += 256)
        if (bins[i]) atomicAdd(&bcount[r * NBK + i], bins[i]);
}

// ---------------- scan bucket counts -> bases, gcur seeds, off[NN] ----------
__global__ void k_bscan(const int* __restrict__ bcount, int* __restrict__ bbase,
                        int* __restrict__ gcur, int* __restrict__ off) {
    int r = threadIdx.x;
    if (r >= 9) return;
    int acc = 0;
    for (int b = 0; b < NBK; ++b) {
        bbase[r * (NBK + 1) + b] = acc;
        gcur[r * NBK + b] = acc;
        acc += bcount[r * NBK + b];
    }
    bbase[r * (NBK + 1) + NBK] = acc;
    off[r * (NN + 1) + NN] = acc;   // == EE
}

// ---------------- pass 1: bucket edges by dst>>9, packed u32 ----------------
__global__ __launch_bounds__(256) void k_bucket(const int* __restrict__ edges,
                                                int* __restrict__ gcur,
                                                unsigned* __restrict__ bpairs) {
    __shared__ int hist[NBK];
    __shared__ int sc[128];
    __shared__ int lofs[NBK + 1];
    __shared__ int lcur[NBK];
    __shared__ int gbase[NBK];
    __shared__ unsigned stage[CH1];
    int bid = blockIdx.x;
    int r = bid / NCH, c = bid - r * NCH;
    int tid = threadIdx.x;
    int e0 = c * CH1;
    int e1 = min(EE, e0 + CH1);
    int n = e1 - e0;
    const int* es = edges + (size_t)r * 2 * EE;
    const int* ed = es + EE;

    for (int i = tid; i < NBK; i += 256) hist[i] = 0;
    __syncthreads();
    for (int e = e0 + tid; e < e1; e += 256)
        atomicAdd(&hist[ed[e] >> 9], 1);
    __syncthreads();
    if (tid < 128) sc[tid] = (tid < NBK) ? hist[tid] : 0;
    __syncthreads();
#pragma unroll
    for (int s = 1; s < 128; s <<= 1) {
        int t = 0;
        if (tid < 128 && tid >= s) t = sc[tid - s];
        __syncthreads();
        if (tid < 128 && tid >= s) sc[tid] += t;
        __syncthreads();
    }
    if (tid < NBK) {
        int ex = sc[tid] - hist[tid];
        lofs[tid] = ex;
        lcur[tid] = ex;
        gbase[tid] = atomicAdd(&gcur[r * NBK + tid], hist[tid]);
    }
    if (tid == 0) lofs[NBK] = n;
    __syncthreads();
    for (int e = e0 + tid; e < e1; e += 256) {
        int dst = ed[e];
        int src = es[e];
        int p = atomicAdd(&lcur[dst >> 9], 1);
        stage[p] = ((unsigned)dst << 16) | (unsigned)src;
    }
    __syncthreads();
    unsigned* bp = bpairs + (size_t)r * EE;
    for (int i = tid; i < n; i += 256) {
        int lo = 0, hi = NBK;
        while (hi - lo > 1) {
            int m = (lo + hi) >> 1;
            if (lofs[m] <= i) lo = m; else hi = m;
        }
        bp[gbase[lo] + (i - lofs[lo])] = stage[i];
    }
}

// ---------------- pass 2: per-bucket degrees + offsets + LDS scatter --------
// Writes esn packed {ns_fp16<<16 | src}.
__global__ __launch_bounds__(256) void k_scatter(const unsigned* __restrict__ bpairs,
                                                 const int* __restrict__ bbase,
                                                 const __half* __restrict__ nsh,
                                                 int* __restrict__ off,
                                                 float* __restrict__ nd,
                                                 unsigned* __restrict__ esn) {
    __shared__ int bins[BKW];
    __shared__ int lcur[BKW];
    __shared__ int wsum[4];
    __shared__ unsigned lout[SCAP];
    int bid = blockIdx.x;
    int r = bid / NBK, b = bid - r * NBK;
    int tid = threadIdx.x;
    int d0 = b * BKW;
    int d1 = min(NN, d0 + BKW);
    int nb = d1 - d0;
    int s0 = bbase[r * (NBK + 1) + b];
    int s1 = bbase[r * (NBK + 1) + b + 1];
    int n = s1 - s0;
    for (int i = tid; i < BKW; i += 256) bins[i] = 0;
    __syncthreads();
    const unsigned* bp = bpairs + (size_t)r * EE + s0;
    for (int i = tid; i < n; i += 256)
        atomicAdd(&bins[(int)(bp[i] >> 16) - d0], 1);
    __syncthreads();
    int v0 = bins[2 * tid], v1 = bins[2 * tid + 1];
    int s = v0 + v1;
    int lane = tid & 63, w = tid >> 6;
    int x = s;
#pragma unroll
    for (int sh = 1; sh < 64; sh <<= 1) {
        int y = __shfl_up(x, (unsigned)sh);
        if (lane >= sh) x += y;
    }
    if (lane == 63) wsum[w] = x;
    __syncthreads();
    int wb = 0;
#pragma unroll
    for (int j = 0; j < 3; ++j) wb += (j < w) ? wsum[j] : 0;
    int ex = wb + x - s;      // exclusive prefix for bin 2t
    int* o = off + r * (NN + 1);
    if (2 * tid < nb) {
        o[d0 + 2 * tid] = s0 + ex;
        nd[r * NN + d0 + 2 * tid] = v0 ? rsqrtf((float)v0) : 0.f;
    }
    if (2 * tid + 1 < nb) {
        o[d0 + 2 * tid + 1] = s0 + ex + v0;
        nd[r * NN + d0 + 2 * tid + 1] = v1 ? rsqrtf((float)v1) : 0.f;
    }
    lcur[2 * tid] = ex;
    lcur[2 * tid + 1] = ex + v0;
    __syncthreads();
    const __half* nsr = nsh + (size_t)r * NN;
    unsigned* out = esn + (size_t)r * EE + s0;
    if (n <= SCAP) {
        for (int i = tid; i < n; i += 256) {
            unsigned pr = bp[i];
            int src = (int)(pr & 0xffffu);
            unsigned wbits = (unsigned)__half_as_ushort(nsr[src]);
            int p = atomicAdd(&lcur[(int)(pr >> 16) - d0], 1);
            lout[p] = (wbits << 16) | (unsigned)src;
        }
        __syncthreads();
        for (int i = tid; i < n; i += 256) out[i] = lout[i];
    } else {  // statistically unreachable safety path
        for (int i = tid; i < n; i += 256) {
            unsigned pr = bp[i];
            int src = (int)(pr & 0xffffu);
            unsigned wbits = (unsigned)__half_as_ushort(nsr[src]);
            int p = atomicAdd(&lcur[(int)(pr >> 16) - d0], 1);
            out[p] = (wbits << 16) | (unsigned)src;
        }
    }
}

// ---------------- x -> fp16 conversion ---------------------------------------
__global__ void k_xprep(const float* __restrict__ x0, const float* __restrict__ x1,
                        const float* __restrict__ x2, __half* __restrict__ xh) {
    int i = blockIdx.x * blockDim.x + threadIdx.x;  // float4 index over 3*NN*32
    const int per = NN * 32;
    if (i >= 3 * per) return;
    int tsel = i / per;
    int o = i - tsel * per;
    const float* xp = (tsel == 0) ? x0 : ((tsel == 1) ? x1 : x2);
    float4 v = *reinterpret_cast<const float4*>(xp + (size_t)o * 4);
    __half* dst = xh + (size_t)tsel * NN * 128 + (size_t)o * 4;
    *reinterpret_cast<__half2*>(dst) = __floats2half2_rn(v.x, v.y);
    *reinterpret_cast<__half2*>(dst + 2) = __floats2half2_rn(v.z, v.w);
}

// ---------------- W prep: fp32 [K][N] -> chunk-major fp16 plane -------------
__global__ void k_wprep(const float* __restrict__ W1, const float* __restrict__ W2,
                        __half* __restrict__ whi) {
    int id = blockIdx.x * blockDim.x + threadIdx.x;
    const int total = 2 * 9 * 128 * 128;
    if (id >= total) return;
    int n = id & 127;
    int k = (id >> 7) & 127;
    int rl = id >> 14;  // layer*9 + r
    const float* W = (rl < 9) ? W1 : W2;
    int r = (rl < 9) ? rl : rl - 9;
    float f = W[((size_t)r * 128 + k) * 128 + n];
    size_t oidx = (((size_t)rl * 4 + (k >> 5)) * 128 + n) * 32 + (k & 31);
    whi[oidx] = __float2half_rn(f);
}

// ---------------- aggregation (packed-fp16 CSR gather, 3 src-sharing tasks) -
// One wave per dst row: 4 edge-slots x 16 col-lanes. Batches A,B cover 8
// edges; batches C,D (next 8) sit behind a wave-uniform branch so deg<=8 rows
// (~55%) skip half the body. No ReLU here (moved to GEMM epilogue).
struct AggT {
    const __half* xin;
    const int* off;
    const unsigned* esn;
    const float* nd;
    __half* A;
};

__global__ __launch_bounds__(256) void k_agg3(AggT t0, AggT t1, AggT t2) {
    int bid = blockIdx.x;
    int task = bid % 3;
    AggT t = (task == 0) ? t0 : ((task == 1) ? t1 : t2);
    int wave = (bid / 3) * 4 + (threadIdx.x >> 6);
    int lane = threadIdx.x & 63;
    if (wave >= NN) return;
    int g = lane >> 4;       // edge slot 0..3
    int c = lane & 15;       // column group: cols c*8 .. c*8+7
    int e0 = t.off[wave], e1 = t.off[wave + 1];
    const __half* xin = t.xin;
    const unsigned* esn = t.esn;
    const h2f zz = {(_Float16)0.f, (_Float16)0.f};
    h2f accA[4] = {zz, zz, zz, zz};
    h2f accB[4] = {zz, zz, zz, zz};
    h2f accC[4] = {zz, zz, zz, zz};
    h2f accD[4] = {zz, zz, zz, zz};
    for (int e = e0; e < e1; e += 16) {
        // ---- batches A,B: edges e .. e+7 ----
        {
            int ea = e + g, eb = e + 4 + g;
            bool va = ea < e1, vb = eb < e1;
            unsigned ua = esn[va ? ea : e];
            unsigned ub = esn[vb ? eb : e];
            int sa = ua & 0xffffu, sb = ub & 0xffffu;
            _Float16 wa = va ? __builtin_bit_cast(_Float16, (unsigned short)(ua >> 16)) : (_Float16)0.f;
            _Float16 wb = vb ? __builtin_bit_cast(_Float16, (unsigned short)(ub >> 16)) : (_Float16)0.f;
            h2f wav = {wa, wa}, wbv = {wb, wb};
            float4 ra = *reinterpret_cast<const float4*>(xin + (size_t)sa * 128 + c * 8);
            float4 rb = *reinterpret_cast<const float4*>(xin + (size_t)sb * 128 + c * 8);
            const h2f* pa = reinterpret_cast<const h2f*>(&ra);
            const h2f* pb = reinterpret_cast<const h2f*>(&rb);
#pragma unroll
            for (int j = 0; j < 4; ++j) {
                accA[j] = wav * pa[j] + accA[j];   // v_pk_fma_f16
                accB[j] = wbv * pb[j] + accB[j];
            }
        }
        // ---- batches C,D: edges e+8 .. e+15 (wave-uniform skip) ----
        if (e + 8 < e1) {
            int ec = e + 8 + g, ed = e + 12 + g;
            bool vc = ec < e1, vd = ed < e1;
            unsigned uc = esn[vc ? ec : e];
            unsigned ud = esn[vd ? ed : e];
            int sc_ = uc & 0xffffu, sd = ud & 0xffffu;
            _Float16 wc = vc ? __builtin_bit_cast(_Float16, (unsigned short)(uc >> 16)) : (_Float16)0.f;
            _Float16 wd = vd ? __builtin_bit_cast(_Float16, (unsigned short)(ud >> 16)) : (_Float16)0.f;
            h2f wcv = {wc, wc}, wdv = {wd, wd};
            float4 rc = *reinterpret_cast<const float4*>(xin + (size_t)sc_ * 128 + c * 8);
            float4 rd = *reinterpret_cast<const float4*>(xin + (size_t)sd * 128 + c * 8);
            const h2f* pc = reinterpret_cast<const h2f*>(&rc);
            const h2f* pd = reinterpret_cast<const h2f*>(&rd);
#pragma unroll
            for (int j = 0; j < 4; ++j) {
                accC[j] = wcv * pc[j] + accC[j];
                accD[j] = wdv * pd[j] + accD[j];
            }
        }
    }
    float acc[8];
#pragma unroll
    for (int j = 0; j < 4; ++j) {
        acc[2 * j]     = ((float)accA[j][0] + (float)accB[j][0]) +
                         ((float)accC[j][0] + (float)accD[j][0]);
        acc[2 * j + 1] = ((float)accA[j][1] + (float)accB[j][1]) +
                         ((float)accC[j][1] + (float)accD[j][1]);
    }
#pragma unroll
    for (int j = 0; j < 8; ++j) {
        acc[j] += __shfl_xor(acc[j], 16);
        acc[j] += __shfl_xor(acc[j], 32);
    }
    if (g == 0) {
        float nr = t.nd[wave];
        f16x8 hv;
#pragma unroll
        for (int j = 0; j < 8; ++j) hv[j] = (_Float16)(acc[j] * nr);
        *reinterpret_cast<f16x8*>(t.A + (size_t)wave * 128 + c * 8) = hv;
    }
}

// ---------------- f16 MFMA GEMM: H (=|+=) sum_s A_s @ W_s + bias ------------
// RELU=1 on each plane's FINAL writer (relu folded out of the next gather).
template <int NS, int STORE, int RELU>
__global__ __launch_bounds__(256) void k_gemm_mfma(
    const __half* __restrict__ Aa, const __half* __restrict__ Ab,
    const __half* __restrict__ wha, const __half* __restrict__ whb,
    const float* __restrict__ ba, const float* __restrict__ bb,
    __half* __restrict__ H) {
    int tid = threadIdx.x;
    int w = tid >> 6, lane = tid & 63;
    int row0 = blockIdx.x * 64;
    int colbase = w * 32;
    int r16 = lane & 15;
    int koff = (lane >> 4) * 8;

    f32x4 acc[4][2];
#pragma unroll
    for (int rt = 0; rt < 4; ++rt)
#pragma unroll
        for (int nt = 0; nt < 2; ++nt)
            acc[rt][nt] = f32x4{0.f, 0.f, 0.f, 0.f};

#pragma unroll
    for (int s = 0; s < NS; ++s) {
        const __half* A = (s == 0) ? Aa : Ab;
        const __half* w_h = (s == 0) ? wha : whb;
#pragma unroll
        for (int c = 0; c < 4; ++c) {
            int kbase = c * 32 + koff;
            f16x8 av[4], bh[2];
#pragma unroll
            for (int rt = 0; rt < 4; ++rt) {
                int rr = rt * 16 + r16;
                int rc = (row0 + rr < NN) ? rr : 0;
                av[rt] = *reinterpret_cast<const f16x8*>(
                    A + ((size_t)(row0 + rc)) * 128 + kbase);
            }
#pragma unroll
            for (int nt = 0; nt < 2; ++nt) {
                int col = colbase + nt * 16 + r16;
                size_t widx = ((size_t)c * 128 + col) * 32 + koff;
                bh[nt] = *reinterpret_cast<const f16x8*>(w_h + widx);
            }
#pragma unroll
            for (int rt = 0; rt < 4; ++rt)
#pragma unroll
                for (int nt = 0; nt < 2; ++nt)
                    acc[rt][nt] = MFMAH(av[rt], bh[nt], acc[rt][nt]);
        }
    }

    int orow = (lane >> 4) * 4;
#pragma unroll
    for (int nt = 0; nt < 2; ++nt) {
        int col = colbase + nt * 16 + r16;
        float bias = ba[col];
        if (NS == 2) bias += bb[col];
#pragma unroll
        for (int rt = 0; rt < 4; ++rt) {
#pragma unroll
            for (int j = 0; j < 4; ++j) {
                int grow = row0 + rt * 16 + orow + j;
                if (grow < NN) {
                    __half* hp = H + (size_t)grow * 128 + col;
                    float v = acc[rt][nt][j] + bias;
                    if (!STORE) v += __half2float(*hp);
                    if (RELU) v = fmaxf(v, 0.f);
                    *hp = __float2half_rn(v);
                }
            }
        }
    }
}

// ---------------- classifier: out = relu(H_fp16) @ Wc + bc ------------------
// (H already relu'd by GEMM epilogue; fmaxf kept — idempotent, safe.)
__global__ __launch_bounds__(256) void k_classifier(const __half* __restrict__ H,
                                                    const float* __restrict__ Wc,
                                                    const float* __restrict__ bc,
                                                    float* __restrict__ out) {
    __shared__ float sW[128 * 16];
    __shared__ float sb[16];
    int tid = threadIdx.x;
#pragma unroll
    for (int i = tid; i < 2048; i += 256) sW[i] = Wc[i];
    if (tid < 16) sb[tid] = bc[tid];
    __syncthreads();
    int node = blockIdx.x * 64 + (tid >> 2);
    if (node >= 3 * NN) return;
    int cg = (tid & 3) << 2;
    const __half* h = H + (size_t)node * 128;
    float acc0 = 0.f, acc1 = 0.f, acc2 = 0.f, acc3 = 0.f;
#pragma unroll 2
    for (int k0 = 0; k0 < 128; k0 += 8) {
        float4 raw = *reinterpret_cast<const float4*>(h + k0);  // 8 halves
        const __half2* hp2 = reinterpret_cast<const __half2*>(&raw);
#pragma unroll
        for (int jj = 0; jj < 4; ++jj) {
            float2 f = __half22float2(hp2[jj]);
            float a;
            a = fmaxf(f.x, 0.f);
            { float4 wv = *reinterpret_cast<const float4*>(&sW[(k0 + 2 * jj) * 16 + cg]);
              acc0 = fmaf(a, wv.x, acc0); acc1 = fmaf(a, wv.y, acc1);
              acc2 = fmaf(a, wv.z, acc2); acc3 = fmaf(a, wv.w, acc3); }
            a = fmaxf(f.y, 0.f);
            { float4 wv = *reinterpret_cast<const float4*>(&sW[(k0 + 2 * jj + 1) * 16 + cg]);
              acc0 = fmaf(a, wv.x, acc0); acc1 = fmaf(a, wv.y, acc1);
              acc2 = fmaf(a, wv.z, acc2); acc3 = fmaf(a, wv.w, acc3); }
        }
    }
    float4 o = make_float4(acc0 + sb[cg], acc1 + sb[cg + 1],
                           acc2 + sb[cg + 2], acc3 + sb[cg + 3]);
    *reinterpret_cast<float4*>(out + (size_t)node * 16 + cg) = o;
}

// ---------------------------------------------------------------------------
extern "C" void kernel_launch(void* const* d_in, const int* in_sizes, int n_in,
                              void* d_out, int out_size, void* d_ws, size_t ws_size,
                              hipStream_t stream) {
    const float* x0 = (const float*)d_in[0];
    const float* x1 = (const float*)d_in[1];
    const float* x2 = (const float*)d_in[2];
    const float* W1 = (const float*)d_in[3];
    const float* b1 = (const float*)d_in[4];
    const float* W2 = (const float*)d_in[5];
    const float* b2 = (const float*)d_in[6];
    const float* Wc = (const float*)d_in[7];
    const float* bc = (const float*)d_in[8];
    const int* edges = (const int*)d_in[9];

    // ---- workspace carve-up with overlays (~212 MB peak) ----
    char* p = (char*)d_ws;
    auto alloc = [&](size_t bytes) -> void* {
        void* r = (void*)p;
        p += (bytes + 255) & ~(size_t)255;
        return r;
    };
    __half* h2h = (__half*)alloc((size_t)3 * NN * 128 * sizeof(__half));  // 38.4 MB
    // aliases inside h2h (dead before first h2h write at layer-2 GEMM):
    unsigned* hist = (unsigned*)h2h;     // 14.4 MB, live [k_hist, k_sums)
    unsigned* bpairs = (unsigned*)h2h;   // 14.4 MB, live [k_bucket, k_scatter)
    __half* xh  = (__half*)alloc((size_t)3 * NN * 128 * sizeof(__half));  // 38.4 MB
    __half* h1h = (__half*)alloc((size_t)3 * NN * 128 * sizeof(__half));  // 38.4 MB
    __half* A6  = (__half*)alloc((size_t)6 * NN * 128 * sizeof(__half));  // 76.8 MB
    int* off = (int*)alloc((size_t)9 * (NN + 1) * sizeof(int));
    __half* nsh = (__half*)alloc((size_t)9 * NN * sizeof(__half));
    float* nd = (float*)alloc((size_t)9 * NN * sizeof(float));
    unsigned* esn = (unsigned*)alloc((size_t)9 * EE * sizeof(unsigned));  // 14.4 MB
    __half* whi = (__half*)alloc((size_t)2 * 9 * 128 * 128 * sizeof(__half));
    int* gcur = (int*)alloc((size_t)9 * NBK * sizeof(int));
    int* bcount = (int*)alloc((size_t)9 * NBK * sizeof(int));
    int* bbase = (int*)alloc((size_t)9 * (NBK + 1) * sizeof(int));
    __half* P[6];
    for (int j = 0; j < 6; ++j) P[j] = A6 + (size_t)j * NN * 128;
    const __half* xph[3] = {xh, xh + (size_t)NN * 128, xh + (size_t)2 * NN * 128};

    // ---- CSR build + input/weight prep (reused by both layers) ----
    k_hist<<<9 * NRG * HCH, 256, 0, stream>>>(edges, hist);
    k_xprep<<<(3 * NN * 32 + 255) / 256, 256, 0, stream>>>(x0, x1, x2, xh);
    k_sums<<<(9 * (NN / 2) + 255) / 256, 256, 0, stream>>>(hist, nsh);
    hipMemsetAsync(bcount, 0, (size_t)9 * NBK * sizeof(int), stream);
    k_bcount<<<9 * NCH, 256, 0, stream>>>(edges, bcount);
    k_bscan<<<1, 64, 0, stream>>>(bcount, bbase, gcur, off);
    k_bucket<<<9 * NCH, 256, 0, stream>>>(edges, gcur, bpairs);
    k_scatter<<<9 * NBK, 256, 0, stream>>>(bpairs, bbase, nsh, off, nd, esn);
    k_wprep<<<(2 * 9 * 128 * 128 + 255) / 256, 256, 0, stream>>>(W1, W2, whi);

    const int agg_grid = 3 * 12500;
    const int gemm_blocks = (NN + 63) / 64;   // 782

    auto mk = [&](int r, const __half* xin, __half* slot) -> AggT {
        return AggT{xin, off + r * (NN + 1), esn + (size_t)r * EE,
                    nd + r * NN, slot};
    };
    auto wp = [&](int layer, int r) { return (size_t)(layer * 9 + r) * 16384; };

    // src groups: S0={0,3,6} (src type0), S1={1,2,8} (type1), S2={4,5,7} (type2)
    // dst map: r0->2 r1->2 r2->0 r3->0 r4->1 r5->0 r6->0 r7->2 r8->1
    for (int L = 0; L < 2; ++L) {
        const float* b = (L == 0) ? b1 : b2;
        __half* o0 = ((L == 0) ? h1h : h2h) + (size_t)0 * NN * 128;
        __half* o1 = ((L == 0) ? h1h : h2h) + (size_t)1 * NN * 128;
        __half* o2 = ((L == 0) ? h1h : h2h) + (size_t)2 * NN * 128;
        const __half* in0 = (L == 0) ? xph[0] : h1h + (size_t)0 * NN * 128;
        const __half* in1 = (L == 0) ? xph[1] : h1h + (size_t)1 * NN * 128;
        const __half* in2 = (L == 0) ? xph[2] : h1h + (size_t)2 * NN * 128;

        // aggS0: rels {0,3,6} all read in0 -> slots P0,P1,P2
        k_agg3<<<agg_grid, 256, 0, stream>>>(mk(0, in0, P[0]), mk(3, in0, P[1]),
                                             mk(6, in0, P[2]));
        // gemm (3,6) -> o0 STORE (not final) ; gemm (0) -> o2 STORE (not final)
        k_gemm_mfma<2, 1, 0><<<gemm_blocks, 256, 0, stream>>>(
            P[1], P[2], whi + wp(L, 3), whi + wp(L, 6),
            b + 3 * 128, b + 6 * 128, o0);
        k_gemm_mfma<1, 1, 0><<<gemm_blocks, 256, 0, stream>>>(
            P[0], P[0], whi + wp(L, 0), whi + wp(L, 0),
            b + 0 * 128, b + 0 * 128, o2);

        // aggS1: rels {1,2,8} all read in1 -> slots P3,P4,P5
        k_agg3<<<agg_grid, 256, 0, stream>>>(mk(1, in1, P[3]), mk(2, in1, P[4]),
                                             mk(8, in1, P[5]));
        // aggS2: rels {4,5,7} all read in2 -> slots P0,P1,P2 (S0's, consumed)
        k_agg3<<<agg_grid, 256, 0, stream>>>(mk(4, in2, P[0]), mk(5, in2, P[1]),
                                             mk(7, in2, P[2]));

        // FINAL writers (RELU=1): (8,4) -> o1 STORE ; (2,5) -> o0 ACC ;
        // (1,7) -> o2 ACC
        k_gemm_mfma<2, 1, 1><<<gemm_blocks, 256, 0, stream>>>(
            P[5], P[0], whi + wp(L, 8), whi + wp(L, 4),
            b + 8 * 128, b + 4 * 128, o1);
        k_gemm_mfma<2, 0, 1><<<gemm_blocks, 256, 0, stream>>>(
            P[4], P[1], whi + wp(L, 2), whi + wp(L, 5),
            b + 2 * 128, b + 5 * 128, o0);
        k_gemm_mfma<2, 0, 1><<<gemm_blocks, 256, 0, stream>>>(
            P[3], P[2], whi + wp(L, 1), whi + wp(L, 7),
            b + 1 * 128, b + 7 * 128, o2);
    }

    // ---- classifier: out = relu(h2h) @ Wc + bc ----
    k_classifier<<<(3 * NN + 63) / 64, 256, 0, stream>>>(h2h, Wc, bc, (float*)d_out);
}

// Round 18
// 688.876 us; speedup vs baseline: 2.1027x; 1.0928x over previous
//
#include <hip/hip_runtime.h>
#include <hip/hip_bf16.h>
#include <hip/hip_fp16.h>

// ---------------------------------------------------------------------------
// Hetero-GCN (3 node types, 9 relations), 2 GraphConv layers + classifier.
// Round 18 (agg confirmed L2-miss-service bound; attack the ~110us of launch
// boundaries + redundant H traffic):
//  - ONE agg launch per layer (9 independent tasks, grid 112500; blocks in 3
//    contiguous src-group ranges to keep XCD-L2 plane sharing).
//  - ONE GEMM per dst plane (K=512/256/384, template<NS> pointer arrays):
//    single writer per plane -> all STORE, no ACC read-modify, biases summed
//    in-kernel. 22 compute launches -> 12.
//  - 9 A-slots, zero new workspace: P[6..8] overlay h2h (layer 1) / xh
//    (layer 2) regions, both dead in those phases.
// ---------------------------------------------------------------------------

#define NN 50000
#define EE 400000
#define NRG 4            // node ranges for src histogram
#define RGN (NN / NRG)   // 12500 nodes per range
#define HCH 16           // edge chunks
#define HEG (EE / HCH)   // 25000 edges per chunk
#define NBK 98           // dst buckets (dst>>9)
#define BKW 512          // dsts per bucket
#define CH1 8192         // bucket pass-1 edges per chunk
#define NCH ((EE + CH1 - 1) / CH1)   // 49
#define SCAP 6656        // bucket pass-2 LDS segment capacity

typedef __attribute__((ext_vector_type(8))) _Float16 f16x8;
typedef __attribute__((ext_vector_type(2))) _Float16 h2f;
typedef __attribute__((ext_vector_type(4))) float f32x4;
#define MFMAH(a, b, c) __builtin_amdgcn_mfma_f32_16x16x32_f16(a, b, c, 0, 0, 0)

// ---------------- src-degree histogram (chunked, LDS) -----------------------
__global__ __launch_bounds__(256) void k_hist(const int* __restrict__ edges,
                                              unsigned* __restrict__ hist) {
    __shared__ unsigned bins[RGN / 2];  // 6250 u32 = 25 KB
    int bid = blockIdx.x;
    int r = bid >> 6;              // NRG*HCH = 64 blocks per relation
    int rem = bid & 63;
    int rg = rem >> 4;
    int c = rem & 15;
    int tid = threadIdx.x;
    for (int i = tid; i < RGN / 2; i += 256) bins[i] = 0;
    __syncthreads();
    const int* ea = edges + (size_t)r * 2 * EE + (size_t)c * HEG;  // src side
    int base = rg * RGN;
    for (int e = tid; e < HEG; e += 256) {
        int idx = __builtin_nontemporal_load(&ea[e]) - base;
        if ((unsigned)idx < (unsigned)RGN)
            atomicAdd(&bins[idx >> 1], (idx & 1) ? 65536u : 1u);
    }
    __syncthreads();
    unsigned* ho = hist + ((size_t)(r * NRG + rg) * HCH + c) * (RGN / 2);
    for (int i = tid; i < RGN / 2; i += 256) ho[i] = bins[i];
}

// ---------------- reduce histograms -> ns (fp16) ----------------------------
__global__ void k_sums(const unsigned* __restrict__ hist, __half* __restrict__ nsh) {
    int i = blockIdx.x * blockDim.x + threadIdx.x;
    if (i >= 9 * (NN / 2)) return;
    int r = i / (NN / 2);
    int ps = i - r * (NN / 2);
    int rg = ps / (RGN / 2);
    int slot = ps - rg * (RGN / 2);
    const unsigned* hs = hist + ((size_t)(r * NRG + rg) * HCH) * (RGN / 2) + slot;
    unsigned slo = 0, shi = 0;
#pragma unroll
    for (int c = 0; c < HCH; ++c) {
        unsigned a = hs[(size_t)c * (RGN / 2)];
        slo += a & 0xffffu; shi += a >> 16;
    }
    int n0 = 2 * ps;
    nsh[r * NN + n0]     = slo ? __float2half_rn(rsqrtf((float)slo)) : __half(0.f);
    nsh[r * NN + n0 + 1] = shi ? __float2half_rn(rsqrtf((float)shi)) : __half(0.f);
}

// ---------------- per-bucket edge counts ------------------------------------
__global__ __launch_bounds__(256) void k_bcount(const int* __restrict__ edges,
                                                int* __restrict__ bcount) {
    __shared__ int bins[NBK];
    int bid = blockIdx.x;
    int r = bid / NCH, c = bid - r * NCH;
    int tid = threadIdx.x;
    for (int i = tid; i < NBK; i += 256) bins[i] = 0;
    __syncthreads();
    int e0 = c * CH1, e1 = min(EE, e0 + CH1);
    const int* ed = edges + (size_t)r * 2 * EE + EE;
    for (int e = e0 + tid; e < e1; e += 256)
        atomicAdd(&bins[__builtin_nontemporal_load(&ed[e]) >> 9], 1);
    __syncthreads();
    for (int i = tid; i < NBK; i += 256)
        if (bins[i]) atomicAdd(&bcount[r * NBK + i], bins[i]);
}

// ---------------- scan bucket counts -> bases, gcur seeds, off[NN] ----------
__global__ void k_bscan(const int* __restrict__ bcount, int* __restrict__ bbase,
                        int* __restrict__ gcur, int* __restrict__ off) {
    int r = threadIdx.x;
    if (r >= 9) return;
    int acc = 0;
    for (int b = 0; b < NBK; ++b) {
        bbase[r * (NBK + 1) + b] = acc;
        gcur[r * NBK + b] = acc;
        acc += bcount[r * NBK + b];
    }
    bbase[r * (NBK + 1) + NBK] = acc;
    off[r * (NN + 1) + NN] = acc;   // == EE
}

// ---------------- pass 1: bucket edges by dst>>9, packed u32 ----------------
__global__ __launch_bounds__(256) void k_bucket(const int* __restrict__ edges,
                                                int* __restrict__ gcur,
                                                unsigned* __restrict__ bpairs) {
    __shared__ int hist[NBK];
    __shared__ int sc[128];
    __shared__ int lofs[NBK + 1];
    __shared__ int lcur[NBK];
    __shared__ int gbase[NBK];
    __shared__ unsigned stage[CH1];
    int bid = blockIdx.x;
    int r = bid / NCH, c = bid - r * NCH;
    int tid = threadIdx.x;
    int e0 = c * CH1;
    int e1 = min(EE, e0 + CH1);
    int n = e1 - e0;
    const int* es = edges + (size_t)r * 2 * EE;
    const int* ed = es + EE;

    for (int i = tid; i < NBK; i += 256) hist[i] = 0;
    __syncthreads();
    for (int e = e0 + tid; e < e1; e += 256)
        atomicAdd(&hist[ed[e] >> 9], 1);
    __syncthreads();
    if (tid < 128) sc[tid] = (tid < NBK) ? hist[tid] : 0;
    __syncthreads();
#pragma unroll
    for (int s = 1; s < 128; s <<= 1) {
        int t = 0;
        if (tid < 128 && tid >= s) t = sc[tid - s];
        __syncthreads();
        if (tid < 128 && tid >= s) sc[tid] += t;
        __syncthreads();
    }
    if (tid < NBK) {
        int ex = sc[tid] - hist[tid];
        lofs[tid] = ex;
        lcur[tid] = ex;
        gbase[tid] = atomicAdd(&gcur[r * NBK + tid], hist[tid]);
    }
    if (tid == 0) lofs[NBK] = n;
    __syncthreads();
    for (int e = e0 + tid; e < e1; e += 256) {
        int dst = ed[e];
        int src = es[e];
        int p = atomicAdd(&lcur[dst >> 9], 1);
        stage[p] = ((unsigned)dst << 16) | (unsigned)src;
    }
    __syncthreads();
    unsigned* bp = bpairs + (size_t)r * EE;
    for (int i = tid; i < n; i += 256) {
        int lo = 0, hi = NBK;
        while (hi - lo > 1) {
            int m = (lo + hi) >> 1;
            if (lofs[m] <= i) lo = m; else hi = m;
        }
        bp[gbase[lo] + (i - lofs[lo])] = stage[i];
    }
}

// ---------------- pass 2: per-bucket degrees + offsets + LDS scatter --------
// Writes esn packed {ns_fp16<<16 | src}.
__global__ __launch_bounds__(256) void k_scatter(const unsigned* __restrict__ bpairs,
                                                 const int* __restrict__ bbase,
                                                 const __half* __restrict__ nsh,
                                                 int* __restrict__ off,
                                                 float* __restrict__ nd,
                                                 unsigned* __restrict__ esn) {
    __shared__ int bins[BKW];
    __shared__ int lcur[BKW];
    __shared__ int wsum[4];
    __shared__ unsigned lout[SCAP];
    int bid = blockIdx.x;
    int r = bid / NBK, b = bid - r * NBK;
    int tid = threadIdx.x;
    int d0 = b * BKW;
    int d1 = min(NN, d0 + BKW);
    int nb = d1 - d0;
    int s0 = bbase[r * (NBK + 1) + b];
    int s1 = bbase[r * (NBK + 1) + b + 1];
    int n = s1 - s0;
    for (int i = tid; i < BKW; i += 256) bins[i] = 0;
    __syncthreads();
    const unsigned* bp = bpairs + (size_t)r * EE + s0;
    for (int i = tid; i < n; i += 256)
        atomicAdd(&bins[(int)(bp[i] >> 16) - d0], 1);
    __syncthreads();
    int v0 = bins[2 * tid], v1 = bins[2 * tid + 1];
    int s = v0 + v1;
    int lane = tid & 63, w = tid >> 6;
    int x = s;
#pragma unroll
    for (int sh = 1; sh < 64; sh <<= 1) {
        int y = __shfl_up(x, (unsigned)sh);
        if (lane >= sh) x += y;
    }
    if (lane == 63) wsum[w] = x;
    __syncthreads();
    int wb = 0;
#pragma unroll
    for (int j = 0; j < 3; ++j) wb += (j < w) ? wsum[j] : 0;
    int ex = wb + x - s;      // exclusive prefix for bin 2t
    int* o = off + r * (NN + 1);
    if (2 * tid < nb) {
        o[d0 + 2 * tid] = s0 + ex;
        nd[r * NN + d0 + 2 * tid] = v0 ? rsqrtf((float)v0) : 0.f;
    }
    if (2 * tid + 1 < nb) {
        o[d0 + 2 * tid + 1] = s0 + ex + v0;
        nd[r * NN + d0 + 2 * tid + 1] = v1 ? rsqrtf((float)v1) : 0.f;
    }
    lcur[2 * tid] = ex;
    lcur[2 * tid + 1] = ex + v0;
    __syncthreads();
    const __half* nsr = nsh + (size_t)r * NN;
    unsigned* out = esn + (size_t)r * EE + s0;
    if (n <= SCAP) {
        for (int i = tid; i < n; i += 256) {
            unsigned pr = bp[i];
            int src = (int)(pr & 0xffffu);
            unsigned wbits = (unsigned)__half_as_ushort(nsr[src]);
            int p = atomicAdd(&lcur[(int)(pr >> 16) - d0], 1);
            lout[p] = (wbits << 16) | (unsigned)src;
        }
        __syncthreads();
        for (int i = tid; i < n; i += 256) out[i] = lout[i];
    } else {  // statistically unreachable safety path
        for (int i = tid; i < n; i += 256) {
            unsigned pr = bp[i];
            int src = (int)(pr & 0xffffu);
            unsigned wbits = (unsigned)__half_as_ushort(nsr[src]);
            int p = atomicAdd(&lcur[(int)(pr >> 16) - d0], 1);
            out[p] = (wbits << 16) | (unsigned)src;
        }
    }
}

// ---------------- x -> fp16 conversion ---------------------------------------
__global__ void k_xprep(const float* __restrict__ x0, const float* __restrict__ x1,
                        const float* __restrict__ x2, __half* __restrict__ xh) {
    int i = blockIdx.x * blockDim.x + threadIdx.x;  // float4 index over 3*NN*32
    const int per = NN * 32;
    if (i >= 3 * per) return;
    int tsel = i / per;
    int o = i - tsel * per;
    const float* xp = (tsel == 0) ? x0 : ((tsel == 1) ? x1 : x2);
    float4 v = *reinterpret_cast<const float4*>(xp + (size_t)o * 4);
    __half* dst = xh + (size_t)tsel * NN * 128 + (size_t)o * 4;
    *reinterpret_cast<__half2*>(dst) = __floats2half2_rn(v.x, v.y);
    *reinterpret_cast<__half2*>(dst + 2) = __floats2half2_rn(v.z, v.w);
}

// ---------------- W prep: fp32 [K][N] -> chunk-major fp16 plane -------------
__global__ void k_wprep(const float* __restrict__ W1, const float* __restrict__ W2,
                        __half* __restrict__ whi) {
    int id = blockIdx.x * blockDim.x + threadIdx.x;
    const int total = 2 * 9 * 128 * 128;
    if (id >= total) return;
    int n = id & 127;
    int k = (id >> 7) & 127;
    int rl = id >> 14;  // layer*9 + r
    const float* W = (rl < 9) ? W1 : W2;
    int r = (rl < 9) ? rl : rl - 9;
    float f = W[((size_t)r * 128 + k) * 128 + n];
    size_t oidx = (((size_t)rl * 4 + (k >> 5)) * 128 + n) * 32 + (k & 31);
    whi[oidx] = __float2half_rn(f);
}

// ---------------- aggregation: ALL 9 relations in one launch -----------------
// grid 112500 = 3 src-group ranges x (3 rels x 12500). Blocks in a range
// interleave that range's 3 relations (%3) -> concurrent blocks share ONE src
// plane (XCD-L2 locality); ranges run back-to-back. Body: 4 edge-slots x 16
// col-lanes, A/B batches always, C/D behind wave-uniform branch.
struct AggT {
    const __half* xin;
    const int* off;
    const unsigned* esn;
    const float* nd;
    __half* A;
};
struct Agg9 { AggT t[9]; };

__global__ __launch_bounds__(256) void k_agg9(Agg9 a) {
    int bid = blockIdx.x;
    int range = bid / 37500;           // src group 0..2
    int sub = bid - range * 37500;
    int task = range * 3 + (sub % 3);
    int wave = (sub / 3) * 4 + (threadIdx.x >> 6);
    int lane = threadIdx.x & 63;
    if (wave >= NN) return;
    AggT t = a.t[task];
    int g = lane >> 4;       // edge slot 0..3
    int c = lane & 15;       // column group: cols c*8 .. c*8+7
    int e0 = t.off[wave], e1 = t.off[wave + 1];
    const __half* xin = t.xin;
    const unsigned* esn = t.esn;
    const h2f zz = {(_Float16)0.f, (_Float16)0.f};
    h2f accA[4] = {zz, zz, zz, zz};
    h2f accB[4] = {zz, zz, zz, zz};
    h2f accC[4] = {zz, zz, zz, zz};
    h2f accD[4] = {zz, zz, zz, zz};
    for (int e = e0; e < e1; e += 16) {
        // ---- batches A,B: edges e .. e+7 ----
        {
            int ea = e + g, eb = e + 4 + g;
            bool va = ea < e1, vb = eb < e1;
            unsigned ua = esn[va ? ea : e];
            unsigned ub = esn[vb ? eb : e];
            int sa = ua & 0xffffu, sb = ub & 0xffffu;
            _Float16 wa = va ? __builtin_bit_cast(_Float16, (unsigned short)(ua >> 16)) : (_Float16)0.f;
            _Float16 wb = vb ? __builtin_bit_cast(_Float16, (unsigned short)(ub >> 16)) : (_Float16)0.f;
            h2f wav = {wa, wa}, wbv = {wb, wb};
            float4 ra = *reinterpret_cast<const float4*>(xin + (size_t)sa * 128 + c * 8);
            float4 rb = *reinterpret_cast<const float4*>(xin + (size_t)sb * 128 + c * 8);
            const h2f* pa = reinterpret_cast<const h2f*>(&ra);
            const h2f* pb = reinterpret_cast<const h2f*>(&rb);
#pragma unroll
            for (int j = 0; j < 4; ++j) {
                accA[j] = wav * pa[j] + accA[j];   // v_pk_fma_f16
                accB[j] = wbv * pb[j] + accB[j];
            }
        }
        // ---- batches C,D: edges e+8 .. e+15 (wave-uniform skip) ----
        if (e + 8 < e1) {
            int ec = e + 8 + g, ed = e + 12 + g;
            bool vc = ec < e1, vd = ed < e1;
            unsigned uc = esn[vc ? ec : e];
            unsigned ud = esn[vd ? ed : e];
            int sc_ = uc & 0xffffu, sd = ud & 0xffffu;
            _Float16 wc = vc ? __builtin_bit_cast(_Float16, (unsigned short)(uc >> 16)) : (_Float16)0.f;
            _Float16 wd = vd ? __builtin_bit_cast(_Float16, (unsigned short)(ud >> 16)) : (_Float16)0.f;
            h2f wcv = {wc, wc}, wdv = {wd, wd};
            float4 rc = *reinterpret_cast<const float4*>(xin + (size_t)sc_ * 128 + c * 8);
            float4 rd = *reinterpret_cast<const float4*>(xin + (size_t)sd * 128 + c * 8);
            const h2f* pc = reinterpret_cast<const h2f*>(&rc);
            const h2f* pd = reinterpret_cast<const h2f*>(&rd);
#pragma unroll
            for (int j = 0; j < 4; ++j) {
                accC[j] = wcv * pc[j] + accC[j];
                accD[j] = wdv * pd[j] + accD[j];
            }
        }
    }
    float acc[8];
#pragma unroll
    for (int j = 0; j < 4; ++j) {
        acc[2 * j]     = ((float)accA[j][0] + (float)accB[j][0]) +
                         ((float)accC[j][0] + (float)accD[j][0]);
        acc[2 * j + 1] = ((float)accA[j][1] + (float)accB[j][1]) +
                         ((float)accC[j][1] + (float)accD[j][1]);
    }
#pragma unroll
    for (int j = 0; j < 8; ++j) {
        acc[j] += __shfl_xor(acc[j], 16);
        acc[j] += __shfl_xor(acc[j], 32);
    }
    if (g == 0) {
        float nr = t.nd[wave];
        f16x8 hv;
#pragma unroll
        for (int j = 0; j < 8; ++j) hv[j] = (_Float16)(acc[j] * nr);
        *reinterpret_cast<f16x8*>(t.A + (size_t)wave * 128 + c * 8) = hv;
    }
}

// ---------------- merged f16 MFMA GEMM: H = relu(sum_s A_s @ W_s + b_s) -----
// One launch per dst plane; single writer -> pure STORE, summed biases.
struct GArg {
    const __half* A[4];
    const __half* W[4];
    const float* b[4];
};

template <int NS>
__global__ __launch_bounds__(256) void k_gemmM(GArg ga, __half* __restrict__ H) {
    int tid = threadIdx.x;
    int w = tid >> 6, lane = tid & 63;
    int row0 = blockIdx.x * 64;
    int colbase = w * 32;
    int r16 = lane & 15;
    int koff = (lane >> 4) * 8;

    f32x4 acc[4][2];
#pragma unroll
    for (int rt = 0; rt < 4; ++rt)
#pragma unroll
        for (int nt = 0; nt < 2; ++nt)
            acc[rt][nt] = f32x4{0.f, 0.f, 0.f, 0.f};

#pragma unroll
    for (int s = 0; s < NS; ++s) {
        const __half* A = ga.A[s];
        const __half* w_h = ga.W[s];
#pragma unroll
        for (int c = 0; c < 4; ++c) {
            int kbase = c * 32 + koff;
            f16x8 av[4], bh[2];
#pragma unroll
            for (int rt = 0; rt < 4; ++rt) {
                int rr = rt * 16 + r16;
                int rc = (row0 + rr < NN) ? rr : 0;
                av[rt] = *reinterpret_cast<const f16x8*>(
                    A + ((size_t)(row0 + rc)) * 128 + kbase);
            }
#pragma unroll
            for (int nt = 0; nt < 2; ++nt) {
                int col = colbase + nt * 16 + r16;
                size_t widx = ((size_t)c * 128 + col) * 32 + koff;
                bh[nt] = *reinterpret_cast<const f16x8*>(w_h + widx);
            }
#pragma unroll
            for (int rt = 0; rt < 4; ++rt)
#pragma unroll
                for (int nt = 0; nt < 2; ++nt)
                    acc[rt][nt] = MFMAH(av[rt], bh[nt], acc[rt][nt]);
        }
    }

    int orow = (lane >> 4) * 4;
#pragma unroll
    for (int nt = 0; nt < 2; ++nt) {
        int col = colbase + nt * 16 + r16;
        float bias = 0.f;
#pragma unroll
        for (int s = 0; s < NS; ++s) bias += ga.b[s][col];
#pragma unroll
        for (int rt = 0; rt < 4; ++rt) {
#pragma unroll
            for (int j = 0; j < 4; ++j) {
                int grow = row0 + rt * 16 + orow + j;
                if (grow < NN) {
                    __half* hp = H + (size_t)grow * 128 + col;
                    float v = fmaxf(acc[rt][nt][j] + bias, 0.f);
                    *hp = __float2half_rn(v);
                }
            }
        }
    }
}

// ---------------- classifier: out = relu(H_fp16) @ Wc + bc ------------------
// (H already relu'd by GEMM epilogue; fmaxf kept — idempotent, safe.)
__global__ __launch_bounds__(256) void k_classifier(const __half* __restrict__ H,
                                                    const float* __restrict__ Wc,
                                                    const float* __restrict__ bc,
                                                    float* __restrict__ out) {
    __shared__ float sW[128 * 16];
    __shared__ float sb[16];
    int tid = threadIdx.x;
#pragma unroll
    for (int i = tid; i < 2048; i += 256) sW[i] = Wc[i];
    if (tid < 16) sb[tid] = bc[tid];
    __syncthreads();
    int node = blockIdx.x * 64 + (tid >> 2);
    if (node >= 3 * NN) return;
    int cg = (tid & 3) << 2;
    const __half* h = H + (size_t)node * 128;
    float acc0 = 0.f, acc1 = 0.f, acc2 = 0.f, acc3 = 0.f;
#pragma unroll 2
    for (int k0 = 0; k0 < 128; k0 += 8) {
        float4 raw = *reinterpret_cast<const float4*>(h + k0);  // 8 halves
        const __half2* hp2 = reinterpret_cast<const __half2*>(&raw);
#pragma unroll
        for (int jj = 0; jj < 4; ++jj) {
            float2 f = __half22float2(hp2[jj]);
            float a;
            a = fmaxf(f.x, 0.f);
            { float4 wv = *reinterpret_cast<const float4*>(&sW[(k0 + 2 * jj) * 16 + cg]);
              acc0 = fmaf(a, wv.x, acc0); acc1 = fmaf(a, wv.y, acc1);
              acc2 = fmaf(a, wv.z, acc2); acc3 = fmaf(a, wv.w, acc3); }
            a = fmaxf(f.y, 0.f);
            { float4 wv = *reinterpret_cast<const float4*>(&sW[(k0 + 2 * jj + 1) * 16 + cg]);
              acc0 = fmaf(a, wv.x, acc0); acc1 = fmaf(a, wv.y, acc1);
              acc2 = fmaf(a, wv.z, acc2); acc3 = fmaf(a, wv.w, acc3); }
        }
    }
    float4 o = make_float4(acc0 + sb[cg], acc1 + sb[cg + 1],
                           acc2 + sb[cg + 2], acc3 + sb[cg + 3]);
    *reinterpret_cast<float4*>(out + (size_t)node * 16 + cg) = o;
}

// ---------------------------------------------------------------------------
extern "C" void kernel_launch(void* const* d_in, const int* in_sizes, int n_in,
                              void* d_out, int out_size, void* d_ws, size_t ws_size,
                              hipStream_t stream) {
    const float* x0 = (const float*)d_in[0];
    const float* x1 = (const float*)d_in[1];
    const float* x2 = (const float*)d_in[2];
    const float* W1 = (const float*)d_in[3];
    const float* b1 = (const float*)d_in[4];
    const float* W2 = (const float*)d_in[5];
    const float* b2 = (const float*)d_in[6];
    const float* Wc = (const float*)d_in[7];
    const float* bc = (const float*)d_in[8];
    const int* edges = (const int*)d_in[9];

    // ---- workspace carve-up with overlays (~212 MB peak) ----
    char* p = (char*)d_ws;
    auto alloc = [&](size_t bytes) -> void* {
        void* r = (void*)p;
        p += (bytes + 255) & ~(size_t)255;
        return r;
    };
    __half* h2h = (__half*)alloc((size_t)3 * NN * 128 * sizeof(__half));  // 38.4 MB
    // aliases inside h2h: hist [k_hist,k_sums), bpairs [k_bucket,k_scatter),
    // A-slots 6..8 during LAYER 1 (h2h written only by layer-2 GEMM).
    unsigned* hist = (unsigned*)h2h;
    unsigned* bpairs = (unsigned*)h2h;
    __half* xh  = (__half*)alloc((size_t)3 * NN * 128 * sizeof(__half));  // 38.4 MB
    __half* h1h = (__half*)alloc((size_t)3 * NN * 128 * sizeof(__half));  // 38.4 MB
    __half* A6  = (__half*)alloc((size_t)6 * NN * 128 * sizeof(__half));  // 76.8 MB
    int* off = (int*)alloc((size_t)9 * (NN + 1) * sizeof(int));
    __half* nsh = (__half*)alloc((size_t)9 * NN * sizeof(__half));
    float* nd = (float*)alloc((size_t)9 * NN * sizeof(float));
    unsigned* esn = (unsigned*)alloc((size_t)9 * EE * sizeof(unsigned));  // 14.4 MB
    __half* whi = (__half*)alloc((size_t)2 * 9 * 128 * 128 * sizeof(__half));
    int* gcur = (int*)alloc((size_t)9 * NBK * sizeof(int));
    int* bcount = (int*)alloc((size_t)9 * NBK * sizeof(int));
    int* bbase = (int*)alloc((size_t)9 * (NBK + 1) * sizeof(int));
    const __half* xph[3] = {xh, xh + (size_t)NN * 128, xh + (size_t)2 * NN * 128};

    // ---- CSR build + input/weight prep (reused by both layers) ----
    k_hist<<<9 * NRG * HCH, 256, 0, stream>>>(edges, hist);
    k_xprep<<<(3 * NN * 32 + 255) / 256, 256, 0, stream>>>(x0, x1, x2, xh);
    k_sums<<<(9 * (NN / 2) + 255) / 256, 256, 0, stream>>>(hist, nsh);
    hipMemsetAsync(bcount, 0, (size_t)9 * NBK * sizeof(int), stream);
    k_bcount<<<9 * NCH, 256, 0, stream>>>(edges, bcount);
    k_bscan<<<1, 64, 0, stream>>>(bcount, bbase, gcur, off);
    k_bucket<<<9 * NCH, 256, 0, stream>>>(edges, gcur, bpairs);
    k_scatter<<<9 * NBK, 256, 0, stream>>>(bpairs, bbase, nsh, off, nd, esn);
    k_wprep<<<(2 * 9 * 128 * 128 + 255) / 256, 256, 0, stream>>>(W1, W2, whi);

    const int gemm_blocks = (NN + 63) / 64;   // 782
    auto wp = [&](int layer, int r) { return (size_t)(layer * 9 + r) * 16384; };

    // task order (slot j -> relation): grouped by src type
    const int TASKREL[9] = {0, 3, 6,  1, 2, 8,  4, 5, 7};
    // dst planes: plane0 <- rels {3,6,2,5} ; plane1 <- {8,4} ; plane2 <- {0,1,7}

    for (int L = 0; L < 2; ++L) {
        const float* b = (L == 0) ? b1 : b2;
        __half* hout = (L == 0) ? h1h : h2h;
        // A-slot pointers: 0..5 in A6; 6..8 overlay h2h (L0) / xh (L1)
        __half* ovl = (L == 0) ? h2h : xh;
        __half* P[9];
        for (int j = 0; j < 6; ++j) P[j] = A6 + (size_t)j * NN * 128;
        for (int j = 6; j < 9; ++j) P[j] = ovl + (size_t)(j - 6) * NN * 128;

        // ---- one agg launch: all 9 relations ----
        Agg9 a9;
        for (int j = 0; j < 9; ++j) {
            int r = TASKREL[j];
            const __half* xin;
            if (L == 0) xin = xph[j / 3];
            else        xin = h1h + (size_t)(j / 3) * NN * 128;
            a9.t[j] = AggT{xin, off + r * (NN + 1), esn + (size_t)r * EE,
                           nd + r * NN, P[j]};
        }
        k_agg9<<<112500, 256, 0, stream>>>(a9);

        // ---- three merged GEMMs (single writer per plane) ----
        // plane0: rels (3,6,2,5) -> slots (1,2,4,7)
        {
            GArg ga;
            const int rs[4] = {3, 6, 2, 5};
            const int sl[4] = {1, 2, 4, 7};
            for (int s = 0; s < 4; ++s) {
                ga.A[s] = P[sl[s]];
                ga.W[s] = whi + wp(L, rs[s]);
                ga.b[s] = b + rs[s] * 128;
            }
            k_gemmM<4><<<gemm_blocks, 256, 0, stream>>>(ga, hout + (size_t)0 * NN * 128);
        }
        // plane1: rels (8,4) -> slots (5,6)
        {
            GArg ga;
            const int rs[2] = {8, 4};
            const int sl[2] = {5, 6};
            for (int s = 0; s < 2; ++s) {
                ga.A[s] = P[sl[s]];
                ga.W[s] = whi + wp(L, rs[s]);
                ga.b[s] = b + rs[s] * 128;
            }
            ga.A[2] = ga.A[3] = ga.A[0]; ga.W[2] = ga.W[3] = ga.W[0];
            ga.b[2] = ga.b[3] = ga.b[0];
            k_gemmM<2><<<gemm_blocks, 256, 0, stream>>>(ga, hout + (size_t)1 * NN * 128);
        }
        // plane2: rels (0,1,7) -> slots (0,3,8)
        {
            GArg ga;
            const int rs[3] = {0, 1, 7};
            const int sl[3] = {0, 3, 8};
            for (int s = 0; s < 3; ++s) {
                ga.A[s] = P[sl[s]];
                ga.W[s] = whi + wp(L, rs[s]);
                ga.b[s] = b + rs[s] * 128;
            }
            ga.A[3] = ga.A[0]; ga.W[3] = ga.W[0]; ga.b[3] = ga.b[0];
            k_gemmM<3><<<gemm_blocks, 256, 0, stream>>>(ga, hout + (size_t)2 * NN * 128);
        }
    }

    // ---- classifier: out = relu(h2h) @ Wc + bc ----
    k_classifier<<<(3 * NN + 63) / 64, 256, 0, stream>>>(h2h, Wc, bc, (float*)d_out);
}